// Round 1
// baseline (806.462 us; speedup 1.0000x reference)
//
#include <hip/hip_runtime.h>
#include <hip/hip_bf16.h>

#define N_NODES 50000
#define N_EDGES 800000

// ---------------- CSR build ----------------

__global__ __launch_bounds__(256) void hist_kernel(const int* __restrict__ dst,
                                                   int* __restrict__ deg) {
    int e = blockIdx.x * 256 + threadIdx.x;
    if (e < N_EDGES) atomicAdd(&deg[dst[e]], 1);
}

__global__ __launch_bounds__(256) void invdeg_kernel(const int* __restrict__ deg,
                                                     float* __restrict__ inv_deg) {
    int i = blockIdx.x * 256 + threadIdx.x;
    if (i < N_NODES) {
        int d = deg[i];
        inv_deg[i] = 1.0f / (float)(d > 0 ? d : 1);
    }
}

// single-block exclusive scan over deg[N_NODES] -> row_off[N_NODES+1]
__global__ __launch_bounds__(1024) void scan_kernel(const int* __restrict__ deg,
                                                    int* __restrict__ row_off) {
    __shared__ int wsum[16];
    __shared__ int carry_s;
    int tid = threadIdx.x;
    int lane = tid & 63;
    int wv = tid >> 6;  // 16 waves
    if (tid == 0) carry_s = 0;
    __syncthreads();
    for (int base = 0; base < N_NODES; base += 1024) {
        int i = base + tid;
        int v = (i < N_NODES) ? deg[i] : 0;
        // wave-inclusive scan
        int incl = v;
        #pragma unroll
        for (int off = 1; off < 64; off <<= 1) {
            int t = __shfl_up(incl, off, 64);
            if (lane >= off) incl += t;
        }
        if (lane == 63) wsum[wv] = incl;
        __syncthreads();
        if (wv == 0) {
            int s = (lane < 16) ? wsum[lane] : 0;
            #pragma unroll
            for (int off = 1; off < 16; off <<= 1) {
                int t = __shfl_up(s, off, 64);
                if (lane >= off) s += t;
            }
            if (lane < 16) wsum[lane] = s;  // inclusive sums of wave totals
        }
        __syncthreads();
        int wpre = (wv > 0) ? wsum[wv - 1] : 0;
        int carry = carry_s;
        if (i < N_NODES) row_off[i] = carry + wpre + incl - v;  // exclusive
        __syncthreads();
        if (tid == 1023) carry_s = carry + wsum[15];
        __syncthreads();
    }
    if (tid == 0) row_off[N_NODES] = carry_s;
}

__global__ __launch_bounds__(256) void scatter_kernel(const int* __restrict__ src,
                                                      const int* __restrict__ dst,
                                                      const float* __restrict__ w,
                                                      const int* __restrict__ row_off,
                                                      int* __restrict__ cursor,
                                                      int* __restrict__ ssrc,
                                                      float* __restrict__ sw) {
    int e = blockIdx.x * 256 + threadIdx.x;
    if (e < N_EDGES) {
        int d = dst[e];
        int p = atomicAdd(&cursor[d], 1);
        int idx = row_off[d] + p;
        ssrc[idx] = src[e];
        sw[idx] = w[e];
    }
}

// ---------------- Aggregation (gather, one wave per dst node) ----------------

__global__ __launch_bounds__(64) void agg64_kernel(const float* __restrict__ x,
                                                   const int* __restrict__ row_off,
                                                   const int* __restrict__ ssrc,
                                                   const float* __restrict__ sw,
                                                   const float* __restrict__ inv_deg,
                                                   float* __restrict__ out) {
    int n = blockIdx.x;
    int t = threadIdx.x;  // feature dim 0..63
    int e0 = row_off[n], e1 = row_off[n + 1];
    float acc = 0.f;
    for (int e = e0; e < e1; e++) {
        int s = ssrc[e];
        float wv = sw[e];
        acc += wv * x[s * 64 + t];
    }
    out[n * 64 + t] = acc * inv_deg[n];
}

__global__ __launch_bounds__(64) void agg256_kernel(const float* __restrict__ x,
                                                    const int* __restrict__ row_off,
                                                    const int* __restrict__ ssrc,
                                                    const float* __restrict__ sw,
                                                    const float* __restrict__ inv_deg,
                                                    float* __restrict__ out) {
    int n = blockIdx.x;
    int t = threadIdx.x;  // float4 lane: dims [4t, 4t+3]
    int e0 = row_off[n], e1 = row_off[n + 1];
    const float4* xv = (const float4*)x;
    float4 acc = make_float4(0.f, 0.f, 0.f, 0.f);
    for (int e = e0; e < e1; e++) {
        int s = ssrc[e];
        float wv = sw[e];
        float4 v = xv[s * 64 + t];
        acc.x += wv * v.x;
        acc.y += wv * v.y;
        acc.z += wv * v.z;
        acc.w += wv * v.w;
    }
    float id = inv_deg[n];
    float4 r = make_float4(acc.x * id, acc.y * id, acc.z * id, acc.w * id);
    ((float4*)out)[n * 64 + t] = r;
}

// ---------------- Layer GEMMs (fp32 vector, register-tiled) ----------------

// x1 = relu(x @ W1s + hn1 @ W1n + b1)   [50000,64]x[64,256]
__global__ __launch_bounds__(256) void gemm1_kernel(const float* __restrict__ x,
                                                    const float* __restrict__ hn,
                                                    const float* __restrict__ Ws,
                                                    const float* __restrict__ Wn,
                                                    const float* __restrict__ b,
                                                    float* __restrict__ out) {
    const int M = 16;
    __shared__ float xs[M][64];
    __shared__ float hs[M][64];
    int n0 = blockIdx.x * M;
    int tid = threadIdx.x;
    for (int i = tid; i < M * 64; i += 256) {
        int m = i >> 6, k = i & 63;
        xs[m][k] = x[(n0 + m) * 64 + k];
        hs[m][k] = hn[(n0 + m) * 64 + k];
    }
    __syncthreads();
    int j = tid;
    float acc[M];
    #pragma unroll
    for (int m = 0; m < M; m++) acc[m] = 0.f;
    for (int k = 0; k < 64; k++) {
        float ws = Ws[k * 256 + j];
        float wn = Wn[k * 256 + j];
        #pragma unroll
        for (int m = 0; m < M; m++) acc[m] += xs[m][k] * ws + hs[m][k] * wn;
    }
    float bias = b[j];
    #pragma unroll
    for (int m = 0; m < M; m++) {
        float v = acc[m] + bias;
        out[(n0 + m) * 256 + j] = v > 0.f ? v : 0.f;
    }
}

// emb = x1 @ W2s + hn2 @ W2n + b2    [50000,256]x[256,128]
__global__ __launch_bounds__(128) void gemm2_kernel(const float* __restrict__ x,
                                                    const float* __restrict__ hn,
                                                    const float* __restrict__ Ws,
                                                    const float* __restrict__ Wn,
                                                    const float* __restrict__ b,
                                                    float* __restrict__ out) {
    const int M = 16;
    __shared__ float xs[M][256];
    __shared__ float hs[M][256];
    int n0 = blockIdx.x * M;
    int tid = threadIdx.x;
    for (int i = tid; i < M * 256; i += 128) {
        int m = i >> 8, k = i & 255;
        xs[m][k] = x[(n0 + m) * 256 + k];
        hs[m][k] = hn[(n0 + m) * 256 + k];
    }
    __syncthreads();
    int j = tid;
    float acc[M];
    #pragma unroll
    for (int m = 0; m < M; m++) acc[m] = 0.f;
    for (int k = 0; k < 256; k++) {
        float ws = Ws[k * 128 + j];
        float wn = Wn[k * 128 + j];
        #pragma unroll
        for (int m = 0; m < M; m++) acc[m] += xs[m][k] * ws + hs[m][k] * wn;
    }
    float bias = b[j];
    #pragma unroll
    for (int m = 0; m < M; m++) out[(n0 + m) * 128 + j] = acc[m] + bias;
}

// ---------------- MLP head ----------------

// h64 = relu(emb @ Wl1 + bl1)   [50000,128]x[128,64]
__global__ __launch_bounds__(64) void mlp1_kernel(const float* __restrict__ emb,
                                                  const float* __restrict__ W,
                                                  const float* __restrict__ b,
                                                  float* __restrict__ out) {
    const int M = 16;
    __shared__ float es[M][128];
    int n0 = blockIdx.x * M;
    int tid = threadIdx.x;
    for (int i = tid; i < M * 128; i += 64) {
        int m = i >> 7, k = i & 127;
        es[m][k] = emb[(n0 + m) * 128 + k];
    }
    __syncthreads();
    int j = tid;
    float acc[M];
    #pragma unroll
    for (int m = 0; m < M; m++) acc[m] = 0.f;
    for (int k = 0; k < 128; k++) {
        float wv = W[k * 64 + j];
        #pragma unroll
        for (int m = 0; m < M; m++) acc[m] += es[m][k] * wv;
    }
    float bias = b[j];
    #pragma unroll
    for (int m = 0; m < M; m++) {
        float v = acc[m] + bias;
        out[(n0 + m) * 64 + j] = v > 0.f ? v : 0.f;
    }
}

// h32 = relu(h64 @ Wl2 + bl2)   [50000,64]x[64,32]; 64 threads = 2 groups of j in [0,32)
__global__ __launch_bounds__(64) void mlp2_kernel(const float* __restrict__ h64,
                                                  const float* __restrict__ W,
                                                  const float* __restrict__ b,
                                                  float* __restrict__ out) {
    const int M = 16;
    __shared__ float hsld[32][64];
    int n0 = blockIdx.x * 32;
    int tid = threadIdx.x;
    for (int i = tid; i < 32 * 64; i += 64) {
        int m = i >> 6, k = i & 63;
        int n = n0 + m;
        hsld[m][k] = (n < N_NODES) ? h64[n * 64 + k] : 0.f;
    }
    __syncthreads();
    int j = tid & 31;
    int g = tid >> 5;
    float acc[M];
    #pragma unroll
    for (int m = 0; m < M; m++) acc[m] = 0.f;
    for (int k = 0; k < 64; k++) {
        float wv = W[k * 32 + j];
        #pragma unroll
        for (int m = 0; m < M; m++) acc[m] += hsld[g * 16 + m][k] * wv;
    }
    float bias = b[j];
    #pragma unroll
    for (int m = 0; m < M; m++) {
        int n = n0 + g * 16 + m;
        if (n < N_NODES) {
            float v = acc[m] + bias;
            out[n * 32 + j] = v > 0.f ? v : 0.f;
        }
    }
}

// out = h32 @ Wl3 + bl3   [50000,32]x[32,10]; 320 threads = 32 nodes x 10 cols
__global__ __launch_bounds__(320) void mlp3_kernel(const float* __restrict__ h32,
                                                   const float* __restrict__ W,
                                                   const float* __restrict__ b,
                                                   float* __restrict__ out) {
    int tid = threadIdx.x;
    int nl = tid / 10;
    int j = tid - nl * 10;
    int n = blockIdx.x * 32 + nl;
    if (n >= N_NODES) return;
    float acc = b[j];
    #pragma unroll
    for (int k = 0; k < 32; k++) acc += h32[n * 32 + k] * W[k * 10 + j];
    out[n * 10 + j] = acc;
}

// ---------------- launch ----------------

extern "C" void kernel_launch(void* const* d_in, const int* in_sizes, int n_in,
                              void* d_out, int out_size, void* d_ws, size_t ws_size,
                              hipStream_t stream) {
    const float* x   = (const float*)d_in[0];
    const int* esrc  = (const int*)d_in[1];
    const int* edst  = (const int*)d_in[2];
    const float* ew  = (const float*)d_in[3];
    const float* W1s = (const float*)d_in[4];
    const float* W1n = (const float*)d_in[5];
    const float* b1  = (const float*)d_in[6];
    const float* W2s = (const float*)d_in[7];
    const float* W2n = (const float*)d_in[8];
    const float* b2  = (const float*)d_in[9];
    const float* Wl1 = (const float*)d_in[10];
    const float* bl1 = (const float*)d_in[11];
    const float* Wl2 = (const float*)d_in[12];
    const float* bl2 = (const float*)d_in[13];
    const float* Wl3 = (const float*)d_in[14];
    const float* bl3 = (const float*)d_in[15];

    float* out = (float*)d_out;       // [50000,10]
    float* emb = out + 500000;        // [50000,128] (output 1, also MLP input)

    char* ws = (char*)d_ws;
    size_t off = 0;
    auto alloc = [&](size_t bytes) -> void* {
        void* p = ws + off;
        off = (off + bytes + 255) & ~(size_t)255;
        return p;
    };
    int*   deg     = (int*)alloc((size_t)N_NODES * 4);
    int*   cursor  = (int*)alloc((size_t)N_NODES * 4);
    int*   row_off = (int*)alloc((size_t)(N_NODES + 1) * 4);
    float* inv_deg = (float*)alloc((size_t)N_NODES * 4);
    int*   ssrc    = (int*)alloc((size_t)N_EDGES * 4);
    float* sw      = (float*)alloc((size_t)N_EDGES * 4);
    float* hn1     = (float*)alloc((size_t)N_NODES * 64 * 4);   // reused as h64
    float* x1      = (float*)alloc((size_t)N_NODES * 256 * 4);
    float* hn2     = (float*)alloc((size_t)N_NODES * 256 * 4);  // reused as h32
    float* h64r = hn1;  // free after gemm1
    float* h32r = hn2;  // free after gemm2

    hipMemsetAsync(deg, 0, (size_t)N_NODES * 4, stream);
    hipMemsetAsync(cursor, 0, (size_t)N_NODES * 4, stream);

    hist_kernel<<<(N_EDGES + 255) / 256, 256, 0, stream>>>(edst, deg);
    scan_kernel<<<1, 1024, 0, stream>>>(deg, row_off);
    invdeg_kernel<<<(N_NODES + 255) / 256, 256, 0, stream>>>(deg, inv_deg);
    scatter_kernel<<<(N_EDGES + 255) / 256, 256, 0, stream>>>(esrc, edst, ew, row_off,
                                                              cursor, ssrc, sw);
    agg64_kernel<<<N_NODES, 64, 0, stream>>>(x, row_off, ssrc, sw, inv_deg, hn1);
    gemm1_kernel<<<N_NODES / 16, 256, 0, stream>>>(x, hn1, W1s, W1n, b1, x1);
    agg256_kernel<<<N_NODES, 64, 0, stream>>>(x1, row_off, ssrc, sw, inv_deg, hn2);
    gemm2_kernel<<<N_NODES / 16, 128, 0, stream>>>(x1, hn2, W2s, W2n, b2, emb);
    mlp1_kernel<<<N_NODES / 16, 64, 0, stream>>>(emb, Wl1, bl1, h64r);
    mlp2_kernel<<<(N_NODES + 31) / 32, 64, 0, stream>>>(h64r, Wl2, bl2, h32r);
    mlp3_kernel<<<(N_NODES + 31) / 32, 320, 0, stream>>>(h32r, Wl3, bl3, out);
}

// Round 2
// 393.000 us; speedup vs baseline: 2.0521x; 2.0521x over previous
//
#include <hip/hip_runtime.h>
#include <hip/hip_bf16.h>

#define N_NODES 50000
#define N_EDGES 800000
#define MT_TILES 3125   // 50000 / 16

typedef __attribute__((ext_vector_type(8))) short frag_ab;   // 8 bf16 (4 VGPRs)
typedef __attribute__((ext_vector_type(4))) float frag_cd;   // 4 fp32 acc

static __device__ __forceinline__ unsigned short f2b(float f) {
    union { float f; unsigned u; } v; v.f = f;
    unsigned r = v.u + 0x7fffu + ((v.u >> 16) & 1u);  // RNE
    return (unsigned short)(r >> 16);
}
static __device__ __forceinline__ float b2f(unsigned short b) {
    union { float f; unsigned u; } v; v.u = ((unsigned)b) << 16;
    return v.f;
}

// ---------------- fp32 -> bf16 conversion ----------------
__global__ __launch_bounds__(256) void cvt_bf16_kernel(const float4* __restrict__ in,
                                                       ushort4* __restrict__ out, int n4) {
    int i = blockIdx.x * 256 + threadIdx.x;
    if (i < n4) {
        float4 v = in[i];
        ushort4 o;
        o.x = f2b(v.x); o.y = f2b(v.y); o.z = f2b(v.z); o.w = f2b(v.w);
        out[i] = o;
    }
}

// ---------------- CSR build ----------------
__global__ __launch_bounds__(256) void hist_kernel(const int* __restrict__ dst,
                                                   int* __restrict__ deg) {
    int e = blockIdx.x * 256 + threadIdx.x;
    if (e < N_EDGES) atomicAdd(&deg[dst[e]], 1);
}

__global__ __launch_bounds__(256) void invdeg_kernel(const int* __restrict__ deg,
                                                     float* __restrict__ inv_deg) {
    int i = blockIdx.x * 256 + threadIdx.x;
    if (i < N_NODES) {
        int d = deg[i];
        inv_deg[i] = 1.0f / (float)(d > 0 ? d : 1);
    }
}

#define NB_SCAN 196  // ceil(50000/256)

__global__ __launch_bounds__(256) void bsum_kernel(const int* __restrict__ deg,
                                                   int* __restrict__ bsum) {
    int i = blockIdx.x * 256 + threadIdx.x;
    int v = (i < N_NODES) ? deg[i] : 0;
    #pragma unroll
    for (int off = 32; off; off >>= 1) v += __shfl_down(v, off, 64);
    __shared__ int ws[4];
    if ((threadIdx.x & 63) == 0) ws[threadIdx.x >> 6] = v;
    __syncthreads();
    if (threadIdx.x == 0) bsum[blockIdx.x] = ws[0] + ws[1] + ws[2] + ws[3];
}

__global__ __launch_bounds__(256) void scanb_kernel(const int* __restrict__ bsum,
                                                    int* __restrict__ boff,
                                                    int* __restrict__ row_off) {
    __shared__ int s[256];
    int t = threadIdx.x;
    int v = (t < NB_SCAN) ? bsum[t] : 0;
    s[t] = v;
    __syncthreads();
    for (int off = 1; off < 256; off <<= 1) {
        int add = (t >= off) ? s[t - off] : 0;
        __syncthreads();
        s[t] += add;
        __syncthreads();
    }
    if (t < NB_SCAN) boff[t] = s[t] - v;  // exclusive
    if (t == 255) row_off[N_NODES] = s[255];
}

__global__ __launch_bounds__(256) void rowoff_kernel(const int* __restrict__ deg,
                                                     const int* __restrict__ boff,
                                                     int* __restrict__ row_off) {
    __shared__ int s[256];
    int t = threadIdx.x;
    int i = blockIdx.x * 256 + t;
    int v = (i < N_NODES) ? deg[i] : 0;
    s[t] = v;
    __syncthreads();
    for (int off = 1; off < 256; off <<= 1) {
        int add = (t >= off) ? s[t - off] : 0;
        __syncthreads();
        s[t] += add;
        __syncthreads();
    }
    if (i < N_NODES) row_off[i] = boff[blockIdx.x] + s[t] - v;  // exclusive
}

__global__ __launch_bounds__(256) void scatter_kernel(const int* __restrict__ src,
                                                      const int* __restrict__ dst,
                                                      const float* __restrict__ w,
                                                      const int* __restrict__ row_off,
                                                      int* __restrict__ cursor,
                                                      int* __restrict__ ssrc,
                                                      float* __restrict__ sw) {
    int e = blockIdx.x * 256 + threadIdx.x;
    if (e < N_EDGES) {
        int d = dst[e];
        int p = atomicAdd(&cursor[d], 1);
        int idx = row_off[d] + p;
        ssrc[idx] = src[e];
        sw[idx] = w[e];
    }
}

// ---------------- weight packing into MFMA B-fragment order ----------------
// out[((kt*NT + nt)*64 + lane)*8 + j] = B[kt*32 + (lane>>4)*8 + j][nt*16 + (lane&15)]
// concat along K: B[k][n] = k < Ka ? Wa[k][n] : Wb[k-Ka][n]
__global__ __launch_bounds__(256) void packBK_kernel(const float* __restrict__ Wa,
                                                     const float* __restrict__ Wb,
                                                     int Ka, int N, int total,
                                                     unsigned short* __restrict__ out) {
    int idx = blockIdx.x * 256 + threadIdx.x;
    if (idx >= total) return;
    int j = idx & 7;
    int lane = (idx >> 3) & 63;
    int rest = idx >> 9;
    int ntiles = N >> 4;
    int nt = rest % ntiles;
    int kt = rest / ntiles;
    int kk = kt * 32 + (lane >> 4) * 8 + j;
    int nn = nt * 16 + (lane & 15);
    float v = (kk < Ka) ? Wa[kk * N + nn] : Wb[(kk - Ka) * N + nn];
    out[idx] = f2b(v);
}

// concat along N: B[k][n] = n < Na ? Wa[k][n] : Wb[k][n-Na] (Wa rowlen Na, Wb rowlen N-Na)
__global__ __launch_bounds__(256) void packBN_kernel(const float* __restrict__ Wa,
                                                     const float* __restrict__ Wb,
                                                     int Na, int N, int total,
                                                     unsigned short* __restrict__ out) {
    int idx = blockIdx.x * 256 + threadIdx.x;
    if (idx >= total) return;
    int j = idx & 7;
    int lane = (idx >> 3) & 63;
    int rest = idx >> 9;
    int ntiles = N >> 4;
    int nt = rest % ntiles;
    int kt = rest / ntiles;
    int kk = kt * 32 + (lane >> 4) * 8 + j;
    int nn = nt * 16 + (lane & 15);
    float v = (nn < Na) ? Wa[kk * Na + nn] : Wb[kk * (N - Na) + (nn - Na)];
    out[idx] = f2b(v);
}

// ---------------- Aggregations (gather, one wave per dst node) ----------------

// hn1b = bf16( (sum_e w_e * xb[src_e]) * inv_deg )   d=64
__global__ __launch_bounds__(64) void agg64_kernel(const unsigned short* __restrict__ xb,
                                                   const int* __restrict__ row_off,
                                                   const int* __restrict__ ssrc,
                                                   const float* __restrict__ sw,
                                                   const float* __restrict__ inv_deg,
                                                   unsigned short* __restrict__ hn1b) {
    int n = blockIdx.x;
    int t = threadIdx.x;
    int e0 = row_off[n], e1 = row_off[n + 1];
    float acc = 0.f;
    for (int e = e0; e < e1; e++) {
        int s = ssrc[e];
        float w = sw[e];
        acc += w * b2f(xb[s * 64 + t]);
    }
    hn1b[n * 64 + t] = f2b(acc * inv_deg[n]);
}

// emb += agg(z)*inv_deg (emb holds self+bias); also emit bf16 copy.  d=128, 2 dims/lane
__global__ __launch_bounds__(64) void agg128_kernel(const unsigned int* __restrict__ zb32,
                                                    const int* __restrict__ row_off,
                                                    const int* __restrict__ ssrc,
                                                    const float* __restrict__ sw,
                                                    const float* __restrict__ inv_deg,
                                                    float* __restrict__ emb,
                                                    unsigned int* __restrict__ embb32) {
    int n = blockIdx.x;
    int t = threadIdx.x;
    int e0 = row_off[n], e1 = row_off[n + 1];
    float ax = 0.f, ay = 0.f;
    for (int e = e0; e < e1; e++) {
        int s = ssrc[e];
        float w = sw[e];
        unsigned p = zb32[s * 64 + t];
        ax += w * b2f((unsigned short)(p & 0xffffu));
        ay += w * b2f((unsigned short)(p >> 16));
    }
    float id = inv_deg[n];
    float2 self = ((const float2*)emb)[n * 64 + t];
    float vx = self.x + ax * id;
    float vy = self.y + ay * id;
    ((float2*)emb)[n * 64 + t] = make_float2(vx, vy);
    embb32[n * 64 + t] = (unsigned)f2b(vx) | ((unsigned)f2b(vy) << 16);
}

// ---------------- MFMA GEMMs: one wave per 16-row m-tile ----------------

// x1b = bf16(relu([xb|hn1b] @ [W1s;W1n] + b1))   K=128, N=256
__global__ __launch_bounds__(256) void gemm1_mfma(const unsigned short* __restrict__ xb,
                                                  const unsigned short* __restrict__ hn1b,
                                                  const unsigned short* __restrict__ Bp,
                                                  const float* __restrict__ b1,
                                                  unsigned short* __restrict__ x1b) {
    int tid = threadIdx.x;
    int lane = tid & 63;
    int wv = tid >> 6;
    int mt = blockIdx.x * 4 + wv;
    if (mt >= MT_TILES) mt = MT_TILES - 1;  // dup wave, benign same-value stores
    int r0 = mt * 16;
    int row = r0 + (lane & 15);
    int q = lane >> 4;
    const unsigned short* xrow = xb + row * 64 + q * 8;
    const unsigned short* hrow = hn1b + row * 64 + q * 8;
    const frag_ab* bp = (const frag_ab*)Bp;
    frag_cd acc[16];
    #pragma unroll
    for (int nt = 0; nt < 16; nt++) acc[nt] = (frag_cd){0.f, 0.f, 0.f, 0.f};
    #pragma unroll
    for (int kt = 0; kt < 4; kt++) {
        const unsigned short* ap = (kt < 2) ? (xrow + kt * 32) : (hrow + (kt - 2) * 32);
        frag_ab a = *(const frag_ab*)ap;
        #pragma unroll
        for (int nt = 0; nt < 16; nt++) {
            frag_ab b = bp[(kt * 16 + nt) * 64 + lane];
            acc[nt] = __builtin_amdgcn_mfma_f32_16x16x32_bf16(a, b, acc[nt], 0, 0, 0);
        }
    }
    int col = lane & 15;
    #pragma unroll
    for (int nt = 0; nt < 16; nt++) {
        int c = nt * 16 + col;
        float bias = b1[c];
        #pragma unroll
        for (int i = 0; i < 4; i++) {
            int r = r0 + q * 4 + i;
            float v = acc[nt][i] + bias;
            v = v > 0.f ? v : 0.f;
            x1b[r * 256 + c] = f2b(v);
        }
    }
}

// self+z: x1b @ [W2s|W2n] ; cols 0-127 -> emb fp32 (+b2), cols 128-255 -> zb bf16
__global__ __launch_bounds__(256) void gemm2_mfma(const unsigned short* __restrict__ x1b,
                                                  const unsigned short* __restrict__ Bp,
                                                  const float* __restrict__ b2,
                                                  float* __restrict__ emb,
                                                  unsigned short* __restrict__ zb) {
    int tid = threadIdx.x;
    int lane = tid & 63;
    int wv = tid >> 6;
    int mt = blockIdx.x * 4 + wv;
    if (mt >= MT_TILES) mt = MT_TILES - 1;
    int r0 = mt * 16;
    int row = r0 + (lane & 15);
    int q = lane >> 4;
    const unsigned short* arow = x1b + row * 256 + q * 8;
    const frag_ab* bp = (const frag_ab*)Bp;
    frag_cd acc[16];
    #pragma unroll
    for (int nt = 0; nt < 16; nt++) acc[nt] = (frag_cd){0.f, 0.f, 0.f, 0.f};
    #pragma unroll
    for (int kt = 0; kt < 8; kt++) {
        frag_ab a = *(const frag_ab*)(arow + kt * 32);
        #pragma unroll
        for (int nt = 0; nt < 16; nt++) {
            frag_ab b = bp[(kt * 16 + nt) * 64 + lane];
            acc[nt] = __builtin_amdgcn_mfma_f32_16x16x32_bf16(a, b, acc[nt], 0, 0, 0);
        }
    }
    int col = lane & 15;
    #pragma unroll
    for (int nt = 0; nt < 8; nt++) {
        int c = nt * 16 + col;
        float bias = b2[c];
        #pragma unroll
        for (int i = 0; i < 4; i++) {
            int r = r0 + q * 4 + i;
            emb[r * 128 + c] = acc[nt][i] + bias;
        }
    }
    #pragma unroll
    for (int nt = 8; nt < 16; nt++) {
        int c = (nt - 8) * 16 + col;
        #pragma unroll
        for (int i = 0; i < 4; i++) {
            int r = r0 + q * 4 + i;
            zb[r * 128 + c] = f2b(acc[nt][i]);
        }
    }
}

// h64b = bf16(relu(embb @ Wl1 + bl1))   K=128, N=64
__global__ __launch_bounds__(256) void mlp1_mfma(const unsigned short* __restrict__ embb,
                                                 const unsigned short* __restrict__ Bp,
                                                 const float* __restrict__ bl1,
                                                 unsigned short* __restrict__ h64b) {
    int tid = threadIdx.x;
    int lane = tid & 63;
    int wv = tid >> 6;
    int mt = blockIdx.x * 4 + wv;
    if (mt >= MT_TILES) mt = MT_TILES - 1;
    int r0 = mt * 16;
    int row = r0 + (lane & 15);
    int q = lane >> 4;
    const unsigned short* arow = embb + row * 128 + q * 8;
    const frag_ab* bp = (const frag_ab*)Bp;
    frag_cd acc[4];
    #pragma unroll
    for (int nt = 0; nt < 4; nt++) acc[nt] = (frag_cd){0.f, 0.f, 0.f, 0.f};
    #pragma unroll
    for (int kt = 0; kt < 4; kt++) {
        frag_ab a = *(const frag_ab*)(arow + kt * 32);
        #pragma unroll
        for (int nt = 0; nt < 4; nt++) {
            frag_ab b = bp[(kt * 4 + nt) * 64 + lane];
            acc[nt] = __builtin_amdgcn_mfma_f32_16x16x32_bf16(a, b, acc[nt], 0, 0, 0);
        }
    }
    int col = lane & 15;
    #pragma unroll
    for (int nt = 0; nt < 4; nt++) {
        int c = nt * 16 + col;
        float bias = bl1[c];
        #pragma unroll
        for (int i = 0; i < 4; i++) {
            int r = r0 + q * 4 + i;
            float v = acc[nt][i] + bias;
            v = v > 0.f ? v : 0.f;
            h64b[r * 64 + c] = f2b(v);
        }
    }
}

// h32 = relu(h64b @ Wl2 + bl2)  fp32 out  K=64, N=32
__global__ __launch_bounds__(256) void mlp2_mfma(const unsigned short* __restrict__ h64b,
                                                 const unsigned short* __restrict__ Bp,
                                                 const float* __restrict__ bl2,
                                                 float* __restrict__ h32) {
    int tid = threadIdx.x;
    int lane = tid & 63;
    int wv = tid >> 6;
    int mt = blockIdx.x * 4 + wv;
    if (mt >= MT_TILES) mt = MT_TILES - 1;
    int r0 = mt * 16;
    int row = r0 + (lane & 15);
    int q = lane >> 4;
    const unsigned short* arow = h64b + row * 64 + q * 8;
    const frag_ab* bp = (const frag_ab*)Bp;
    frag_cd acc[2];
    #pragma unroll
    for (int nt = 0; nt < 2; nt++) acc[nt] = (frag_cd){0.f, 0.f, 0.f, 0.f};
    #pragma unroll
    for (int kt = 0; kt < 2; kt++) {
        frag_ab a = *(const frag_ab*)(arow + kt * 32);
        #pragma unroll
        for (int nt = 0; nt < 2; nt++) {
            frag_ab b = bp[(kt * 2 + nt) * 64 + lane];
            acc[nt] = __builtin_amdgcn_mfma_f32_16x16x32_bf16(a, b, acc[nt], 0, 0, 0);
        }
    }
    int col = lane & 15;
    #pragma unroll
    for (int nt = 0; nt < 2; nt++) {
        int c = nt * 16 + col;
        float bias = bl2[c];
        #pragma unroll
        for (int i = 0; i < 4; i++) {
            int r = r0 + q * 4 + i;
            float v = acc[nt][i] + bias;
            h32[r * 32 + c] = v > 0.f ? v : 0.f;
        }
    }
}

// out = h32 @ Wl3 + bl3   [50000,32]x[32,10]
__global__ __launch_bounds__(320) void mlp3_kernel(const float* __restrict__ h32,
                                                   const float* __restrict__ W,
                                                   const float* __restrict__ b,
                                                   float* __restrict__ out) {
    int tid = threadIdx.x;
    int nl = tid / 10;
    int j = tid - nl * 10;
    int n = blockIdx.x * 32 + nl;
    if (n >= N_NODES) return;
    float acc = b[j];
    #pragma unroll
    for (int k = 0; k < 32; k++) acc += h32[n * 32 + k] * W[k * 10 + j];
    out[n * 10 + j] = acc;
}

// ---------------- launch ----------------

extern "C" void kernel_launch(void* const* d_in, const int* in_sizes, int n_in,
                              void* d_out, int out_size, void* d_ws, size_t ws_size,
                              hipStream_t stream) {
    const float* x   = (const float*)d_in[0];
    const int* esrc  = (const int*)d_in[1];
    const int* edst  = (const int*)d_in[2];
    const float* ew  = (const float*)d_in[3];
    const float* W1s = (const float*)d_in[4];
    const float* W1n = (const float*)d_in[5];
    const float* b1  = (const float*)d_in[6];
    const float* W2s = (const float*)d_in[7];
    const float* W2n = (const float*)d_in[8];
    const float* b2  = (const float*)d_in[9];
    const float* Wl1 = (const float*)d_in[10];
    const float* bl1 = (const float*)d_in[11];
    const float* Wl2 = (const float*)d_in[12];
    const float* bl2 = (const float*)d_in[13];
    const float* Wl3 = (const float*)d_in[14];
    const float* bl3 = (const float*)d_in[15];

    float* out = (float*)d_out;       // [50000,10]
    float* emb = out + 500000;        // [50000,128] output 1

    char* ws = (char*)d_ws;
    size_t off = 0;
    auto alloc = [&](size_t bytes) -> void* {
        void* p = ws + off;
        off = (off + bytes + 255) & ~(size_t)255;
        return p;
    };
    int*   deg     = (int*)alloc((size_t)N_NODES * 4);
    int*   cursor  = (int*)alloc((size_t)N_NODES * 4);
    int*   row_off = (int*)alloc((size_t)(N_NODES + 1) * 4);
    float* inv_deg = (float*)alloc((size_t)N_NODES * 4);
    int*   bsum    = (int*)alloc(256 * 4);
    int*   boff    = (int*)alloc(256 * 4);
    int*   ssrc    = (int*)alloc((size_t)N_EDGES * 4);
    float* sw      = (float*)alloc((size_t)N_EDGES * 4);
    unsigned short* xb   = (unsigned short*)alloc((size_t)N_NODES * 64 * 2);
    unsigned short* hn1b = (unsigned short*)alloc((size_t)N_NODES * 64 * 2);
    unsigned short* x1b  = (unsigned short*)alloc((size_t)N_NODES * 256 * 2);
    unsigned short* zb   = (unsigned short*)alloc((size_t)N_NODES * 128 * 2);
    unsigned short* embb = (unsigned short*)alloc((size_t)N_NODES * 128 * 2);
    unsigned short* h64b = (unsigned short*)alloc((size_t)N_NODES * 64 * 2);
    float* h32           = (float*)alloc((size_t)N_NODES * 32 * 4);
    unsigned short* B1p  = (unsigned short*)alloc(128 * 256 * 2);
    unsigned short* B2p  = (unsigned short*)alloc(256 * 256 * 2);
    unsigned short* Bl1p = (unsigned short*)alloc(128 * 64 * 2);
    unsigned short* Bl2p = (unsigned short*)alloc(64 * 32 * 2);

    hipMemsetAsync(deg, 0, (size_t)N_NODES * 4, stream);
    hipMemsetAsync(cursor, 0, (size_t)N_NODES * 4, stream);

    // conversions & weight packing (independent of CSR)
    cvt_bf16_kernel<<<(N_NODES * 64 / 4 + 255) / 256, 256, 0, stream>>>(
        (const float4*)x, (ushort4*)xb, N_NODES * 64 / 4);
    packBK_kernel<<<(128 * 256 + 255) / 256, 256, 0, stream>>>(W1s, W1n, 64, 256,
                                                               128 * 256, B1p);
    packBN_kernel<<<(256 * 256 + 255) / 256, 256, 0, stream>>>(W2s, W2n, 128, 256,
                                                               256 * 256, B2p);
    packBK_kernel<<<(128 * 64 + 255) / 256, 256, 0, stream>>>(Wl1, Wl1, 128, 64,
                                                              128 * 64, Bl1p);
    packBK_kernel<<<(64 * 32 + 255) / 256, 256, 0, stream>>>(Wl2, Wl2, 64, 32,
                                                             64 * 32, Bl2p);

    // CSR build
    hist_kernel<<<(N_EDGES + 255) / 256, 256, 0, stream>>>(edst, deg);
    bsum_kernel<<<NB_SCAN, 256, 0, stream>>>(deg, bsum);
    scanb_kernel<<<1, 256, 0, stream>>>(bsum, boff, row_off);
    rowoff_kernel<<<NB_SCAN, 256, 0, stream>>>(deg, boff, row_off);
    invdeg_kernel<<<(N_NODES + 255) / 256, 256, 0, stream>>>(deg, inv_deg);
    scatter_kernel<<<(N_EDGES + 255) / 256, 256, 0, stream>>>(esrc, edst, ew, row_off,
                                                              cursor, ssrc, sw);

    const int GBLK = (MT_TILES + 3) / 4;  // 782

    // layer 1
    agg64_kernel<<<N_NODES, 64, 0, stream>>>(xb, row_off, ssrc, sw, inv_deg, hn1b);
    gemm1_mfma<<<GBLK, 256, 0, stream>>>(xb, hn1b, B1p, b1, x1b);

    // layer 2: GEMM first (self + z), then aggregate z in 128-dim
    gemm2_mfma<<<GBLK, 256, 0, stream>>>(x1b, B2p, b2, emb, zb);
    agg128_kernel<<<N_NODES, 64, 0, stream>>>((const unsigned int*)zb, row_off, ssrc,
                                              sw, inv_deg, emb, (unsigned int*)embb);

    // MLP head
    mlp1_mfma<<<GBLK, 256, 0, stream>>>(embb, Bl1p, bl1, h64b);
    mlp2_mfma<<<GBLK, 256, 0, stream>>>(h64b, Bl2p, bl2, h32);
    mlp3_kernel<<<(N_NODES + 31) / 32, 320, 0, stream>>>(h32, Wl3, bl3, out);
}

// Round 3
// 392.395 us; speedup vs baseline: 2.0552x; 1.0015x over previous
//
#include <hip/hip_runtime.h>
#include <hip/hip_bf16.h>

#define N_NODES 50000
#define N_EDGES 800000
#define MT_TILES 3125   // 50000 / 16

typedef __attribute__((ext_vector_type(8))) short frag_ab;   // 8 bf16 (4 VGPRs)
typedef __attribute__((ext_vector_type(4))) float frag_cd;   // 4 fp32 acc

static __device__ __forceinline__ unsigned short f2b(float f) {
    union { float f; unsigned u; } v; v.f = f;
    unsigned r = v.u + 0x7fffu + ((v.u >> 16) & 1u);  // RNE
    return (unsigned short)(r >> 16);
}
static __device__ __forceinline__ float b2f(unsigned short b) {
    union { float f; unsigned u; } v; v.u = ((unsigned)b) << 16;
    return v.f;
}

// ---------------- fp32 -> bf16 conversion ----------------
__global__ __launch_bounds__(256) void cvt_bf16_kernel(const float4* __restrict__ in,
                                                       ushort4* __restrict__ out, int n4) {
    int i = blockIdx.x * 256 + threadIdx.x;
    if (i < n4) {
        float4 v = in[i];
        ushort4 o;
        o.x = f2b(v.x); o.y = f2b(v.y); o.z = f2b(v.z); o.w = f2b(v.w);
        out[i] = o;
    }
}

// ---------------- CSR build ----------------
__global__ __launch_bounds__(256) void hist_kernel(const int* __restrict__ dst,
                                                   int* __restrict__ deg) {
    int e = blockIdx.x * 256 + threadIdx.x;
    if (e < N_EDGES) atomicAdd(&deg[dst[e]], 1);
}

// inv_deg from deg; cursor initialized to row_off (saves a load in scatter)
__global__ __launch_bounds__(256) void invdeg_kernel(const int* __restrict__ deg,
                                                     const int* __restrict__ row_off,
                                                     float* __restrict__ inv_deg,
                                                     int* __restrict__ cursor) {
    int i = blockIdx.x * 256 + threadIdx.x;
    if (i < N_NODES) {
        int d = deg[i];
        inv_deg[i] = 1.0f / (float)(d > 0 ? d : 1);
        cursor[i] = row_off[i];
    }
}

#define NB_SCAN 196  // ceil(50000/256)

__global__ __launch_bounds__(256) void bsum_kernel(const int* __restrict__ deg,
                                                   int* __restrict__ bsum) {
    int i = blockIdx.x * 256 + threadIdx.x;
    int v = (i < N_NODES) ? deg[i] : 0;
    #pragma unroll
    for (int off = 32; off; off >>= 1) v += __shfl_down(v, off, 64);
    __shared__ int ws[4];
    if ((threadIdx.x & 63) == 0) ws[threadIdx.x >> 6] = v;
    __syncthreads();
    if (threadIdx.x == 0) bsum[blockIdx.x] = ws[0] + ws[1] + ws[2] + ws[3];
}

__global__ __launch_bounds__(256) void scanb_kernel(const int* __restrict__ bsum,
                                                    int* __restrict__ boff,
                                                    int* __restrict__ row_off) {
    __shared__ int s[256];
    int t = threadIdx.x;
    int v = (t < NB_SCAN) ? bsum[t] : 0;
    s[t] = v;
    __syncthreads();
    for (int off = 1; off < 256; off <<= 1) {
        int add = (t >= off) ? s[t - off] : 0;
        __syncthreads();
        s[t] += add;
        __syncthreads();
    }
    if (t < NB_SCAN) boff[t] = s[t] - v;  // exclusive
    if (t == 255) row_off[N_NODES] = s[255];
}

__global__ __launch_bounds__(256) void rowoff_kernel(const int* __restrict__ deg,
                                                     const int* __restrict__ boff,
                                                     int* __restrict__ row_off) {
    __shared__ int s[256];
    int t = threadIdx.x;
    int i = blockIdx.x * 256 + t;
    int v = (i < N_NODES) ? deg[i] : 0;
    s[t] = v;
    __syncthreads();
    for (int off = 1; off < 256; off <<= 1) {
        int add = (t >= off) ? s[t - off] : 0;
        __syncthreads();
        s[t] += add;
        __syncthreads();
    }
    if (i < N_NODES) row_off[i] = boff[blockIdx.x] + s[t] - v;  // exclusive
}

// one combined 8B store per edge: (src, w-bits)
__global__ __launch_bounds__(256) void scatter_kernel(const int* __restrict__ src,
                                                      const int* __restrict__ dst,
                                                      const float* __restrict__ w,
                                                      int* __restrict__ cursor,
                                                      int2* __restrict__ sedge) {
    int e = blockIdx.x * 256 + threadIdx.x;
    if (e < N_EDGES) {
        int d = dst[e];
        int idx = atomicAdd(&cursor[d], 1);
        sedge[idx] = make_int2(src[e], __float_as_int(w[e]));
    }
}

// ---------------- weight packing into MFMA B-fragment order ----------------
__global__ __launch_bounds__(256) void packBK_kernel(const float* __restrict__ Wa,
                                                     const float* __restrict__ Wb,
                                                     int Ka, int N, int total,
                                                     unsigned short* __restrict__ out) {
    int idx = blockIdx.x * 256 + threadIdx.x;
    if (idx >= total) return;
    int j = idx & 7;
    int lane = (idx >> 3) & 63;
    int rest = idx >> 9;
    int ntiles = N >> 4;
    int nt = rest % ntiles;
    int kt = rest / ntiles;
    int kk = kt * 32 + (lane >> 4) * 8 + j;
    int nn = nt * 16 + (lane & 15);
    float v = (kk < Ka) ? Wa[kk * N + nn] : Wb[(kk - Ka) * N + nn];
    out[idx] = f2b(v);
}

__global__ __launch_bounds__(256) void packBN_kernel(const float* __restrict__ Wa,
                                                     const float* __restrict__ Wb,
                                                     int Na, int N, int total,
                                                     unsigned short* __restrict__ out) {
    int idx = blockIdx.x * 256 + threadIdx.x;
    if (idx >= total) return;
    int j = idx & 7;
    int lane = (idx >> 3) & 63;
    int rest = idx >> 9;
    int ntiles = N >> 4;
    int nt = rest % ntiles;
    int kt = rest / ntiles;
    int kk = kt * 32 + (lane >> 4) * 8 + j;
    int nn = nt * 16 + (lane & 15);
    float v = (nn < Na) ? Wa[kk * Na + nn] : Wb[kk * (N - Na) + (nn - Na)];
    out[idx] = f2b(v);
}

// ---------------- Aggregations (gather; 4 waves/block, 1 node/wave) ----------------
// Edge metadata prefetched 64-wide per wave, broadcast via shfl.

__global__ __launch_bounds__(256) void agg64_kernel(const unsigned short* __restrict__ xb,
                                                    const int* __restrict__ row_off,
                                                    const int2* __restrict__ sedge,
                                                    const float* __restrict__ inv_deg,
                                                    unsigned short* __restrict__ hn1b) {
    int lane = threadIdx.x & 63;
    int n = blockIdx.x * 4 + (threadIdx.x >> 6);
    if (n >= N_NODES) return;
    int e0 = row_off[n], e1 = row_off[n + 1];
    float acc = 0.f;
    for (int base = e0; base < e1; base += 64) {
        int cnt = e1 - base; if (cnt > 64) cnt = 64;
        int2 m = sedge[min(base + lane, e1 - 1)];
        for (int j = 0; j < cnt; j++) {
            int s = __shfl(m.x, j, 64);
            float w = __int_as_float(__shfl(m.y, j, 64));
            acc += w * b2f(xb[s * 64 + lane]);
        }
    }
    hn1b[n * 64 + lane] = f2b(acc * inv_deg[n]);
}

// emb += agg(z)*inv_deg (emb holds self+bias); also emit bf16 copy.  d=128, 2 dims/lane
__global__ __launch_bounds__(256) void agg128_kernel(const unsigned int* __restrict__ zb32,
                                                     const int* __restrict__ row_off,
                                                     const int2* __restrict__ sedge,
                                                     const float* __restrict__ inv_deg,
                                                     float* __restrict__ emb,
                                                     unsigned int* __restrict__ embb32) {
    int lane = threadIdx.x & 63;
    int n = blockIdx.x * 4 + (threadIdx.x >> 6);
    if (n >= N_NODES) return;
    int e0 = row_off[n], e1 = row_off[n + 1];
    float ax = 0.f, ay = 0.f;
    for (int base = e0; base < e1; base += 64) {
        int cnt = e1 - base; if (cnt > 64) cnt = 64;
        int2 m = sedge[min(base + lane, e1 - 1)];
        for (int j = 0; j < cnt; j++) {
            int s = __shfl(m.x, j, 64);
            float w = __int_as_float(__shfl(m.y, j, 64));
            unsigned p = zb32[s * 64 + lane];
            ax += w * b2f((unsigned short)(p & 0xffffu));
            ay += w * b2f((unsigned short)(p >> 16));
        }
    }
    float id = inv_deg[n];
    float2 self = ((const float2*)emb)[n * 64 + lane];
    float vx = self.x + ax * id;
    float vy = self.y + ay * id;
    ((float2*)emb)[n * 64 + lane] = make_float2(vx, vy);
    embb32[n * 64 + lane] = (unsigned)f2b(vx) | ((unsigned)f2b(vy) << 16);
}

// ---------------- MFMA GEMMs: one wave per 16-row m-tile ----------------

__global__ __launch_bounds__(256) void gemm1_mfma(const unsigned short* __restrict__ xb,
                                                  const unsigned short* __restrict__ hn1b,
                                                  const unsigned short* __restrict__ Bp,
                                                  const float* __restrict__ b1,
                                                  unsigned short* __restrict__ x1b) {
    int tid = threadIdx.x;
    int lane = tid & 63;
    int wv = tid >> 6;
    int mt = blockIdx.x * 4 + wv;
    if (mt >= MT_TILES) mt = MT_TILES - 1;  // dup wave, benign same-value stores
    int r0 = mt * 16;
    int row = r0 + (lane & 15);
    int q = lane >> 4;
    const unsigned short* xrow = xb + row * 64 + q * 8;
    const unsigned short* hrow = hn1b + row * 64 + q * 8;
    const frag_ab* bp = (const frag_ab*)Bp;
    frag_cd acc[16];
    #pragma unroll
    for (int nt = 0; nt < 16; nt++) acc[nt] = (frag_cd){0.f, 0.f, 0.f, 0.f};
    #pragma unroll
    for (int kt = 0; kt < 4; kt++) {
        const unsigned short* ap = (kt < 2) ? (xrow + kt * 32) : (hrow + (kt - 2) * 32);
        frag_ab a = *(const frag_ab*)ap;
        #pragma unroll
        for (int nt = 0; nt < 16; nt++) {
            frag_ab b = bp[(kt * 16 + nt) * 64 + lane];
            acc[nt] = __builtin_amdgcn_mfma_f32_16x16x32_bf16(a, b, acc[nt], 0, 0, 0);
        }
    }
    int col = lane & 15;
    #pragma unroll
    for (int nt = 0; nt < 16; nt++) {
        int c = nt * 16 + col;
        float bias = b1[c];
        #pragma unroll
        for (int i = 0; i < 4; i++) {
            int r = r0 + q * 4 + i;
            float v = acc[nt][i] + bias;
            v = v > 0.f ? v : 0.f;
            x1b[r * 256 + c] = f2b(v);
        }
    }
}

__global__ __launch_bounds__(256) void gemm2_mfma(const unsigned short* __restrict__ x1b,
                                                  const unsigned short* __restrict__ Bp,
                                                  const float* __restrict__ b2,
                                                  float* __restrict__ emb,
                                                  unsigned short* __restrict__ zb) {
    int tid = threadIdx.x;
    int lane = tid & 63;
    int wv = tid >> 6;
    int mt = blockIdx.x * 4 + wv;
    if (mt >= MT_TILES) mt = MT_TILES - 1;
    int r0 = mt * 16;
    int row = r0 + (lane & 15);
    int q = lane >> 4;
    const unsigned short* arow = x1b + row * 256 + q * 8;
    const frag_ab* bp = (const frag_ab*)Bp;
    frag_cd acc[16];
    #pragma unroll
    for (int nt = 0; nt < 16; nt++) acc[nt] = (frag_cd){0.f, 0.f, 0.f, 0.f};
    #pragma unroll
    for (int kt = 0; kt < 8; kt++) {
        frag_ab a = *(const frag_ab*)(arow + kt * 32);
        #pragma unroll
        for (int nt = 0; nt < 16; nt++) {
            frag_ab b = bp[(kt * 16 + nt) * 64 + lane];
            acc[nt] = __builtin_amdgcn_mfma_f32_16x16x32_bf16(a, b, acc[nt], 0, 0, 0);
        }
    }
    int col = lane & 15;
    #pragma unroll
    for (int nt = 0; nt < 8; nt++) {
        int c = nt * 16 + col;
        float bias = b2[c];
        #pragma unroll
        for (int i = 0; i < 4; i++) {
            int r = r0 + q * 4 + i;
            emb[r * 128 + c] = acc[nt][i] + bias;
        }
    }
    #pragma unroll
    for (int nt = 8; nt < 16; nt++) {
        int c = (nt - 8) * 16 + col;
        #pragma unroll
        for (int i = 0; i < 4; i++) {
            int r = r0 + q * 4 + i;
            zb[r * 128 + c] = f2b(acc[nt][i]);
        }
    }
}

__global__ __launch_bounds__(256) void mlp1_mfma(const unsigned short* __restrict__ embb,
                                                 const unsigned short* __restrict__ Bp,
                                                 const float* __restrict__ bl1,
                                                 unsigned short* __restrict__ h64b) {
    int tid = threadIdx.x;
    int lane = tid & 63;
    int wv = tid >> 6;
    int mt = blockIdx.x * 4 + wv;
    if (mt >= MT_TILES) mt = MT_TILES - 1;
    int r0 = mt * 16;
    int row = r0 + (lane & 15);
    int q = lane >> 4;
    const unsigned short* arow = embb + row * 128 + q * 8;
    const frag_ab* bp = (const frag_ab*)Bp;
    frag_cd acc[4];
    #pragma unroll
    for (int nt = 0; nt < 4; nt++) acc[nt] = (frag_cd){0.f, 0.f, 0.f, 0.f};
    #pragma unroll
    for (int kt = 0; kt < 4; kt++) {
        frag_ab a = *(const frag_ab*)(arow + kt * 32);
        #pragma unroll
        for (int nt = 0; nt < 4; nt++) {
            frag_ab b = bp[(kt * 4 + nt) * 64 + lane];
            acc[nt] = __builtin_amdgcn_mfma_f32_16x16x32_bf16(a, b, acc[nt], 0, 0, 0);
        }
    }
    int col = lane & 15;
    #pragma unroll
    for (int nt = 0; nt < 4; nt++) {
        int c = nt * 16 + col;
        float bias = bl1[c];
        #pragma unroll
        for (int i = 0; i < 4; i++) {
            int r = r0 + q * 4 + i;
            float v = acc[nt][i] + bias;
            v = v > 0.f ? v : 0.f;
            h64b[r * 64 + c] = f2b(v);
        }
    }
}

__global__ __launch_bounds__(256) void mlp2_mfma(const unsigned short* __restrict__ h64b,
                                                 const unsigned short* __restrict__ Bp,
                                                 const float* __restrict__ bl2,
                                                 float* __restrict__ h32) {
    int tid = threadIdx.x;
    int lane = tid & 63;
    int wv = tid >> 6;
    int mt = blockIdx.x * 4 + wv;
    if (mt >= MT_TILES) mt = MT_TILES - 1;
    int r0 = mt * 16;
    int row = r0 + (lane & 15);
    int q = lane >> 4;
    const unsigned short* arow = h64b + row * 64 + q * 8;
    const frag_ab* bp = (const frag_ab*)Bp;
    frag_cd acc[2];
    #pragma unroll
    for (int nt = 0; nt < 2; nt++) acc[nt] = (frag_cd){0.f, 0.f, 0.f, 0.f};
    #pragma unroll
    for (int kt = 0; kt < 2; kt++) {
        frag_ab a = *(const frag_ab*)(arow + kt * 32);
        #pragma unroll
        for (int nt = 0; nt < 2; nt++) {
            frag_ab b = bp[(kt * 2 + nt) * 64 + lane];
            acc[nt] = __builtin_amdgcn_mfma_f32_16x16x32_bf16(a, b, acc[nt], 0, 0, 0);
        }
    }
    int col = lane & 15;
    #pragma unroll
    for (int nt = 0; nt < 2; nt++) {
        int c = nt * 16 + col;
        float bias = bl2[c];
        #pragma unroll
        for (int i = 0; i < 4; i++) {
            int r = r0 + q * 4 + i;
            float v = acc[nt][i] + bias;
            h32[r * 32 + c] = v > 0.f ? v : 0.f;
        }
    }
}

__global__ __launch_bounds__(320) void mlp3_kernel(const float* __restrict__ h32,
                                                   const float* __restrict__ W,
                                                   const float* __restrict__ b,
                                                   float* __restrict__ out) {
    int tid = threadIdx.x;
    int nl = tid / 10;
    int j = tid - nl * 10;
    int n = blockIdx.x * 32 + nl;
    if (n >= N_NODES) return;
    float acc = b[j];
    #pragma unroll
    for (int k = 0; k < 32; k++) acc += h32[n * 32 + k] * W[k * 10 + j];
    out[n * 10 + j] = acc;
}

// ---------------- launch ----------------

extern "C" void kernel_launch(void* const* d_in, const int* in_sizes, int n_in,
                              void* d_out, int out_size, void* d_ws, size_t ws_size,
                              hipStream_t stream) {
    const float* x   = (const float*)d_in[0];
    const int* esrc  = (const int*)d_in[1];
    const int* edst  = (const int*)d_in[2];
    const float* ew  = (const float*)d_in[3];
    const float* W1s = (const float*)d_in[4];
    const float* W1n = (const float*)d_in[5];
    const float* b1  = (const float*)d_in[6];
    const float* W2s = (const float*)d_in[7];
    const float* W2n = (const float*)d_in[8];
    const float* b2  = (const float*)d_in[9];
    const float* Wl1 = (const float*)d_in[10];
    const float* bl1 = (const float*)d_in[11];
    const float* Wl2 = (const float*)d_in[12];
    const float* bl2 = (const float*)d_in[13];
    const float* Wl3 = (const float*)d_in[14];
    const float* bl3 = (const float*)d_in[15];

    float* out = (float*)d_out;       // [50000,10]
    float* emb = out + 500000;        // [50000,128] output 1

    char* ws = (char*)d_ws;
    size_t off = 0;
    auto alloc = [&](size_t bytes) -> void* {
        void* p = ws + off;
        off = (off + bytes + 255) & ~(size_t)255;
        return p;
    };
    int*   deg     = (int*)alloc((size_t)N_NODES * 4);
    int*   cursor  = (int*)alloc((size_t)N_NODES * 4);
    int*   row_off = (int*)alloc((size_t)(N_NODES + 1) * 4);
    float* inv_deg = (float*)alloc((size_t)N_NODES * 4);
    int*   bsum    = (int*)alloc(256 * 4);
    int*   boff    = (int*)alloc(256 * 4);
    int2*  sedge   = (int2*)alloc((size_t)N_EDGES * 8);
    unsigned short* xb   = (unsigned short*)alloc((size_t)N_NODES * 64 * 2);
    unsigned short* hn1b = (unsigned short*)alloc((size_t)N_NODES * 64 * 2);
    unsigned short* x1b  = (unsigned short*)alloc((size_t)N_NODES * 256 * 2);
    unsigned short* zb   = (unsigned short*)alloc((size_t)N_NODES * 128 * 2);
    unsigned short* embb = (unsigned short*)alloc((size_t)N_NODES * 128 * 2);
    unsigned short* h64b = (unsigned short*)alloc((size_t)N_NODES * 64 * 2);
    float* h32           = (float*)alloc((size_t)N_NODES * 32 * 4);
    unsigned short* B1p  = (unsigned short*)alloc(128 * 256 * 2);
    unsigned short* B2p  = (unsigned short*)alloc(256 * 256 * 2);
    unsigned short* Bl1p = (unsigned short*)alloc(128 * 64 * 2);
    unsigned short* Bl2p = (unsigned short*)alloc(64 * 32 * 2);

    hipMemsetAsync(deg, 0, (size_t)N_NODES * 4, stream);

    // conversions & weight packing (independent of CSR)
    cvt_bf16_kernel<<<(N_NODES * 64 / 4 + 255) / 256, 256, 0, stream>>>(
        (const float4*)x, (ushort4*)xb, N_NODES * 64 / 4);
    packBK_kernel<<<(128 * 256 + 255) / 256, 256, 0, stream>>>(W1s, W1n, 64, 256,
                                                               128 * 256, B1p);
    packBN_kernel<<<(256 * 256 + 255) / 256, 256, 0, stream>>>(W2s, W2n, 128, 256,
                                                               256 * 256, B2p);
    packBK_kernel<<<(128 * 64 + 255) / 256, 256, 0, stream>>>(Wl1, Wl1, 128, 64,
                                                              128 * 64, Bl1p);
    packBK_kernel<<<(64 * 32 + 255) / 256, 256, 0, stream>>>(Wl2, Wl2, 64, 32,
                                                             64 * 32, Bl2p);

    // CSR build
    hist_kernel<<<(N_EDGES + 255) / 256, 256, 0, stream>>>(edst, deg);
    bsum_kernel<<<NB_SCAN, 256, 0, stream>>>(deg, bsum);
    scanb_kernel<<<1, 256, 0, stream>>>(bsum, boff, row_off);
    rowoff_kernel<<<NB_SCAN, 256, 0, stream>>>(deg, boff, row_off);
    invdeg_kernel<<<(N_NODES + 255) / 256, 256, 0, stream>>>(deg, row_off, inv_deg,
                                                             cursor);
    scatter_kernel<<<(N_EDGES + 255) / 256, 256, 0, stream>>>(esrc, edst, ew, cursor,
                                                              sedge);

    const int GBLK = (MT_TILES + 3) / 4;   // 782
    const int ABLK = (N_NODES + 3) / 4;    // 12500

    // layer 1
    agg64_kernel<<<ABLK, 256, 0, stream>>>(xb, row_off, sedge, inv_deg, hn1b);
    gemm1_mfma<<<GBLK, 256, 0, stream>>>(xb, hn1b, B1p, b1, x1b);

    // layer 2: GEMM first (self + z), then aggregate z in 128-dim
    gemm2_mfma<<<GBLK, 256, 0, stream>>>(x1b, B2p, b2, emb, zb);
    agg128_kernel<<<ABLK, 256, 0, stream>>>((const unsigned int*)zb, row_off, sedge,
                                            inv_deg, emb, (unsigned int*)embb);

    // MLP head
    mlp1_mfma<<<GBLK, 256, 0, stream>>>(embb, Bl1p, bl1, h64b);
    mlp2_mfma<<<GBLK, 256, 0, stream>>>(h64b, Bl2p, bl2, h32);
    mlp3_kernel<<<(N_NODES + 31) / 32, 320, 0, stream>>>(h32, Wl3, bl3, out);
}

// Round 4
// 337.995 us; speedup vs baseline: 2.3860x; 1.1609x over previous
//
#include <hip/hip_runtime.h>
#include <hip/hip_bf16.h>

#define N_NODES 50000
#define N_EDGES 800000
#define MT_TILES 3125   // 50000 / 16

typedef __attribute__((ext_vector_type(8))) short frag_ab;   // 8 bf16 (4 VGPRs)
typedef __attribute__((ext_vector_type(4))) float frag_cd;   // 4 fp32 acc

static __device__ __forceinline__ unsigned short f2b(float f) {
    union { float f; unsigned u; } v; v.f = f;
    unsigned r = v.u + 0x7fffu + ((v.u >> 16) & 1u);  // RNE
    return (unsigned short)(r >> 16);
}
static __device__ __forceinline__ float b2f(unsigned short b) {
    union { float f; unsigned u; } v; v.u = ((unsigned)b) << 16;
    return v.f;
}
static __device__ __forceinline__ float blo(unsigned p) { return b2f((unsigned short)(p & 0xffffu)); }
static __device__ __forceinline__ float bhi(unsigned p) { return b2f((unsigned short)(p >> 16)); }

// ---------------- fused prep: cvt x -> bf16, pack all weights ----------------
static __device__ __forceinline__ unsigned short packBK_elem(const float* __restrict__ Wa,
                                                             const float* __restrict__ Wb,
                                                             int Ka, int N, int idx) {
    int j = idx & 7;
    int lane = (idx >> 3) & 63;
    int rest = idx >> 9;
    int ntiles = N >> 4;
    int nt = rest % ntiles;
    int kt = rest / ntiles;
    int kk = kt * 32 + (lane >> 4) * 8 + j;
    int nn = nt * 16 + (lane & 15);
    float v = (kk < Ka) ? Wa[kk * N + nn] : Wb[(kk - Ka) * N + nn];
    return f2b(v);
}
static __device__ __forceinline__ unsigned short packBN_elem(const float* __restrict__ Wa,
                                                             const float* __restrict__ Wb,
                                                             int Na, int N, int idx) {
    int j = idx & 7;
    int lane = (idx >> 3) & 63;
    int rest = idx >> 9;
    int ntiles = N >> 4;
    int nt = rest % ntiles;
    int kt = rest / ntiles;
    int kk = kt * 32 + (lane >> 4) * 8 + j;
    int nn = nt * 16 + (lane & 15);
    float v = (nn < Na) ? Wa[kk * Na + nn] : Wb[kk * (N - Na) + (nn - Na)];
    return f2b(v);
}

#define PREP_S0 800000                 // cvt: ushort4 items (N_NODES*64/4)
#define PREP_S1 (PREP_S0 + 32768)      // B1p  128x256
#define PREP_S2 (PREP_S1 + 65536)      // B2p  256x256
#define PREP_S3 (PREP_S2 + 8192)       // Bl1p 128x64
#define PREP_S4 (PREP_S3 + 2048)       // Bl2p 64x32   -> total 908544 = 3549*256

__global__ __launch_bounds__(256) void prep_kernel(const float4* __restrict__ x4,
                                                   ushort4* __restrict__ xb4,
                                                   const float* __restrict__ W1s,
                                                   const float* __restrict__ W1n,
                                                   const float* __restrict__ W2s,
                                                   const float* __restrict__ W2n,
                                                   const float* __restrict__ Wl1,
                                                   const float* __restrict__ Wl2,
                                                   unsigned short* __restrict__ B1p,
                                                   unsigned short* __restrict__ B2p,
                                                   unsigned short* __restrict__ Bl1p,
                                                   unsigned short* __restrict__ Bl2p) {
    int idx = blockIdx.x * 256 + threadIdx.x;
    if (idx < PREP_S0) {
        float4 v = x4[idx];
        ushort4 o;
        o.x = f2b(v.x); o.y = f2b(v.y); o.z = f2b(v.z); o.w = f2b(v.w);
        xb4[idx] = o;
    } else if (idx < PREP_S1) {
        int i = idx - PREP_S0;
        B1p[i] = packBK_elem(W1s, W1n, 64, 256, i);
    } else if (idx < PREP_S2) {
        int i = idx - PREP_S1;
        B2p[i] = packBN_elem(W2s, W2n, 128, 256, i);
    } else if (idx < PREP_S3) {
        int i = idx - PREP_S2;
        Bl1p[i] = packBK_elem(Wl1, Wl1, 128, 64, i);
    } else if (idx < PREP_S4) {
        int i = idx - PREP_S3;
        Bl2p[i] = packBK_elem(Wl2, Wl2, 64, 32, i);
    }
}

// ---------------- CSR build ----------------
__global__ __launch_bounds__(256) void hist_kernel(const int* __restrict__ dst,
                                                   int* __restrict__ deg) {
    int e = blockIdx.x * 256 + threadIdx.x;
    if (e < N_EDGES) atomicAdd(&deg[dst[e]], 1);
}

#define NB_SCAN 196  // ceil(50000/256)

__global__ __launch_bounds__(256) void bsum_kernel(const int* __restrict__ deg,
                                                   int* __restrict__ bsum) {
    int i = blockIdx.x * 256 + threadIdx.x;
    int v = (i < N_NODES) ? deg[i] : 0;
    #pragma unroll
    for (int off = 32; off; off >>= 1) v += __shfl_down(v, off, 64);
    __shared__ int ws[4];
    if ((threadIdx.x & 63) == 0) ws[threadIdx.x >> 6] = v;
    __syncthreads();
    if (threadIdx.x == 0) bsum[blockIdx.x] = ws[0] + ws[1] + ws[2] + ws[3];
}

__global__ __launch_bounds__(256) void scanb_kernel(const int* __restrict__ bsum,
                                                    int* __restrict__ boff,
                                                    int* __restrict__ row_off) {
    __shared__ int s[256];
    int t = threadIdx.x;
    int v = (t < NB_SCAN) ? bsum[t] : 0;
    s[t] = v;
    __syncthreads();
    for (int off = 1; off < 256; off <<= 1) {
        int add = (t >= off) ? s[t - off] : 0;
        __syncthreads();
        s[t] += add;
        __syncthreads();
    }
    if (t < NB_SCAN) boff[t] = s[t] - v;  // exclusive
    if (t == 255) row_off[N_NODES] = s[255];
}

// row_off + inv_deg + cursor in one pass
__global__ __launch_bounds__(256) void rowoff_kernel(const int* __restrict__ deg,
                                                     const int* __restrict__ boff,
                                                     int* __restrict__ row_off,
                                                     float* __restrict__ inv_deg,
                                                     int* __restrict__ cursor) {
    __shared__ int s[256];
    int t = threadIdx.x;
    int i = blockIdx.x * 256 + t;
    int v = (i < N_NODES) ? deg[i] : 0;
    s[t] = v;
    __syncthreads();
    for (int off = 1; off < 256; off <<= 1) {
        int add = (t >= off) ? s[t - off] : 0;
        __syncthreads();
        s[t] += add;
        __syncthreads();
    }
    if (i < N_NODES) {
        int ro = boff[blockIdx.x] + s[t] - v;  // exclusive
        row_off[i] = ro;
        cursor[i] = ro;
        inv_deg[i] = 1.0f / (float)(v > 0 ? v : 1);
    }
}

// one combined 8B store per edge: (src, w-bits)
__global__ __launch_bounds__(256) void scatter_kernel(const int* __restrict__ src,
                                                      const int* __restrict__ dst,
                                                      const float* __restrict__ w,
                                                      int* __restrict__ cursor,
                                                      int2* __restrict__ sedge) {
    int e = blockIdx.x * 256 + threadIdx.x;
    if (e < N_EDGES) {
        int d = dst[e];
        int idx = atomicAdd(&cursor[d], 1);
        sedge[idx] = make_int2(src[e], __float_as_int(w[e]));
    }
}

// ---------------- Aggregations (gather; 4 waves/block, 1 node/wave) ----------------

// d=64: half-wave per edge (32 lanes x 2 dims via dword), 8-edge unroll -> 4 gathers in flight
__global__ __launch_bounds__(256) void agg64_kernel(const unsigned* __restrict__ xb32,
                                                    const int* __restrict__ row_off,
                                                    const int2* __restrict__ sedge,
                                                    const float* __restrict__ inv_deg,
                                                    unsigned* __restrict__ hn1b32) {
    int tid = threadIdx.x;
    int lane = tid & 63;
    int half = lane >> 5;
    int l31 = lane & 31;
    int n = blockIdx.x * 4 + (tid >> 6);
    if (n >= N_NODES) return;
    int e0 = row_off[n], e1 = row_off[n + 1];
    float ax = 0.f, ay = 0.f;
    int e = e0;
    for (; e + 8 <= e1; e += 8) {
        int2 m0 = sedge[e + half];
        int2 m1 = sedge[e + 2 + half];
        int2 m2 = sedge[e + 4 + half];
        int2 m3 = sedge[e + 6 + half];
        unsigned p0 = xb32[m0.x * 32 + l31];
        unsigned p1 = xb32[m1.x * 32 + l31];
        unsigned p2 = xb32[m2.x * 32 + l31];
        unsigned p3 = xb32[m3.x * 32 + l31];
        float w0 = __int_as_float(m0.y), w1 = __int_as_float(m1.y);
        float w2 = __int_as_float(m2.y), w3 = __int_as_float(m3.y);
        ax += w0 * blo(p0) + w1 * blo(p1) + w2 * blo(p2) + w3 * blo(p3);
        ay += w0 * bhi(p0) + w1 * bhi(p1) + w2 * bhi(p2) + w3 * bhi(p3);
    }
    for (; e < e1; e += 2) {
        int ee = e + half;
        if (ee < e1) {
            int2 m = sedge[ee];
            unsigned p = xb32[m.x * 32 + l31];
            float w = __int_as_float(m.y);
            ax += w * blo(p);
            ay += w * bhi(p);
        }
    }
    ax += __shfl_xor(ax, 32, 64);
    ay += __shfl_xor(ay, 32, 64);
    if (half == 0) {
        float id = inv_deg[n];
        hn1b32[n * 32 + l31] = (unsigned)f2b(ax * id) | ((unsigned)f2b(ay * id) << 16);
    }
}

// d=128: full wave per edge (2 dims/lane), 4-edge unroll -> 4 gathers in flight
__global__ __launch_bounds__(256) void agg128_kernel(const unsigned* __restrict__ zb32,
                                                     const int* __restrict__ row_off,
                                                     const int2* __restrict__ sedge,
                                                     const float* __restrict__ inv_deg,
                                                     float* __restrict__ emb,
                                                     unsigned* __restrict__ embb32) {
    int tid = threadIdx.x;
    int lane = tid & 63;
    int n = blockIdx.x * 4 + (tid >> 6);
    if (n >= N_NODES) return;
    int e0 = row_off[n], e1 = row_off[n + 1];
    float ax = 0.f, ay = 0.f;
    int e = e0;
    for (; e + 4 <= e1; e += 4) {
        int2 m0 = sedge[e + 0];
        int2 m1 = sedge[e + 1];
        int2 m2 = sedge[e + 2];
        int2 m3 = sedge[e + 3];
        unsigned p0 = zb32[m0.x * 64 + lane];
        unsigned p1 = zb32[m1.x * 64 + lane];
        unsigned p2 = zb32[m2.x * 64 + lane];
        unsigned p3 = zb32[m3.x * 64 + lane];
        float w0 = __int_as_float(m0.y), w1 = __int_as_float(m1.y);
        float w2 = __int_as_float(m2.y), w3 = __int_as_float(m3.y);
        ax += w0 * blo(p0) + w1 * blo(p1) + w2 * blo(p2) + w3 * blo(p3);
        ay += w0 * bhi(p0) + w1 * bhi(p1) + w2 * bhi(p2) + w3 * bhi(p3);
    }
    for (; e < e1; e++) {
        int2 m = sedge[e];
        unsigned p = zb32[m.x * 64 + lane];
        float w = __int_as_float(m.y);
        ax += w * blo(p);
        ay += w * bhi(p);
    }
    float id = inv_deg[n];
    float2 self = ((const float2*)emb)[n * 64 + lane];
    float vx = self.x + ax * id;
    float vy = self.y + ay * id;
    ((float2*)emb)[n * 64 + lane] = make_float2(vx, vy);
    embb32[n * 64 + lane] = (unsigned)f2b(vx) | ((unsigned)f2b(vy) << 16);
}

// ---------------- MFMA GEMMs: one wave per 16-row m-tile ----------------

__global__ __launch_bounds__(256) void gemm1_mfma(const unsigned short* __restrict__ xb,
                                                  const unsigned short* __restrict__ hn1b,
                                                  const unsigned short* __restrict__ Bp,
                                                  const float* __restrict__ b1,
                                                  unsigned short* __restrict__ x1b) {
    int tid = threadIdx.x;
    int lane = tid & 63;
    int wv = tid >> 6;
    int mt = blockIdx.x * 4 + wv;
    if (mt >= MT_TILES) mt = MT_TILES - 1;  // dup wave, benign same-value stores
    int r0 = mt * 16;
    int row = r0 + (lane & 15);
    int q = lane >> 4;
    const unsigned short* xrow = xb + row * 64 + q * 8;
    const unsigned short* hrow = hn1b + row * 64 + q * 8;
    const frag_ab* bp = (const frag_ab*)Bp;
    frag_cd acc[16];
    #pragma unroll
    for (int nt = 0; nt < 16; nt++) acc[nt] = (frag_cd){0.f, 0.f, 0.f, 0.f};
    #pragma unroll
    for (int kt = 0; kt < 4; kt++) {
        const unsigned short* ap = (kt < 2) ? (xrow + kt * 32) : (hrow + (kt - 2) * 32);
        frag_ab a = *(const frag_ab*)ap;
        #pragma unroll
        for (int nt = 0; nt < 16; nt++) {
            frag_ab b = bp[(kt * 16 + nt) * 64 + lane];
            acc[nt] = __builtin_amdgcn_mfma_f32_16x16x32_bf16(a, b, acc[nt], 0, 0, 0);
        }
    }
    int col = lane & 15;
    #pragma unroll
    for (int nt = 0; nt < 16; nt++) {
        int c = nt * 16 + col;
        float bias = b1[c];
        #pragma unroll
        for (int i = 0; i < 4; i++) {
            int r = r0 + q * 4 + i;
            float v = acc[nt][i] + bias;
            v = v > 0.f ? v : 0.f;
            x1b[r * 256 + c] = f2b(v);
        }
    }
}

__global__ __launch_bounds__(256) void gemm2_mfma(const unsigned short* __restrict__ x1b,
                                                  const unsigned short* __restrict__ Bp,
                                                  const float* __restrict__ b2,
                                                  float* __restrict__ emb,
                                                  unsigned short* __restrict__ zb) {
    int tid = threadIdx.x;
    int lane = tid & 63;
    int wv = tid >> 6;
    int mt = blockIdx.x * 4 + wv;
    if (mt >= MT_TILES) mt = MT_TILES - 1;
    int r0 = mt * 16;
    int row = r0 + (lane & 15);
    int q = lane >> 4;
    const unsigned short* arow = x1b + row * 256 + q * 8;
    const frag_ab* bp = (const frag_ab*)Bp;
    frag_cd acc[16];
    #pragma unroll
    for (int nt = 0; nt < 16; nt++) acc[nt] = (frag_cd){0.f, 0.f, 0.f, 0.f};
    #pragma unroll
    for (int kt = 0; kt < 8; kt++) {
        frag_ab a = *(const frag_ab*)(arow + kt * 32);
        #pragma unroll
        for (int nt = 0; nt < 16; nt++) {
            frag_ab b = bp[(kt * 16 + nt) * 64 + lane];
            acc[nt] = __builtin_amdgcn_mfma_f32_16x16x32_bf16(a, b, acc[nt], 0, 0, 0);
        }
    }
    int col = lane & 15;
    #pragma unroll
    for (int nt = 0; nt < 8; nt++) {
        int c = nt * 16 + col;
        float bias = b2[c];
        #pragma unroll
        for (int i = 0; i < 4; i++) {
            int r = r0 + q * 4 + i;
            emb[r * 128 + c] = acc[nt][i] + bias;
        }
    }
    #pragma unroll
    for (int nt = 8; nt < 16; nt++) {
        int c = (nt - 8) * 16 + col;
        #pragma unroll
        for (int i = 0; i < 4; i++) {
            int r = r0 + q * 4 + i;
            zb[r * 128 + c] = f2b(acc[nt][i]);
        }
    }
}

__global__ __launch_bounds__(256) void mlp1_mfma(const unsigned short* __restrict__ embb,
                                                 const unsigned short* __restrict__ Bp,
                                                 const float* __restrict__ bl1,
                                                 unsigned short* __restrict__ h64b) {
    int tid = threadIdx.x;
    int lane = tid & 63;
    int wv = tid >> 6;
    int mt = blockIdx.x * 4 + wv;
    if (mt >= MT_TILES) mt = MT_TILES - 1;
    int r0 = mt * 16;
    int row = r0 + (lane & 15);
    int q = lane >> 4;
    const unsigned short* arow = embb + row * 128 + q * 8;
    const frag_ab* bp = (const frag_ab*)Bp;
    frag_cd acc[4];
    #pragma unroll
    for (int nt = 0; nt < 4; nt++) acc[nt] = (frag_cd){0.f, 0.f, 0.f, 0.f};
    #pragma unroll
    for (int kt = 0; kt < 4; kt++) {
        frag_ab a = *(const frag_ab*)(arow + kt * 32);
        #pragma unroll
        for (int nt = 0; nt < 4; nt++) {
            frag_ab b = bp[(kt * 4 + nt) * 64 + lane];
            acc[nt] = __builtin_amdgcn_mfma_f32_16x16x32_bf16(a, b, acc[nt], 0, 0, 0);
        }
    }
    int col = lane & 15;
    #pragma unroll
    for (int nt = 0; nt < 4; nt++) {
        int c = nt * 16 + col;
        float bias = bl1[c];
        #pragma unroll
        for (int i = 0; i < 4; i++) {
            int r = r0 + q * 4 + i;
            float v = acc[nt][i] + bias;
            v = v > 0.f ? v : 0.f;
            h64b[r * 64 + c] = f2b(v);
        }
    }
}

__global__ __launch_bounds__(256) void mlp2_mfma(const unsigned short* __restrict__ h64b,
                                                 const unsigned short* __restrict__ Bp,
                                                 const float* __restrict__ bl2,
                                                 float* __restrict__ h32) {
    int tid = threadIdx.x;
    int lane = tid & 63;
    int wv = tid >> 6;
    int mt = blockIdx.x * 4 + wv;
    if (mt >= MT_TILES) mt = MT_TILES - 1;
    int r0 = mt * 16;
    int row = r0 + (lane & 15);
    int q = lane >> 4;
    const unsigned short* arow = h64b + row * 64 + q * 8;
    const frag_ab* bp = (const frag_ab*)Bp;
    frag_cd acc[2];
    #pragma unroll
    for (int nt = 0; nt < 2; nt++) acc[nt] = (frag_cd){0.f, 0.f, 0.f, 0.f};
    #pragma unroll
    for (int kt = 0; kt < 2; kt++) {
        frag_ab a = *(const frag_ab*)(arow + kt * 32);
        #pragma unroll
        for (int nt = 0; nt < 2; nt++) {
            frag_ab b = bp[(kt * 2 + nt) * 64 + lane];
            acc[nt] = __builtin_amdgcn_mfma_f32_16x16x32_bf16(a, b, acc[nt], 0, 0, 0);
        }
    }
    int col = lane & 15;
    #pragma unroll
    for (int nt = 0; nt < 2; nt++) {
        int c = nt * 16 + col;
        float bias = bl2[c];
        #pragma unroll
        for (int i = 0; i < 4; i++) {
            int r = r0 + q * 4 + i;
            float v = acc[nt][i] + bias;
            h32[r * 32 + c] = v > 0.f ? v : 0.f;
        }
    }
}

__global__ __launch_bounds__(320) void mlp3_kernel(const float* __restrict__ h32,
                                                   const float* __restrict__ W,
                                                   const float* __restrict__ b,
                                                   float* __restrict__ out) {
    int tid = threadIdx.x;
    int nl = tid / 10;
    int j = tid - nl * 10;
    int n = blockIdx.x * 32 + nl;
    if (n >= N_NODES) return;
    float acc = b[j];
    #pragma unroll
    for (int k = 0; k < 32; k++) acc += h32[n * 32 + k] * W[k * 10 + j];
    out[n * 10 + j] = acc;
}

// ---------------- launch ----------------

extern "C" void kernel_launch(void* const* d_in, const int* in_sizes, int n_in,
                              void* d_out, int out_size, void* d_ws, size_t ws_size,
                              hipStream_t stream) {
    const float* x   = (const float*)d_in[0];
    const int* esrc  = (const int*)d_in[1];
    const int* edst  = (const int*)d_in[2];
    const float* ew  = (const float*)d_in[3];
    const float* W1s = (const float*)d_in[4];
    const float* W1n = (const float*)d_in[5];
    const float* b1  = (const float*)d_in[6];
    const float* W2s = (const float*)d_in[7];
    const float* W2n = (const float*)d_in[8];
    const float* b2  = (const float*)d_in[9];
    const float* Wl1 = (const float*)d_in[10];
    const float* bl1 = (const float*)d_in[11];
    const float* Wl2 = (const float*)d_in[12];
    const float* bl2 = (const float*)d_in[13];
    const float* Wl3 = (const float*)d_in[14];
    const float* bl3 = (const float*)d_in[15];

    float* out = (float*)d_out;       // [50000,10]
    float* emb = out + 500000;        // [50000,128] output 1

    char* ws = (char*)d_ws;
    size_t off = 0;
    auto alloc = [&](size_t bytes) -> void* {
        void* p = ws + off;
        off = (off + bytes + 255) & ~(size_t)255;
        return p;
    };
    int*   deg     = (int*)alloc((size_t)N_NODES * 4);
    int*   cursor  = (int*)alloc((size_t)N_NODES * 4);
    int*   row_off = (int*)alloc((size_t)(N_NODES + 1) * 4);
    float* inv_deg = (float*)alloc((size_t)N_NODES * 4);
    int*   bsum    = (int*)alloc(256 * 4);
    int*   boff    = (int*)alloc(256 * 4);
    int2*  sedge   = (int2*)alloc((size_t)N_EDGES * 8);
    unsigned short* xb   = (unsigned short*)alloc((size_t)N_NODES * 64 * 2);
    unsigned short* hn1b = (unsigned short*)alloc((size_t)N_NODES * 64 * 2);
    unsigned short* x1b  = (unsigned short*)alloc((size_t)N_NODES * 256 * 2);
    unsigned short* zb   = (unsigned short*)alloc((size_t)N_NODES * 128 * 2);
    unsigned short* embb = (unsigned short*)alloc((size_t)N_NODES * 128 * 2);
    unsigned short* h64b = (unsigned short*)alloc((size_t)N_NODES * 64 * 2);
    float* h32           = (float*)alloc((size_t)N_NODES * 32 * 4);
    unsigned short* B1p  = (unsigned short*)alloc(128 * 256 * 2);
    unsigned short* B2p  = (unsigned short*)alloc(256 * 256 * 2);
    unsigned short* Bl1p = (unsigned short*)alloc(128 * 64 * 2);
    unsigned short* Bl2p = (unsigned short*)alloc(64 * 32 * 2);

    hipMemsetAsync(deg, 0, (size_t)N_NODES * 4, stream);

    // fused cvt + weight packing (independent of CSR)
    prep_kernel<<<PREP_S4 / 256, 256, 0, stream>>>((const float4*)x, (ushort4*)xb,
                                                   W1s, W1n, W2s, W2n, Wl1, Wl2,
                                                   B1p, B2p, Bl1p, Bl2p);

    // CSR build
    hist_kernel<<<(N_EDGES + 255) / 256, 256, 0, stream>>>(edst, deg);
    bsum_kernel<<<NB_SCAN, 256, 0, stream>>>(deg, bsum);
    scanb_kernel<<<1, 256, 0, stream>>>(bsum, boff, row_off);
    rowoff_kernel<<<NB_SCAN, 256, 0, stream>>>(deg, boff, row_off, inv_deg, cursor);
    scatter_kernel<<<(N_EDGES + 255) / 256, 256, 0, stream>>>(esrc, edst, ew, cursor,
                                                              sedge);

    const int GBLK = (MT_TILES + 3) / 4;   // 782
    const int ABLK = (N_NODES + 3) / 4;    // 12500

    // layer 1
    agg64_kernel<<<ABLK, 256, 0, stream>>>((const unsigned*)xb, row_off, sedge,
                                           inv_deg, (unsigned*)hn1b);
    gemm1_mfma<<<GBLK, 256, 0, stream>>>(xb, hn1b, B1p, b1, x1b);

    // layer 2: GEMM first (self + z), then aggregate z in 128-dim
    gemm2_mfma<<<GBLK, 256, 0, stream>>>(x1b, B2p, b2, emb, zb);
    agg128_kernel<<<ABLK, 256, 0, stream>>>((const unsigned*)zb, row_off, sedge,
                                            inv_deg, emb, (unsigned*)embb);

    // MLP head
    mlp1_mfma<<<GBLK, 256, 0, stream>>>(embb, Bl1p, bl1, h64b);
    mlp2_mfma<<<GBLK, 256, 0, stream>>>(h64b, Bl2p, bl2, h32);
    mlp3_kernel<<<(N_NODES + 31) / 32, 320, 0, stream>>>(h32, Wl3, bl3, out);
}

// Round 5
// 312.115 us; speedup vs baseline: 2.5839x; 1.0829x over previous
//
#include <hip/hip_runtime.h>
#include <hip/hip_bf16.h>

#define N_NODES 50000
#define N_EDGES 800000
#define MT_TILES 3125   // 50000 / 16

#define NBLK_SORT 200
#define CHUNK_SORT 4000   // NBLK_SORT * CHUNK_SORT == N_EDGES
#define NBKT 196          // ceil(50000 / 256)

typedef __attribute__((ext_vector_type(8))) short frag_ab;   // 8 bf16 (4 VGPRs)
typedef __attribute__((ext_vector_type(4))) float frag_cd;   // 4 fp32 acc

static __device__ __forceinline__ unsigned short f2b(float f) {
    union { float f; unsigned u; } v; v.f = f;
    unsigned r = v.u + 0x7fffu + ((v.u >> 16) & 1u);  // RNE
    return (unsigned short)(r >> 16);
}
static __device__ __forceinline__ float b2f(unsigned short b) {
    union { float f; unsigned u; } v; v.u = ((unsigned)b) << 16;
    return v.f;
}
static __device__ __forceinline__ float blo(unsigned p) { return b2f((unsigned short)(p & 0xffffu)); }
static __device__ __forceinline__ float bhi(unsigned p) { return b2f((unsigned short)(p >> 16)); }

// ---------------- fused prep: cvt x -> bf16, pack all weights ----------------
static __device__ __forceinline__ unsigned short packBK_elem(const float* __restrict__ Wa,
                                                             const float* __restrict__ Wb,
                                                             int Ka, int N, int idx) {
    int j = idx & 7;
    int lane = (idx >> 3) & 63;
    int rest = idx >> 9;
    int ntiles = N >> 4;
    int nt = rest % ntiles;
    int kt = rest / ntiles;
    int kk = kt * 32 + (lane >> 4) * 8 + j;
    int nn = nt * 16 + (lane & 15);
    float v = (kk < Ka) ? Wa[kk * N + nn] : Wb[(kk - Ka) * N + nn];
    return f2b(v);
}
static __device__ __forceinline__ unsigned short packBN_elem(const float* __restrict__ Wa,
                                                             const float* __restrict__ Wb,
                                                             int Na, int N, int idx) {
    int j = idx & 7;
    int lane = (idx >> 3) & 63;
    int rest = idx >> 9;
    int ntiles = N >> 4;
    int nt = rest % ntiles;
    int kt = rest / ntiles;
    int kk = kt * 32 + (lane >> 4) * 8 + j;
    int nn = nt * 16 + (lane & 15);
    float v = (nn < Na) ? Wa[kk * Na + nn] : Wb[kk * (N - Na) + (nn - Na)];
    return f2b(v);
}

#define PREP_S0 800000                 // cvt: ushort4 items (N_NODES*64/4)
#define PREP_S1 (PREP_S0 + 32768)      // B1p  128x256
#define PREP_S2 (PREP_S1 + 65536)      // B2p  256x256
#define PREP_S3 (PREP_S2 + 8192)       // Bl1p 128x64
#define PREP_S4 (PREP_S3 + 2048)       // Bl2p 64x32   -> total 908544 = 3549*256

__global__ __launch_bounds__(256) void prep_kernel(const float4* __restrict__ x4,
                                                   ushort4* __restrict__ xb4,
                                                   const float* __restrict__ W1s,
                                                   const float* __restrict__ W1n,
                                                   const float* __restrict__ W2s,
                                                   const float* __restrict__ W2n,
                                                   const float* __restrict__ Wl1,
                                                   const float* __restrict__ Wl2,
                                                   unsigned short* __restrict__ B1p,
                                                   unsigned short* __restrict__ B2p,
                                                   unsigned short* __restrict__ Bl1p,
                                                   unsigned short* __restrict__ Bl2p) {
    int idx = blockIdx.x * 256 + threadIdx.x;
    if (idx < PREP_S0) {
        float4 v = x4[idx];
        ushort4 o;
        o.x = f2b(v.x); o.y = f2b(v.y); o.z = f2b(v.z); o.w = f2b(v.w);
        xb4[idx] = o;
    } else if (idx < PREP_S1) {
        int i = idx - PREP_S0;
        B1p[i] = packBK_elem(W1s, W1n, 64, 256, i);
    } else if (idx < PREP_S2) {
        int i = idx - PREP_S1;
        B2p[i] = packBN_elem(W2s, W2n, 128, 256, i);
    } else if (idx < PREP_S3) {
        int i = idx - PREP_S2;
        Bl1p[i] = packBK_elem(Wl1, Wl1, 128, 64, i);
    } else if (idx < PREP_S4) {
        int i = idx - PREP_S3;
        Bl2p[i] = packBK_elem(Wl2, Wl2, 64, 32, i);
    }
}

// ---------------- CSR build: 2-level counting sort, no global atomics ----------------

// P1: per-block bucket histogram (bucket = dst >> 8)
__global__ __launch_bounds__(256) void p1_hist(const int* __restrict__ dst,
                                               int* __restrict__ G) {
    __shared__ int h[256];
    int t = threadIdx.x;
    h[t] = 0;
    __syncthreads();
    int base = blockIdx.x * CHUNK_SORT;
    for (int i = t; i < CHUNK_SORT; i += 256) {
        atomicAdd(&h[dst[base + i] >> 8], 1);
    }
    __syncthreads();
    G[blockIdx.x * 256 + t] = h[t];
}

// P2: column-wise scan of G (per-block,bucket -> global offsets) + bucket_off
__global__ __launch_bounds__(256) void p2_scan(int* __restrict__ G,
                                               int* __restrict__ bucket_off,
                                               int* __restrict__ row_off) {
    int t = threadIdx.x;
    int s = 0;
    for (int blk = 0; blk < NBLK_SORT; blk++) {
        int v = G[blk * 256 + t];
        G[blk * 256 + t] = s;  // within-bucket prefix across blocks
        s += v;
    }
    __shared__ int sc[256];
    sc[t] = s;
    __syncthreads();
    for (int off = 1; off < 256; off <<= 1) {
        int add = (t >= off) ? sc[t - off] : 0;
        __syncthreads();
        sc[t] += add;
        __syncthreads();
    }
    int boff = sc[t] - s;  // exclusive bucket offset
    if (t <= NBKT) bucket_off[t] = boff;
    if (t == 255) row_off[N_NODES] = sc[255];  // == N_EDGES
    for (int blk = 0; blk < NBLK_SORT; blk++) {
        G[blk * 256 + t] += boff;
    }
}

// P3: scatter edges into bucket-grouped arrays via LDS cursors
__global__ __launch_bounds__(256) void p3_scatter(const int* __restrict__ src,
                                                  const int* __restrict__ dst,
                                                  const float* __restrict__ w,
                                                  const int* __restrict__ G,
                                                  int* __restrict__ bdst,
                                                  int2* __restrict__ bsedge) {
    __shared__ int cur[256];
    int t = threadIdx.x;
    cur[t] = G[blockIdx.x * 256 + t];
    __syncthreads();
    int base = blockIdx.x * CHUNK_SORT;
    for (int i = t; i < CHUNK_SORT; i += 256) {
        int e = base + i;
        int d = dst[e];
        int pos = atomicAdd(&cur[d >> 8], 1);
        bdst[pos] = d;
        bsedge[pos] = make_int2(src[e], __float_as_int(w[e]));
    }
}

// P4: one block per bucket — LDS counting sort by dst, emit row_off/inv_deg/sedge
__global__ __launch_bounds__(256) void p4_sort(const int* __restrict__ bucket_off,
                                               const int* __restrict__ bdst,
                                               const int2* __restrict__ bsedge,
                                               int* __restrict__ row_off,
                                               float* __restrict__ inv_deg,
                                               int2* __restrict__ sedge) {
    __shared__ int lcnt[256];
    __shared__ int lcur[256];
    __shared__ int sc[256];
    int t = threadIdx.x;
    int b = blockIdx.x;
    int e0 = bucket_off[b], e1 = bucket_off[b + 1];
    int d0 = b << 8;
    lcnt[t] = 0;
    __syncthreads();
    for (int e = e0 + t; e < e1; e += 256)
        atomicAdd(&lcnt[bdst[e] - d0], 1);
    __syncthreads();
    int v = lcnt[t];
    sc[t] = v;
    __syncthreads();
    for (int off = 1; off < 256; off <<= 1) {
        int add = (t >= off) ? sc[t - off] : 0;
        __syncthreads();
        sc[t] += add;
        __syncthreads();
    }
    int loff = e0 + sc[t] - v;  // exclusive, global
    lcur[t] = loff;
    int d = d0 + t;
    if (d < N_NODES) {
        row_off[d] = loff;
        inv_deg[d] = 1.0f / (float)(v > 0 ? v : 1);
    }
    __syncthreads();
    for (int e = e0 + t; e < e1; e += 256) {
        int dd = bdst[e];
        int2 sv = bsedge[e];
        int pos = atomicAdd(&lcur[dd - d0], 1);
        sedge[pos] = sv;
    }
}

// ---------------- Aggregations (gather; 4 waves/block, 1 node/wave) ----------------

// d=64: half-wave per edge (32 lanes x 2 dims via dword), 8-edge unroll
__global__ __launch_bounds__(256) void agg64_kernel(const unsigned* __restrict__ xb32,
                                                    const int* __restrict__ row_off,
                                                    const int2* __restrict__ sedge,
                                                    const float* __restrict__ inv_deg,
                                                    unsigned* __restrict__ hn1b32) {
    int tid = threadIdx.x;
    int lane = tid & 63;
    int half = lane >> 5;
    int l31 = lane & 31;
    int n = blockIdx.x * 4 + (tid >> 6);
    if (n >= N_NODES) return;
    int e0 = row_off[n], e1 = row_off[n + 1];
    float ax = 0.f, ay = 0.f;
    int e = e0;
    for (; e + 8 <= e1; e += 8) {
        int2 m0 = sedge[e + half];
        int2 m1 = sedge[e + 2 + half];
        int2 m2 = sedge[e + 4 + half];
        int2 m3 = sedge[e + 6 + half];
        unsigned p0 = xb32[m0.x * 32 + l31];
        unsigned p1 = xb32[m1.x * 32 + l31];
        unsigned p2 = xb32[m2.x * 32 + l31];
        unsigned p3 = xb32[m3.x * 32 + l31];
        float w0 = __int_as_float(m0.y), w1 = __int_as_float(m1.y);
        float w2 = __int_as_float(m2.y), w3 = __int_as_float(m3.y);
        ax += w0 * blo(p0) + w1 * blo(p1) + w2 * blo(p2) + w3 * blo(p3);
        ay += w0 * bhi(p0) + w1 * bhi(p1) + w2 * bhi(p2) + w3 * bhi(p3);
    }
    for (; e < e1; e += 2) {
        int ee = e + half;
        if (ee < e1) {
            int2 m = sedge[ee];
            unsigned p = xb32[m.x * 32 + l31];
            float w = __int_as_float(m.y);
            ax += w * blo(p);
            ay += w * bhi(p);
        }
    }
    ax += __shfl_xor(ax, 32, 64);
    ay += __shfl_xor(ay, 32, 64);
    if (half == 0) {
        float id = inv_deg[n];
        hn1b32[n * 32 + l31] = (unsigned)f2b(ax * id) | ((unsigned)f2b(ay * id) << 16);
    }
}

// d=128: full wave per edge (2 dims/lane), 4-edge unroll
__global__ __launch_bounds__(256) void agg128_kernel(const unsigned* __restrict__ zb32,
                                                     const int* __restrict__ row_off,
                                                     const int2* __restrict__ sedge,
                                                     const float* __restrict__ inv_deg,
                                                     float* __restrict__ emb,
                                                     unsigned* __restrict__ embb32) {
    int tid = threadIdx.x;
    int lane = tid & 63;
    int n = blockIdx.x * 4 + (tid >> 6);
    if (n >= N_NODES) return;
    int e0 = row_off[n], e1 = row_off[n + 1];
    float ax = 0.f, ay = 0.f;
    int e = e0;
    for (; e + 4 <= e1; e += 4) {
        int2 m0 = sedge[e + 0];
        int2 m1 = sedge[e + 1];
        int2 m2 = sedge[e + 2];
        int2 m3 = sedge[e + 3];
        unsigned p0 = zb32[m0.x * 64 + lane];
        unsigned p1 = zb32[m1.x * 64 + lane];
        unsigned p2 = zb32[m2.x * 64 + lane];
        unsigned p3 = zb32[m3.x * 64 + lane];
        float w0 = __int_as_float(m0.y), w1 = __int_as_float(m1.y);
        float w2 = __int_as_float(m2.y), w3 = __int_as_float(m3.y);
        ax += w0 * blo(p0) + w1 * blo(p1) + w2 * blo(p2) + w3 * blo(p3);
        ay += w0 * bhi(p0) + w1 * bhi(p1) + w2 * bhi(p2) + w3 * bhi(p3);
    }
    for (; e < e1; e++) {
        int2 m = sedge[e];
        unsigned p = zb32[m.x * 64 + lane];
        float w = __int_as_float(m.y);
        ax += w * blo(p);
        ay += w * bhi(p);
    }
    float id = inv_deg[n];
    float2 self = ((const float2*)emb)[n * 64 + lane];
    float vx = self.x + ax * id;
    float vy = self.y + ay * id;
    ((float2*)emb)[n * 64 + lane] = make_float2(vx, vy);
    embb32[n * 64 + lane] = (unsigned)f2b(vx) | ((unsigned)f2b(vy) << 16);
}

// ---------------- MFMA GEMMs: one wave per 16-row m-tile ----------------

__global__ __launch_bounds__(256) void gemm1_mfma(const unsigned short* __restrict__ xb,
                                                  const unsigned short* __restrict__ hn1b,
                                                  const unsigned short* __restrict__ Bp,
                                                  const float* __restrict__ b1,
                                                  unsigned short* __restrict__ x1b) {
    int tid = threadIdx.x;
    int lane = tid & 63;
    int wv = tid >> 6;
    int mt = blockIdx.x * 4 + wv;
    if (mt >= MT_TILES) mt = MT_TILES - 1;  // dup wave, benign same-value stores
    int r0 = mt * 16;
    int row = r0 + (lane & 15);
    int q = lane >> 4;
    const unsigned short* xrow = xb + row * 64 + q * 8;
    const unsigned short* hrow = hn1b + row * 64 + q * 8;
    const frag_ab* bp = (const frag_ab*)Bp;
    frag_cd acc[16];
    #pragma unroll
    for (int nt = 0; nt < 16; nt++) acc[nt] = (frag_cd){0.f, 0.f, 0.f, 0.f};
    #pragma unroll
    for (int kt = 0; kt < 4; kt++) {
        const unsigned short* ap = (kt < 2) ? (xrow + kt * 32) : (hrow + (kt - 2) * 32);
        frag_ab a = *(const frag_ab*)ap;
        #pragma unroll
        for (int nt = 0; nt < 16; nt++) {
            frag_ab b = bp[(kt * 16 + nt) * 64 + lane];
            acc[nt] = __builtin_amdgcn_mfma_f32_16x16x32_bf16(a, b, acc[nt], 0, 0, 0);
        }
    }
    int col = lane & 15;
    #pragma unroll
    for (int nt = 0; nt < 16; nt++) {
        int c = nt * 16 + col;
        float bias = b1[c];
        #pragma unroll
        for (int i = 0; i < 4; i++) {
            int r = r0 + q * 4 + i;
            float v = acc[nt][i] + bias;
            v = v > 0.f ? v : 0.f;
            x1b[r * 256 + c] = f2b(v);
        }
    }
}

__global__ __launch_bounds__(256) void gemm2_mfma(const unsigned short* __restrict__ x1b,
                                                  const unsigned short* __restrict__ Bp,
                                                  const float* __restrict__ b2,
                                                  float* __restrict__ emb,
                                                  unsigned short* __restrict__ zb) {
    int tid = threadIdx.x;
    int lane = tid & 63;
    int wv = tid >> 6;
    int mt = blockIdx.x * 4 + wv;
    if (mt >= MT_TILES) mt = MT_TILES - 1;
    int r0 = mt * 16;
    int row = r0 + (lane & 15);
    int q = lane >> 4;
    const unsigned short* arow = x1b + row * 256 + q * 8;
    const frag_ab* bp = (const frag_ab*)Bp;
    frag_cd acc[16];
    #pragma unroll
    for (int nt = 0; nt < 16; nt++) acc[nt] = (frag_cd){0.f, 0.f, 0.f, 0.f};
    #pragma unroll
    for (int kt = 0; kt < 8; kt++) {
        frag_ab a = *(const frag_ab*)(arow + kt * 32);
        #pragma unroll
        for (int nt = 0; nt < 16; nt++) {
            frag_ab b = bp[(kt * 16 + nt) * 64 + lane];
            acc[nt] = __builtin_amdgcn_mfma_f32_16x16x32_bf16(a, b, acc[nt], 0, 0, 0);
        }
    }
    int col = lane & 15;
    #pragma unroll
    for (int nt = 0; nt < 8; nt++) {
        int c = nt * 16 + col;
        float bias = b2[c];
        #pragma unroll
        for (int i = 0; i < 4; i++) {
            int r = r0 + q * 4 + i;
            emb[r * 128 + c] = acc[nt][i] + bias;
        }
    }
    #pragma unroll
    for (int nt = 8; nt < 16; nt++) {
        int c = (nt - 8) * 16 + col;
        #pragma unroll
        for (int i = 0; i < 4; i++) {
            int r = r0 + q * 4 + i;
            zb[r * 128 + c] = f2b(acc[nt][i]);
        }
    }
}

__global__ __launch_bounds__(256) void mlp1_mfma(const unsigned short* __restrict__ embb,
                                                 const unsigned short* __restrict__ Bp,
                                                 const float* __restrict__ bl1,
                                                 unsigned short* __restrict__ h64b) {
    int tid = threadIdx.x;
    int lane = tid & 63;
    int wv = tid >> 6;
    int mt = blockIdx.x * 4 + wv;
    if (mt >= MT_TILES) mt = MT_TILES - 1;
    int r0 = mt * 16;
    int row = r0 + (lane & 15);
    int q = lane >> 4;
    const unsigned short* arow = embb + row * 128 + q * 8;
    const frag_ab* bp = (const frag_ab*)Bp;
    frag_cd acc[4];
    #pragma unroll
    for (int nt = 0; nt < 4; nt++) acc[nt] = (frag_cd){0.f, 0.f, 0.f, 0.f};
    #pragma unroll
    for (int kt = 0; kt < 4; kt++) {
        frag_ab a = *(const frag_ab*)(arow + kt * 32);
        #pragma unroll
        for (int nt = 0; nt < 4; nt++) {
            frag_ab b = bp[(kt * 4 + nt) * 64 + lane];
            acc[nt] = __builtin_amdgcn_mfma_f32_16x16x32_bf16(a, b, acc[nt], 0, 0, 0);
        }
    }
    int col = lane & 15;
    #pragma unroll
    for (int nt = 0; nt < 4; nt++) {
        int c = nt * 16 + col;
        float bias = bl1[c];
        #pragma unroll
        for (int i = 0; i < 4; i++) {
            int r = r0 + q * 4 + i;
            float v = acc[nt][i] + bias;
            v = v > 0.f ? v : 0.f;
            h64b[r * 64 + c] = f2b(v);
        }
    }
}

__global__ __launch_bounds__(256) void mlp2_mfma(const unsigned short* __restrict__ h64b,
                                                 const unsigned short* __restrict__ Bp,
                                                 const float* __restrict__ bl2,
                                                 float* __restrict__ h32) {
    int tid = threadIdx.x;
    int lane = tid & 63;
    int wv = tid >> 6;
    int mt = blockIdx.x * 4 + wv;
    if (mt >= MT_TILES) mt = MT_TILES - 1;
    int r0 = mt * 16;
    int row = r0 + (lane & 15);
    int q = lane >> 4;
    const unsigned short* arow = h64b + row * 64 + q * 8;
    const frag_ab* bp = (const frag_ab*)Bp;
    frag_cd acc[2];
    #pragma unroll
    for (int nt = 0; nt < 2; nt++) acc[nt] = (frag_cd){0.f, 0.f, 0.f, 0.f};
    #pragma unroll
    for (int kt = 0; kt < 2; kt++) {
        frag_ab a = *(const frag_ab*)(arow + kt * 32);
        #pragma unroll
        for (int nt = 0; nt < 2; nt++) {
            frag_ab b = bp[(kt * 2 + nt) * 64 + lane];
            acc[nt] = __builtin_amdgcn_mfma_f32_16x16x32_bf16(a, b, acc[nt], 0, 0, 0);
        }
    }
    int col = lane & 15;
    #pragma unroll
    for (int nt = 0; nt < 2; nt++) {
        int c = nt * 16 + col;
        float bias = bl2[c];
        #pragma unroll
        for (int i = 0; i < 4; i++) {
            int r = r0 + q * 4 + i;
            float v = acc[nt][i] + bias;
            h32[r * 32 + c] = v > 0.f ? v : 0.f;
        }
    }
}

__global__ __launch_bounds__(320) void mlp3_kernel(const float* __restrict__ h32,
                                                   const float* __restrict__ W,
                                                   const float* __restrict__ b,
                                                   float* __restrict__ out) {
    int tid = threadIdx.x;
    int nl = tid / 10;
    int j = tid - nl * 10;
    int n = blockIdx.x * 32 + nl;
    if (n >= N_NODES) return;
    float acc = b[j];
    #pragma unroll
    for (int k = 0; k < 32; k++) acc += h32[n * 32 + k] * W[k * 10 + j];
    out[n * 10 + j] = acc;
}

// ---------------- launch ----------------

extern "C" void kernel_launch(void* const* d_in, const int* in_sizes, int n_in,
                              void* d_out, int out_size, void* d_ws, size_t ws_size,
                              hipStream_t stream) {
    const float* x   = (const float*)d_in[0];
    const int* esrc  = (const int*)d_in[1];
    const int* edst  = (const int*)d_in[2];
    const float* ew  = (const float*)d_in[3];
    const float* W1s = (const float*)d_in[4];
    const float* W1n = (const float*)d_in[5];
    const float* b1  = (const float*)d_in[6];
    const float* W2s = (const float*)d_in[7];
    const float* W2n = (const float*)d_in[8];
    const float* b2  = (const float*)d_in[9];
    const float* Wl1 = (const float*)d_in[10];
    const float* bl1 = (const float*)d_in[11];
    const float* Wl2 = (const float*)d_in[12];
    const float* bl2 = (const float*)d_in[13];
    const float* Wl3 = (const float*)d_in[14];
    const float* bl3 = (const float*)d_in[15];

    float* out = (float*)d_out;       // [50000,10]
    float* emb = out + 500000;        // [50000,128] output 1

    char* ws = (char*)d_ws;
    size_t off = 0;
    auto alloc = [&](size_t bytes) -> void* {
        void* p = ws + off;
        off = (off + bytes + 255) & ~(size_t)255;
        return p;
    };
    int*   row_off = (int*)alloc((size_t)(N_NODES + 1) * 4);
    float* inv_deg = (float*)alloc((size_t)N_NODES * 4);
    int*   G       = (int*)alloc((size_t)NBLK_SORT * 256 * 4);
    int*   bkt_off = (int*)alloc((size_t)(NBKT + 1) * 4);
    int*   bdst    = (int*)alloc((size_t)N_EDGES * 4);
    int2*  bsedge  = (int2*)alloc((size_t)N_EDGES * 8);
    int2*  sedge   = (int2*)alloc((size_t)N_EDGES * 8);
    unsigned short* xb   = (unsigned short*)alloc((size_t)N_NODES * 64 * 2);
    unsigned short* hn1b = (unsigned short*)alloc((size_t)N_NODES * 64 * 2);
    unsigned short* x1b  = (unsigned short*)alloc((size_t)N_NODES * 256 * 2);
    unsigned short* zb   = (unsigned short*)alloc((size_t)N_NODES * 128 * 2);
    unsigned short* embb = (unsigned short*)alloc((size_t)N_NODES * 128 * 2);
    unsigned short* h64b = (unsigned short*)alloc((size_t)N_NODES * 64 * 2);
    float* h32           = (float*)alloc((size_t)N_NODES * 32 * 4);
    unsigned short* B1p  = (unsigned short*)alloc(128 * 256 * 2);
    unsigned short* B2p  = (unsigned short*)alloc(256 * 256 * 2);
    unsigned short* Bl1p = (unsigned short*)alloc(128 * 64 * 2);
    unsigned short* Bl2p = (unsigned short*)alloc(64 * 32 * 2);

    // fused cvt + weight packing (independent of CSR)
    prep_kernel<<<PREP_S4 / 256, 256, 0, stream>>>((const float4*)x, (ushort4*)xb,
                                                   W1s, W1n, W2s, W2n, Wl1, Wl2,
                                                   B1p, B2p, Bl1p, Bl2p);

    // CSR build via 2-level counting sort (no global atomics)
    p1_hist<<<NBLK_SORT, 256, 0, stream>>>(edst, G);
    p2_scan<<<1, 256, 0, stream>>>(G, bkt_off, row_off);
    p3_scatter<<<NBLK_SORT, 256, 0, stream>>>(esrc, edst, ew, G, bdst, bsedge);
    p4_sort<<<NBKT, 256, 0, stream>>>(bkt_off, bdst, bsedge, row_off, inv_deg, sedge);

    const int GBLK = (MT_TILES + 3) / 4;   // 782
    const int ABLK = (N_NODES + 3) / 4;    // 12500

    // layer 1
    agg64_kernel<<<ABLK, 256, 0, stream>>>((const unsigned*)xb, row_off, sedge,
                                           inv_deg, (unsigned*)hn1b);
    gemm1_mfma<<<GBLK, 256, 0, stream>>>(xb, hn1b, B1p, b1, x1b);

    // layer 2: GEMM first (self + z), then aggregate z in 128-dim
    gemm2_mfma<<<GBLK, 256, 0, stream>>>(x1b, B2p, b2, emb, zb);
    agg128_kernel<<<ABLK, 256, 0, stream>>>((const unsigned*)zb, row_off, sedge,
                                            inv_deg, emb, (unsigned*)embb);

    // MLP head
    mlp1_mfma<<<GBLK, 256, 0, stream>>>(embb, Bl1p, bl1, h64b);
    mlp2_mfma<<<GBLK, 256, 0, stream>>>(h64b, Bl2p, bl2, h32);
    mlp3_kernel<<<(N_NODES + 31) / 32, 320, 0, stream>>>(h32, Wl3, bl3, out);
}

// Round 6
// 310.677 us; speedup vs baseline: 2.5958x; 1.0046x over previous
//
#include <hip/hip_runtime.h>
#include <hip/hip_bf16.h>

#define N_NODES 50000
#define N_EDGES 800000
#define MT_TILES 3125   // 50000 / 16
#define PR_TILES 1563   // ceil(3125 / 2) wave-pairs (2 m-tiles per wave)

#define NBLK_SORT 200
#define CHUNK_SORT 4000   // NBLK_SORT * CHUNK_SORT == N_EDGES
#define NBKT 196          // ceil(50000 / 256)

typedef __attribute__((ext_vector_type(8))) short frag_ab;   // 8 bf16 (4 VGPRs)
typedef __attribute__((ext_vector_type(4))) float frag_cd;   // 4 fp32 acc

static __device__ __forceinline__ unsigned short f2b(float f) {
    union { float f; unsigned u; } v; v.f = f;
    unsigned r = v.u + 0x7fffu + ((v.u >> 16) & 1u);  // RNE
    return (unsigned short)(r >> 16);
}
static __device__ __forceinline__ float b2f(unsigned short b) {
    union { float f; unsigned u; } v; v.u = ((unsigned)b) << 16;
    return v.f;
}
static __device__ __forceinline__ float blo(unsigned p) { return b2f((unsigned short)(p & 0xffffu)); }
static __device__ __forceinline__ float bhi(unsigned p) { return b2f((unsigned short)(p >> 16)); }

// ---------------- fused prep: cvt x -> bf16, pack all weights ----------------
static __device__ __forceinline__ unsigned short packBK_elem(const float* __restrict__ Wa,
                                                             const float* __restrict__ Wb,
                                                             int Ka, int N, int idx) {
    int j = idx & 7;
    int lane = (idx >> 3) & 63;
    int rest = idx >> 9;
    int ntiles = N >> 4;
    int nt = rest % ntiles;
    int kt = rest / ntiles;
    int kk = kt * 32 + (lane >> 4) * 8 + j;
    int nn = nt * 16 + (lane & 15);
    float v = (kk < Ka) ? Wa[kk * N + nn] : Wb[(kk - Ka) * N + nn];
    return f2b(v);
}
static __device__ __forceinline__ unsigned short packBN_elem(const float* __restrict__ Wa,
                                                             const float* __restrict__ Wb,
                                                             int Na, int N, int idx) {
    int j = idx & 7;
    int lane = (idx >> 3) & 63;
    int rest = idx >> 9;
    int ntiles = N >> 4;
    int nt = rest % ntiles;
    int kt = rest / ntiles;
    int kk = kt * 32 + (lane >> 4) * 8 + j;
    int nn = nt * 16 + (lane & 15);
    float v = (nn < Na) ? Wa[kk * Na + nn] : Wb[kk * (N - Na) + (nn - Na)];
    return f2b(v);
}

#define PREP_S0 800000                 // cvt: ushort4 items (N_NODES*64/4)
#define PREP_S1 (PREP_S0 + 32768)      // B1p  128x256
#define PREP_S2 (PREP_S1 + 65536)      // B2p  256x256
#define PREP_S3 (PREP_S2 + 8192)       // Bl1p 128x64
#define PREP_S4 (PREP_S3 + 2048)       // Bl2p 64x32   -> total 908544 = 3549*256

__global__ __launch_bounds__(256) void prep_kernel(const float4* __restrict__ x4,
                                                   ushort4* __restrict__ xb4,
                                                   const float* __restrict__ W1s,
                                                   const float* __restrict__ W1n,
                                                   const float* __restrict__ W2s,
                                                   const float* __restrict__ W2n,
                                                   const float* __restrict__ Wl1,
                                                   const float* __restrict__ Wl2,
                                                   unsigned short* __restrict__ B1p,
                                                   unsigned short* __restrict__ B2p,
                                                   unsigned short* __restrict__ Bl1p,
                                                   unsigned short* __restrict__ Bl2p) {
    int idx = blockIdx.x * 256 + threadIdx.x;
    if (idx < PREP_S0) {
        float4 v = x4[idx];
        ushort4 o;
        o.x = f2b(v.x); o.y = f2b(v.y); o.z = f2b(v.z); o.w = f2b(v.w);
        xb4[idx] = o;
    } else if (idx < PREP_S1) {
        int i = idx - PREP_S0;
        B1p[i] = packBK_elem(W1s, W1n, 64, 256, i);
    } else if (idx < PREP_S2) {
        int i = idx - PREP_S1;
        B2p[i] = packBN_elem(W2s, W2n, 128, 256, i);
    } else if (idx < PREP_S3) {
        int i = idx - PREP_S2;
        Bl1p[i] = packBK_elem(Wl1, Wl1, 128, 64, i);
    } else if (idx < PREP_S4) {
        int i = idx - PREP_S3;
        Bl2p[i] = packBK_elem(Wl2, Wl2, 64, 32, i);
    }
}

// ---------------- CSR build: 2-level counting sort, no global atomics ----------------

// P1: per-block bucket histogram (bucket = dst >> 8)
__global__ __launch_bounds__(256) void p1_hist(const int* __restrict__ dst,
                                               int* __restrict__ G) {
    __shared__ int h[256];
    int t = threadIdx.x;
    h[t] = 0;
    __syncthreads();
    int base = blockIdx.x * CHUNK_SORT;
    for (int i = t; i < CHUNK_SORT; i += 256) {
        atomicAdd(&h[dst[base + i] >> 8], 1);
    }
    __syncthreads();
    G[blockIdx.x * 256 + t] = h[t];
}

// P2: column-wise scan of G (per-block,bucket -> global offsets) + bucket_off
__global__ __launch_bounds__(256) void p2_scan(int* __restrict__ G,
                                               int* __restrict__ bucket_off,
                                               int* __restrict__ row_off) {
    int t = threadIdx.x;
    int s = 0;
    for (int blk = 0; blk < NBLK_SORT; blk++) {
        int v = G[blk * 256 + t];
        G[blk * 256 + t] = s;  // within-bucket prefix across blocks
        s += v;
    }
    __shared__ int sc[256];
    sc[t] = s;
    __syncthreads();
    for (int off = 1; off < 256; off <<= 1) {
        int add = (t >= off) ? sc[t - off] : 0;
        __syncthreads();
        sc[t] += add;
        __syncthreads();
    }
    int boff = sc[t] - s;  // exclusive bucket offset
    if (t <= NBKT) bucket_off[t] = boff;
    if (t == 255) row_off[N_NODES] = sc[255];  // == N_EDGES
    for (int blk = 0; blk < NBLK_SORT; blk++) {
        G[blk * 256 + t] += boff;
    }
}

// P3: scatter edges into bucket-grouped arrays via LDS cursors
__global__ __launch_bounds__(256) void p3_scatter(const int* __restrict__ src,
                                                  const int* __restrict__ dst,
                                                  const float* __restrict__ w,
                                                  const int* __restrict__ G,
                                                  int* __restrict__ bdst,
                                                  int2* __restrict__ bsedge) {
    __shared__ int cur[256];
    int t = threadIdx.x;
    cur[t] = G[blockIdx.x * 256 + t];
    __syncthreads();
    int base = blockIdx.x * CHUNK_SORT;
    for (int i = t; i < CHUNK_SORT; i += 256) {
        int e = base + i;
        int d = dst[e];
        int pos = atomicAdd(&cur[d >> 8], 1);
        bdst[pos] = d;
        bsedge[pos] = make_int2(src[e], __float_as_int(w[e]));
    }
}

// P4: one block per bucket — LDS counting sort by dst, emit row_off/inv_deg/sedge
__global__ __launch_bounds__(256) void p4_sort(const int* __restrict__ bucket_off,
                                               const int* __restrict__ bdst,
                                               const int2* __restrict__ bsedge,
                                               int* __restrict__ row_off,
                                               float* __restrict__ inv_deg,
                                               int2* __restrict__ sedge) {
    __shared__ int lcnt[256];
    __shared__ int lcur[256];
    __shared__ int sc[256];
    int t = threadIdx.x;
    int b = blockIdx.x;
    int e0 = bucket_off[b], e1 = bucket_off[b + 1];
    int d0 = b << 8;
    lcnt[t] = 0;
    __syncthreads();
    for (int e = e0 + t; e < e1; e += 256)
        atomicAdd(&lcnt[bdst[e] - d0], 1);
    __syncthreads();
    int v = lcnt[t];
    sc[t] = v;
    __syncthreads();
    for (int off = 1; off < 256; off <<= 1) {
        int add = (t >= off) ? sc[t - off] : 0;
        __syncthreads();
        sc[t] += add;
        __syncthreads();
    }
    int loff = e0 + sc[t] - v;  // exclusive, global
    lcur[t] = loff;
    int d = d0 + t;
    if (d < N_NODES) {
        row_off[d] = loff;
        inv_deg[d] = 1.0f / (float)(v > 0 ? v : 1);
    }
    __syncthreads();
    for (int e = e0 + t; e < e1; e += 256) {
        int dd = bdst[e];
        int2 sv = bsedge[e];
        int pos = atomicAdd(&lcur[dd - d0], 1);
        sedge[pos] = sv;
    }
}

// ---------------- Aggregations (gather; 4 waves/block, 1 node/wave) ----------------

// d=64: half-wave per edge (32 lanes x 2 dims via dword), 8-edge unroll
__global__ __launch_bounds__(256) void agg64_kernel(const unsigned* __restrict__ xb32,
                                                    const int* __restrict__ row_off,
                                                    const int2* __restrict__ sedge,
                                                    const float* __restrict__ inv_deg,
                                                    unsigned* __restrict__ hn1b32) {
    int tid = threadIdx.x;
    int lane = tid & 63;
    int half = lane >> 5;
    int l31 = lane & 31;
    int n = blockIdx.x * 4 + (tid >> 6);
    if (n >= N_NODES) return;
    int e0 = row_off[n], e1 = row_off[n + 1];
    float ax = 0.f, ay = 0.f;
    int e = e0;
    for (; e + 8 <= e1; e += 8) {
        int2 m0 = sedge[e + half];
        int2 m1 = sedge[e + 2 + half];
        int2 m2 = sedge[e + 4 + half];
        int2 m3 = sedge[e + 6 + half];
        unsigned p0 = xb32[m0.x * 32 + l31];
        unsigned p1 = xb32[m1.x * 32 + l31];
        unsigned p2 = xb32[m2.x * 32 + l31];
        unsigned p3 = xb32[m3.x * 32 + l31];
        float w0 = __int_as_float(m0.y), w1 = __int_as_float(m1.y);
        float w2 = __int_as_float(m2.y), w3 = __int_as_float(m3.y);
        ax += w0 * blo(p0) + w1 * blo(p1) + w2 * blo(p2) + w3 * blo(p3);
        ay += w0 * bhi(p0) + w1 * bhi(p1) + w2 * bhi(p2) + w3 * bhi(p3);
    }
    for (; e < e1; e += 2) {
        int ee = e + half;
        if (ee < e1) {
            int2 m = sedge[ee];
            unsigned p = xb32[m.x * 32 + l31];
            float w = __int_as_float(m.y);
            ax += w * blo(p);
            ay += w * bhi(p);
        }
    }
    ax += __shfl_xor(ax, 32, 64);
    ay += __shfl_xor(ay, 32, 64);
    if (half == 0) {
        float id = inv_deg[n];
        hn1b32[n * 32 + l31] = (unsigned)f2b(ax * id) | ((unsigned)f2b(ay * id) << 16);
    }
}

// d=128: full wave per edge (2 dims/lane), 4-edge unroll
__global__ __launch_bounds__(256) void agg128_kernel(const unsigned* __restrict__ zb32,
                                                     const int* __restrict__ row_off,
                                                     const int2* __restrict__ sedge,
                                                     const float* __restrict__ inv_deg,
                                                     float* __restrict__ emb,
                                                     unsigned* __restrict__ embb32) {
    int tid = threadIdx.x;
    int lane = tid & 63;
    int n = blockIdx.x * 4 + (tid >> 6);
    if (n >= N_NODES) return;
    int e0 = row_off[n], e1 = row_off[n + 1];
    float ax = 0.f, ay = 0.f;
    int e = e0;
    for (; e + 4 <= e1; e += 4) {
        int2 m0 = sedge[e + 0];
        int2 m1 = sedge[e + 1];
        int2 m2 = sedge[e + 2];
        int2 m3 = sedge[e + 3];
        unsigned p0 = zb32[m0.x * 64 + lane];
        unsigned p1 = zb32[m1.x * 64 + lane];
        unsigned p2 = zb32[m2.x * 64 + lane];
        unsigned p3 = zb32[m3.x * 64 + lane];
        float w0 = __int_as_float(m0.y), w1 = __int_as_float(m1.y);
        float w2 = __int_as_float(m2.y), w3 = __int_as_float(m3.y);
        ax += w0 * blo(p0) + w1 * blo(p1) + w2 * blo(p2) + w3 * blo(p3);
        ay += w0 * bhi(p0) + w1 * bhi(p1) + w2 * bhi(p2) + w3 * bhi(p3);
    }
    for (; e < e1; e++) {
        int2 m = sedge[e];
        unsigned p = zb32[m.x * 64 + lane];
        float w = __int_as_float(m.y);
        ax += w * blo(p);
        ay += w * bhi(p);
    }
    float id = inv_deg[n];
    float2 self = ((const float2*)emb)[n * 64 + lane];
    float vx = self.x + ax * id;
    float vy = self.y + ay * id;
    ((float2*)emb)[n * 64 + lane] = make_float2(vx, vy);
    embb32[n * 64 + lane] = (unsigned)f2b(vx) | ((unsigned)f2b(vy) << 16);
}

// ---------------- MFMA GEMMs: 2 m-tiles (32 rows) per wave, B-frag reuse x2 ----------------

// x1b = bf16(relu([xb|hn1b] @ [W1s;W1n] + b1))   K=128, N=256
__global__ __launch_bounds__(256) void gemm1_mfma(const unsigned short* __restrict__ xb,
                                                  const unsigned short* __restrict__ hn1b,
                                                  const unsigned short* __restrict__ Bp,
                                                  const float* __restrict__ b1,
                                                  unsigned short* __restrict__ x1b) {
    int tid = threadIdx.x;
    int lane = tid & 63;
    int wv = tid >> 6;
    int pr = blockIdx.x * 4 + wv;
    if (pr >= PR_TILES) pr = PR_TILES - 1;
    int mt0 = pr * 2;
    int mt1 = mt0 + 1; if (mt1 >= MT_TILES) mt1 = MT_TILES - 1;
    int q = lane >> 4;
    int rl = lane & 15;
    int row0 = mt0 * 16 + rl, row1 = mt1 * 16 + rl;
    const unsigned short* x0 = xb + row0 * 64 + q * 8;
    const unsigned short* x1 = xb + row1 * 64 + q * 8;
    const unsigned short* h0 = hn1b + row0 * 64 + q * 8;
    const unsigned short* h1 = hn1b + row1 * 64 + q * 8;
    const frag_ab* bp = (const frag_ab*)Bp;
    frag_cd acc0[16], acc1[16];
    #pragma unroll
    for (int nt = 0; nt < 16; nt++) {
        acc0[nt] = (frag_cd){0.f, 0.f, 0.f, 0.f};
        acc1[nt] = (frag_cd){0.f, 0.f, 0.f, 0.f};
    }
    #pragma unroll
    for (int kt = 0; kt < 4; kt++) {
        const unsigned short* a0p = (kt < 2) ? (x0 + kt * 32) : (h0 + (kt - 2) * 32);
        const unsigned short* a1p = (kt < 2) ? (x1 + kt * 32) : (h1 + (kt - 2) * 32);
        frag_ab a0 = *(const frag_ab*)a0p;
        frag_ab a1 = *(const frag_ab*)a1p;
        #pragma unroll
        for (int nt = 0; nt < 16; nt++) {
            frag_ab b = bp[(kt * 16 + nt) * 64 + lane];
            acc0[nt] = __builtin_amdgcn_mfma_f32_16x16x32_bf16(a0, b, acc0[nt], 0, 0, 0);
            acc1[nt] = __builtin_amdgcn_mfma_f32_16x16x32_bf16(a1, b, acc1[nt], 0, 0, 0);
        }
    }
    int r0a = mt0 * 16 + q * 4, r0b = mt1 * 16 + q * 4;
    #pragma unroll
    for (int nt = 0; nt < 16; nt++) {
        int c = nt * 16 + rl;
        float bias = b1[c];
        #pragma unroll
        for (int i = 0; i < 4; i++) {
            float v0 = acc0[nt][i] + bias;
            float v1 = acc1[nt][i] + bias;
            x1b[(r0a + i) * 256 + c] = f2b(v0 > 0.f ? v0 : 0.f);
            x1b[(r0b + i) * 256 + c] = f2b(v1 > 0.f ? v1 : 0.f);
        }
    }
}

// self+z: x1b @ [W2s|W2n]; cols 0-127 -> emb fp32 (+b2), cols 128-255 -> zb bf16
__global__ __launch_bounds__(256) void gemm2_mfma(const unsigned short* __restrict__ x1b,
                                                  const unsigned short* __restrict__ Bp,
                                                  const float* __restrict__ b2,
                                                  float* __restrict__ emb,
                                                  unsigned short* __restrict__ zb) {
    int tid = threadIdx.x;
    int lane = tid & 63;
    int wv = tid >> 6;
    int pr = blockIdx.x * 4 + wv;
    if (pr >= PR_TILES) pr = PR_TILES - 1;
    int mt0 = pr * 2;
    int mt1 = mt0 + 1; if (mt1 >= MT_TILES) mt1 = MT_TILES - 1;
    int q = lane >> 4;
    int rl = lane & 15;
    const unsigned short* a0row = x1b + (mt0 * 16 + rl) * 256 + q * 8;
    const unsigned short* a1row = x1b + (mt1 * 16 + rl) * 256 + q * 8;
    const frag_ab* bp = (const frag_ab*)Bp;
    frag_cd acc0[16], acc1[16];
    #pragma unroll
    for (int nt = 0; nt < 16; nt++) {
        acc0[nt] = (frag_cd){0.f, 0.f, 0.f, 0.f};
        acc1[nt] = (frag_cd){0.f, 0.f, 0.f, 0.f};
    }
    #pragma unroll
    for (int kt = 0; kt < 8; kt++) {
        frag_ab a0 = *(const frag_ab*)(a0row + kt * 32);
        frag_ab a1 = *(const frag_ab*)(a1row + kt * 32);
        #pragma unroll
        for (int nt = 0; nt < 16; nt++) {
            frag_ab b = bp[(kt * 16 + nt) * 64 + lane];
            acc0[nt] = __builtin_amdgcn_mfma_f32_16x16x32_bf16(a0, b, acc0[nt], 0, 0, 0);
            acc1[nt] = __builtin_amdgcn_mfma_f32_16x16x32_bf16(a1, b, acc1[nt], 0, 0, 0);
        }
    }
    int r0a = mt0 * 16 + q * 4, r0b = mt1 * 16 + q * 4;
    #pragma unroll
    for (int nt = 0; nt < 8; nt++) {
        int c = nt * 16 + rl;
        float bias = b2[c];
        #pragma unroll
        for (int i = 0; i < 4; i++) {
            emb[(r0a + i) * 128 + c] = acc0[nt][i] + bias;
            emb[(r0b + i) * 128 + c] = acc1[nt][i] + bias;
        }
    }
    #pragma unroll
    for (int nt = 8; nt < 16; nt++) {
        int c = (nt - 8) * 16 + rl;
        #pragma unroll
        for (int i = 0; i < 4; i++) {
            zb[(r0a + i) * 128 + c] = f2b(acc0[nt][i]);
            zb[(r0b + i) * 128 + c] = f2b(acc1[nt][i]);
        }
    }
}

// h64b = bf16(relu(embb @ Wl1 + bl1))   K=128, N=64
__global__ __launch_bounds__(256) void mlp1_mfma(const unsigned short* __restrict__ embb,
                                                 const unsigned short* __restrict__ Bp,
                                                 const float* __restrict__ bl1,
                                                 unsigned short* __restrict__ h64b) {
    int tid = threadIdx.x;
    int lane = tid & 63;
    int wv = tid >> 6;
    int pr = blockIdx.x * 4 + wv;
    if (pr >= PR_TILES) pr = PR_TILES - 1;
    int mt0 = pr * 2;
    int mt1 = mt0 + 1; if (mt1 >= MT_TILES) mt1 = MT_TILES - 1;
    int q = lane >> 4;
    int rl = lane & 15;
    const unsigned short* a0row = embb + (mt0 * 16 + rl) * 128 + q * 8;
    const unsigned short* a1row = embb + (mt1 * 16 + rl) * 128 + q * 8;
    const frag_ab* bp = (const frag_ab*)Bp;
    frag_cd acc0[4], acc1[4];
    #pragma unroll
    for (int nt = 0; nt < 4; nt++) {
        acc0[nt] = (frag_cd){0.f, 0.f, 0.f, 0.f};
        acc1[nt] = (frag_cd){0.f, 0.f, 0.f, 0.f};
    }
    #pragma unroll
    for (int kt = 0; kt < 4; kt++) {
        frag_ab a0 = *(const frag_ab*)(a0row + kt * 32);
        frag_ab a1 = *(const frag_ab*)(a1row + kt * 32);
        #pragma unroll
        for (int nt = 0; nt < 4; nt++) {
            frag_ab b = bp[(kt * 4 + nt) * 64 + lane];
            acc0[nt] = __builtin_amdgcn_mfma_f32_16x16x32_bf16(a0, b, acc0[nt], 0, 0, 0);
            acc1[nt] = __builtin_amdgcn_mfma_f32_16x16x32_bf16(a1, b, acc1[nt], 0, 0, 0);
        }
    }
    int r0a = mt0 * 16 + q * 4, r0b = mt1 * 16 + q * 4;
    #pragma unroll
    for (int nt = 0; nt < 4; nt++) {
        int c = nt * 16 + rl;
        float bias = bl1[c];
        #pragma unroll
        for (int i = 0; i < 4; i++) {
            float v0 = acc0[nt][i] + bias;
            float v1 = acc1[nt][i] + bias;
            h64b[(r0a + i) * 64 + c] = f2b(v0 > 0.f ? v0 : 0.f);
            h64b[(r0b + i) * 64 + c] = f2b(v1 > 0.f ? v1 : 0.f);
        }
    }
}

// h32 = relu(h64b @ Wl2 + bl2)  fp32 out  K=64, N=32
__global__ __launch_bounds__(256) void mlp2_mfma(const unsigned short* __restrict__ h64b,
                                                 const unsigned short* __restrict__ Bp,
                                                 const float* __restrict__ bl2,
                                                 float* __restrict__ h32) {
    int tid = threadIdx.x;
    int lane = tid & 63;
    int wv = tid >> 6;
    int mt = blockIdx.x * 4 + wv;
    if (mt >= MT_TILES) mt = MT_TILES - 1;
    int r0 = mt * 16;
    int row = r0 + (lane & 15);
    int q = lane >> 4;
    const unsigned short* arow = h64b + row * 64 + q * 8;
    const frag_ab* bp = (const frag_ab*)Bp;
    frag_cd acc[2];
    #pragma unroll
    for (int nt = 0; nt < 2; nt++) acc[nt] = (frag_cd){0.f, 0.f, 0.f, 0.f};
    #pragma unroll
    for (int kt = 0; kt < 2; kt++) {
        frag_ab a = *(const frag_ab*)(arow + kt * 32);
        #pragma unroll
        for (int nt = 0; nt < 2; nt++) {
            frag_ab b = bp[(kt * 2 + nt) * 64 + lane];
            acc[nt] = __builtin_amdgcn_mfma_f32_16x16x32_bf16(a, b, acc[nt], 0, 0, 0);
        }
    }
    int col = lane & 15;
    #pragma unroll
    for (int nt = 0; nt < 2; nt++) {
        int c = nt * 16 + col;
        float bias = bl2[c];
        #pragma unroll
        for (int i = 0; i < 4; i++) {
            int r = r0 + q * 4 + i;
            float v = acc[nt][i] + bias;
            h32[r * 32 + c] = v > 0.f ? v : 0.f;
        }
    }
}

__global__ __launch_bounds__(320) void mlp3_kernel(const float* __restrict__ h32,
                                                   const float* __restrict__ W,
                                                   const float* __restrict__ b,
                                                   float* __restrict__ out) {
    int tid = threadIdx.x;
    int nl = tid / 10;
    int j = tid - nl * 10;
    int n = blockIdx.x * 32 + nl;
    if (n >= N_NODES) return;
    float acc = b[j];
    #pragma unroll
    for (int k = 0; k < 32; k++) acc += h32[n * 32 + k] * W[k * 10 + j];
    out[n * 10 + j] = acc;
}

// ---------------- launch ----------------

extern "C" void kernel_launch(void* const* d_in, const int* in_sizes, int n_in,
                              void* d_out, int out_size, void* d_ws, size_t ws_size,
                              hipStream_t stream) {
    const float* x   = (const float*)d_in[0];
    const int* esrc  = (const int*)d_in[1];
    const int* edst  = (const int*)d_in[2];
    const float* ew  = (const float*)d_in[3];
    const float* W1s = (const float*)d_in[4];
    const float* W1n = (const float*)d_in[5];
    const float* b1  = (const float*)d_in[6];
    const float* W2s = (const float*)d_in[7];
    const float* W2n = (const float*)d_in[8];
    const float* b2  = (const float*)d_in[9];
    const float* Wl1 = (const float*)d_in[10];
    const float* bl1 = (const float*)d_in[11];
    const float* Wl2 = (const float*)d_in[12];
    const float* bl2 = (const float*)d_in[13];
    const float* Wl3 = (const float*)d_in[14];
    const float* bl3 = (const float*)d_in[15];

    float* out = (float*)d_out;       // [50000,10]
    float* emb = out + 500000;        // [50000,128] output 1

    char* ws = (char*)d_ws;
    size_t off = 0;
    auto alloc = [&](size_t bytes) -> void* {
        void* p = ws + off;
        off = (off + bytes + 255) & ~(size_t)255;
        return p;
    };
    int*   row_off = (int*)alloc((size_t)(N_NODES + 1) * 4);
    float* inv_deg = (float*)alloc((size_t)N_NODES * 4);
    int*   G       = (int*)alloc((size_t)NBLK_SORT * 256 * 4);
    int*   bkt_off = (int*)alloc((size_t)(NBKT + 1) * 4);
    int*   bdst    = (int*)alloc((size_t)N_EDGES * 4);
    int2*  bsedge  = (int2*)alloc((size_t)N_EDGES * 8);
    int2*  sedge   = (int2*)alloc((size_t)N_EDGES * 8);
    unsigned short* xb   = (unsigned short*)alloc((size_t)N_NODES * 64 * 2);
    unsigned short* hn1b = (unsigned short*)alloc((size_t)N_NODES * 64 * 2);
    unsigned short* x1b  = (unsigned short*)alloc((size_t)N_NODES * 256 * 2);
    unsigned short* zb   = (unsigned short*)alloc((size_t)N_NODES * 128 * 2);
    unsigned short* embb = (unsigned short*)alloc((size_t)N_NODES * 128 * 2);
    unsigned short* h64b = (unsigned short*)alloc((size_t)N_NODES * 64 * 2);
    float* h32           = (float*)alloc((size_t)N_NODES * 32 * 4);
    unsigned short* B1p  = (unsigned short*)alloc(128 * 256 * 2);
    unsigned short* B2p  = (unsigned short*)alloc(256 * 256 * 2);
    unsigned short* Bl1p = (unsigned short*)alloc(128 * 64 * 2);
    unsigned short* Bl2p = (unsigned short*)alloc(64 * 32 * 2);

    // fused cvt + weight packing (independent of CSR)
    prep_kernel<<<PREP_S4 / 256, 256, 0, stream>>>((const float4*)x, (ushort4*)xb,
                                                   W1s, W1n, W2s, W2n, Wl1, Wl2,
                                                   B1p, B2p, Bl1p, Bl2p);

    // CSR build via 2-level counting sort (no global atomics)
    p1_hist<<<NBLK_SORT, 256, 0, stream>>>(edst, G);
    p2_scan<<<1, 256, 0, stream>>>(G, bkt_off, row_off);
    p3_scatter<<<NBLK_SORT, 256, 0, stream>>>(esrc, edst, ew, G, bdst, bsedge);
    p4_sort<<<NBKT, 256, 0, stream>>>(bkt_off, bdst, bsedge, row_off, inv_deg, sedge);

    const int PBLK = (PR_TILES + 3) / 4;   // 391 (2 m-tiles per wave)
    const int GBLK = (MT_TILES + 3) / 4;   // 782
    const int ABLK = (N_NODES + 3) / 4;    // 12500

    // layer 1
    agg64_kernel<<<ABLK, 256, 0, stream>>>((const unsigned*)xb, row_off, sedge,
                                           inv_deg, (unsigned*)hn1b);
    gemm1_mfma<<<PBLK, 256, 0, stream>>>(xb, hn1b, B1p, b1, x1b);

    // layer 2: GEMM first (self + z), then aggregate z in 128-dim
    gemm2_mfma<<<PBLK, 256, 0, stream>>>(x1b, B2p, b2, emb, zb);
    agg128_kernel<<<ABLK, 256, 0, stream>>>((const unsigned*)zb, row_off, sedge,
                                            inv_deg, emb, (unsigned*)embb);

    // MLP head
    mlp1_mfma<<<PBLK, 256, 0, stream>>>(embb, Bl1p, bl1, h64b);
    mlp2_mfma<<<GBLK, 256, 0, stream>>>(h64b, Bl2p, bl2, h32);
    mlp3_kernel<<<(N_NODES + 31) / 32, 320, 0, stream>>>(h32, Wl3, bl3, out);
}

// Round 7
// 299.467 us; speedup vs baseline: 2.6930x; 1.0374x over previous
//
#include <hip/hip_runtime.h>
#include <hip/hip_bf16.h>

#define N_NODES 50000
#define N_EDGES 800000
#define MT_TILES 3125   // 50000 / 16
#define PR_TILES 1563   // ceil(3125 / 2) wave-pairs (2 m-tiles per wave)

#define NBLK_SORT 200
#define CHUNK_SORT 4000   // NBLK_SORT * CHUNK_SORT == N_EDGES
#define NBKT 196          // ceil(50000 / 256)

typedef __attribute__((ext_vector_type(8))) short frag_ab;   // 8 bf16 (4 VGPRs)
typedef __attribute__((ext_vector_type(4))) float frag_cd;   // 4 fp32 acc

static __device__ __forceinline__ unsigned short f2b(float f) {
    union { float f; unsigned u; } v; v.f = f;
    unsigned r = v.u + 0x7fffu + ((v.u >> 16) & 1u);  // RNE
    return (unsigned short)(r >> 16);
}
static __device__ __forceinline__ float b2f(unsigned short b) {
    union { float f; unsigned u; } v; v.u = ((unsigned)b) << 16;
    return v.f;
}
static __device__ __forceinline__ float blo(unsigned p) { return b2f((unsigned short)(p & 0xffffu)); }
static __device__ __forceinline__ float bhi(unsigned p) { return b2f((unsigned short)(p >> 16)); }

// ---------------- fused prep: cvt x -> bf16, pack all weights ----------------
static __device__ __forceinline__ unsigned short packBK_elem(const float* __restrict__ Wa,
                                                             const float* __restrict__ Wb,
                                                             int Ka, int N, int idx) {
    int j = idx & 7;
    int lane = (idx >> 3) & 63;
    int rest = idx >> 9;
    int ntiles = N >> 4;
    int nt = rest % ntiles;
    int kt = rest / ntiles;
    int kk = kt * 32 + (lane >> 4) * 8 + j;
    int nn = nt * 16 + (lane & 15);
    float v = (kk < Ka) ? Wa[kk * N + nn] : Wb[(kk - Ka) * N + nn];
    return f2b(v);
}
static __device__ __forceinline__ unsigned short packBN_elem(const float* __restrict__ Wa,
                                                             const float* __restrict__ Wb,
                                                             int Na, int N, int idx) {
    int j = idx & 7;
    int lane = (idx >> 3) & 63;
    int rest = idx >> 9;
    int ntiles = N >> 4;
    int nt = rest % ntiles;
    int kt = rest / ntiles;
    int kk = kt * 32 + (lane >> 4) * 8 + j;
    int nn = nt * 16 + (lane & 15);
    float v = (nn < Na) ? Wa[kk * Na + nn] : Wb[kk * (N - Na) + (nn - Na)];
    return f2b(v);
}

#define PREP_S0 800000                 // cvt: ushort4 items (N_NODES*64/4)
#define PREP_S1 (PREP_S0 + 32768)      // B1p  128x256
#define PREP_S2 (PREP_S1 + 65536)      // B2p  256x256
#define PREP_S3 (PREP_S2 + 8192)       // Bl1p 128x64
#define PREP_S4 (PREP_S3 + 2048)       // Bl2p 64x32   -> total 908544 = 3549*256

__global__ __launch_bounds__(256) void prep_kernel(const float4* __restrict__ x4,
                                                   ushort4* __restrict__ xb4,
                                                   const float* __restrict__ W1s,
                                                   const float* __restrict__ W1n,
                                                   const float* __restrict__ W2s,
                                                   const float* __restrict__ W2n,
                                                   const float* __restrict__ Wl1,
                                                   const float* __restrict__ Wl2,
                                                   unsigned short* __restrict__ B1p,
                                                   unsigned short* __restrict__ B2p,
                                                   unsigned short* __restrict__ Bl1p,
                                                   unsigned short* __restrict__ Bl2p) {
    int idx = blockIdx.x * 256 + threadIdx.x;
    if (idx < PREP_S0) {
        float4 v = x4[idx];
        ushort4 o;
        o.x = f2b(v.x); o.y = f2b(v.y); o.z = f2b(v.z); o.w = f2b(v.w);
        xb4[idx] = o;
    } else if (idx < PREP_S1) {
        int i = idx - PREP_S0;
        B1p[i] = packBK_elem(W1s, W1n, 64, 256, i);
    } else if (idx < PREP_S2) {
        int i = idx - PREP_S1;
        B2p[i] = packBN_elem(W2s, W2n, 128, 256, i);
    } else if (idx < PREP_S3) {
        int i = idx - PREP_S2;
        Bl1p[i] = packBK_elem(Wl1, Wl1, 128, 64, i);
    } else if (idx < PREP_S4) {
        int i = idx - PREP_S3;
        Bl2p[i] = packBK_elem(Wl2, Wl2, 64, 32, i);
    }
}

// ---------------- CSR build: 2-level counting sort, no global atomics ----------------

__global__ __launch_bounds__(256) void p1_hist(const int* __restrict__ dst,
                                               int* __restrict__ G) {
    __shared__ int h[256];
    int t = threadIdx.x;
    h[t] = 0;
    __syncthreads();
    int base = blockIdx.x * CHUNK_SORT;
    for (int i = t; i < CHUNK_SORT; i += 256) {
        atomicAdd(&h[dst[base + i] >> 8], 1);
    }
    __syncthreads();
    G[blockIdx.x * 256 + t] = h[t];
}

__global__ __launch_bounds__(256) void p2_scan(int* __restrict__ G,
                                               int* __restrict__ bucket_off,
                                               int* __restrict__ row_off) {
    int t = threadIdx.x;
    int s = 0;
    for (int blk = 0; blk < NBLK_SORT; blk++) {
        int v = G[blk * 256 + t];
        G[blk * 256 + t] = s;  // within-bucket prefix across blocks
        s += v;
    }
    __shared__ int sc[256];
    sc[t] = s;
    __syncthreads();
    for (int off = 1; off < 256; off <<= 1) {
        int add = (t >= off) ? sc[t - off] : 0;
        __syncthreads();
        sc[t] += add;
        __syncthreads();
    }
    int boff = sc[t] - s;  // exclusive bucket offset
    if (t <= NBKT) bucket_off[t] = boff;
    if (t == 255) row_off[N_NODES] = sc[255];  // == N_EDGES
    for (int blk = 0; blk < NBLK_SORT; blk++) {
        G[blk * 256 + t] += boff;
    }
}

__global__ __launch_bounds__(256) void p3_scatter(const int* __restrict__ src,
                                                  const int* __restrict__ dst,
                                                  const float* __restrict__ w,
                                                  const int* __restrict__ G,
                                                  int* __restrict__ bdst,
                                                  int2* __restrict__ bsedge) {
    __shared__ int cur[256];
    int t = threadIdx.x;
    cur[t] = G[blockIdx.x * 256 + t];
    __syncthreads();
    int base = blockIdx.x * CHUNK_SORT;
    for (int i = t; i < CHUNK_SORT; i += 256) {
        int e = base + i;
        int d = dst[e];
        int pos = atomicAdd(&cur[d >> 8], 1);
        bdst[pos] = d;
        bsedge[pos] = make_int2(src[e], __float_as_int(w[e]));
    }
}

__global__ __launch_bounds__(256) void p4_sort(const int* __restrict__ bucket_off,
                                               const int* __restrict__ bdst,
                                               const int2* __restrict__ bsedge,
                                               int* __restrict__ row_off,
                                               float* __restrict__ inv_deg,
                                               int2* __restrict__ sedge) {
    __shared__ int lcnt[256];
    __shared__ int lcur[256];
    __shared__ int sc[256];
    int t = threadIdx.x;
    int b = blockIdx.x;
    int e0 = bucket_off[b], e1 = bucket_off[b + 1];
    int d0 = b << 8;
    lcnt[t] = 0;
    __syncthreads();
    for (int e = e0 + t; e < e1; e += 256)
        atomicAdd(&lcnt[bdst[e] - d0], 1);
    __syncthreads();
    int v = lcnt[t];
    sc[t] = v;
    __syncthreads();
    for (int off = 1; off < 256; off <<= 1) {
        int add = (t >= off) ? sc[t - off] : 0;
        __syncthreads();
        sc[t] += add;
        __syncthreads();
    }
    int loff = e0 + sc[t] - v;  // exclusive, global
    lcur[t] = loff;
    int d = d0 + t;
    if (d < N_NODES) {
        row_off[d] = loff;
        inv_deg[d] = 1.0f / (float)(v > 0 ? v : 1);
    }
    __syncthreads();
    for (int e = e0 + t; e < e1; e += 256) {
        int dd = bdst[e];
        int2 sv = bsedge[e];
        int pos = atomicAdd(&lcur[dd - d0], 1);
        sedge[pos] = sv;
    }
}

// ---------------- Aggregations (gather; 4 waves/block, 1 node/wave) ----------------

// d=64: half-wave per edge (32 lanes x 2 dims via dword); 16-edge main (8 in flight/half)
__global__ __launch_bounds__(256) void agg64_kernel(const unsigned* __restrict__ xb32,
                                                    const int* __restrict__ row_off,
                                                    const int2* __restrict__ sedge,
                                                    const float* __restrict__ inv_deg,
                                                    unsigned* __restrict__ hn1b32) {
    int tid = threadIdx.x;
    int lane = tid & 63;
    int half = lane >> 5;
    int l31 = lane & 31;
    int n = blockIdx.x * 4 + (tid >> 6);
    if (n >= N_NODES) return;
    int e0 = row_off[n], e1 = row_off[n + 1];
    float ax = 0.f, ay = 0.f;
    int e = e0;
    for (; e + 16 <= e1; e += 16) {
        int2 m0 = sedge[e + half];
        int2 m1 = sedge[e + 2 + half];
        int2 m2 = sedge[e + 4 + half];
        int2 m3 = sedge[e + 6 + half];
        int2 m4 = sedge[e + 8 + half];
        int2 m5 = sedge[e + 10 + half];
        int2 m6 = sedge[e + 12 + half];
        int2 m7 = sedge[e + 14 + half];
        unsigned p0 = xb32[m0.x * 32 + l31];
        unsigned p1 = xb32[m1.x * 32 + l31];
        unsigned p2 = xb32[m2.x * 32 + l31];
        unsigned p3 = xb32[m3.x * 32 + l31];
        unsigned p4 = xb32[m4.x * 32 + l31];
        unsigned p5 = xb32[m5.x * 32 + l31];
        unsigned p6 = xb32[m6.x * 32 + l31];
        unsigned p7 = xb32[m7.x * 32 + l31];
        float w0 = __int_as_float(m0.y), w1 = __int_as_float(m1.y);
        float w2 = __int_as_float(m2.y), w3 = __int_as_float(m3.y);
        float w4 = __int_as_float(m4.y), w5 = __int_as_float(m5.y);
        float w6 = __int_as_float(m6.y), w7 = __int_as_float(m7.y);
        ax += w0 * blo(p0) + w1 * blo(p1) + w2 * blo(p2) + w3 * blo(p3)
            + w4 * blo(p4) + w5 * blo(p5) + w6 * blo(p6) + w7 * blo(p7);
        ay += w0 * bhi(p0) + w1 * bhi(p1) + w2 * bhi(p2) + w3 * bhi(p3)
            + w4 * bhi(p4) + w5 * bhi(p5) + w6 * bhi(p6) + w7 * bhi(p7);
    }
    for (; e + 8 <= e1; e += 8) {
        int2 m0 = sedge[e + half];
        int2 m1 = sedge[e + 2 + half];
        int2 m2 = sedge[e + 4 + half];
        int2 m3 = sedge[e + 6 + half];
        unsigned p0 = xb32[m0.x * 32 + l31];
        unsigned p1 = xb32[m1.x * 32 + l31];
        unsigned p2 = xb32[m2.x * 32 + l31];
        unsigned p3 = xb32[m3.x * 32 + l31];
        float w0 = __int_as_float(m0.y), w1 = __int_as_float(m1.y);
        float w2 = __int_as_float(m2.y), w3 = __int_as_float(m3.y);
        ax += w0 * blo(p0) + w1 * blo(p1) + w2 * blo(p2) + w3 * blo(p3);
        ay += w0 * bhi(p0) + w1 * bhi(p1) + w2 * bhi(p2) + w3 * bhi(p3);
    }
    for (; e < e1; e += 2) {
        int ee = e + half;
        if (ee < e1) {
            int2 m = sedge[ee];
            unsigned p = xb32[m.x * 32 + l31];
            float w = __int_as_float(m.y);
            ax += w * blo(p);
            ay += w * bhi(p);
        }
    }
    ax += __shfl_xor(ax, 32, 64);
    ay += __shfl_xor(ay, 32, 64);
    if (half == 0) {
        float id = inv_deg[n];
        hn1b32[n * 32 + l31] = (unsigned)f2b(ax * id) | ((unsigned)f2b(ay * id) << 16);
    }
}

// d=128: full wave per edge (2 dims/lane); 8-edge main (8 gathers in flight)
__global__ __launch_bounds__(256) void agg128_kernel(const unsigned* __restrict__ zb32,
                                                     const int* __restrict__ row_off,
                                                     const int2* __restrict__ sedge,
                                                     const float* __restrict__ inv_deg,
                                                     float* __restrict__ emb,
                                                     unsigned* __restrict__ embb32) {
    int tid = threadIdx.x;
    int lane = tid & 63;
    int n = blockIdx.x * 4 + (tid >> 6);
    if (n >= N_NODES) return;
    int e0 = row_off[n], e1 = row_off[n + 1];
    float ax = 0.f, ay = 0.f;
    int e = e0;
    for (; e + 8 <= e1; e += 8) {
        int2 m0 = sedge[e + 0];
        int2 m1 = sedge[e + 1];
        int2 m2 = sedge[e + 2];
        int2 m3 = sedge[e + 3];
        int2 m4 = sedge[e + 4];
        int2 m5 = sedge[e + 5];
        int2 m6 = sedge[e + 6];
        int2 m7 = sedge[e + 7];
        unsigned p0 = zb32[m0.x * 64 + lane];
        unsigned p1 = zb32[m1.x * 64 + lane];
        unsigned p2 = zb32[m2.x * 64 + lane];
        unsigned p3 = zb32[m3.x * 64 + lane];
        unsigned p4 = zb32[m4.x * 64 + lane];
        unsigned p5 = zb32[m5.x * 64 + lane];
        unsigned p6 = zb32[m6.x * 64 + lane];
        unsigned p7 = zb32[m7.x * 64 + lane];
        float w0 = __int_as_float(m0.y), w1 = __int_as_float(m1.y);
        float w2 = __int_as_float(m2.y), w3 = __int_as_float(m3.y);
        float w4 = __int_as_float(m4.y), w5 = __int_as_float(m5.y);
        float w6 = __int_as_float(m6.y), w7 = __int_as_float(m7.y);
        ax += w0 * blo(p0) + w1 * blo(p1) + w2 * blo(p2) + w3 * blo(p3)
            + w4 * blo(p4) + w5 * blo(p5) + w6 * blo(p6) + w7 * blo(p7);
        ay += w0 * bhi(p0) + w1 * bhi(p1) + w2 * bhi(p2) + w3 * bhi(p3)
            + w4 * bhi(p4) + w5 * bhi(p5) + w6 * bhi(p6) + w7 * bhi(p7);
    }
    for (; e + 4 <= e1; e += 4) {
        int2 m0 = sedge[e + 0];
        int2 m1 = sedge[e + 1];
        int2 m2 = sedge[e + 2];
        int2 m3 = sedge[e + 3];
        unsigned p0 = zb32[m0.x * 64 + lane];
        unsigned p1 = zb32[m1.x * 64 + lane];
        unsigned p2 = zb32[m2.x * 64 + lane];
        unsigned p3 = zb32[m3.x * 64 + lane];
        float w0 = __int_as_float(m0.y), w1 = __int_as_float(m1.y);
        float w2 = __int_as_float(m2.y), w3 = __int_as_float(m3.y);
        ax += w0 * blo(p0) + w1 * blo(p1) + w2 * blo(p2) + w3 * blo(p3);
        ay += w0 * bhi(p0) + w1 * bhi(p1) + w2 * bhi(p2) + w3 * bhi(p3);
    }
    for (; e < e1; e++) {
        int2 m = sedge[e];
        unsigned p = zb32[m.x * 64 + lane];
        float w = __int_as_float(m.y);
        ax += w * blo(p);
        ay += w * bhi(p);
    }
    float id = inv_deg[n];
    float2 self = ((const float2*)emb)[n * 64 + lane];
    float vx = self.x + ax * id;
    float vy = self.y + ay * id;
    ((float2*)emb)[n * 64 + lane] = make_float2(vx, vy);
    embb32[n * 64 + lane] = (unsigned)f2b(vx) | ((unsigned)f2b(vy) << 16);
}

// ---------------- MFMA GEMMs: 2 m-tiles (32 rows) per wave, B-frag reuse x2 ----------------

__global__ __launch_bounds__(256) void gemm1_mfma(const unsigned short* __restrict__ xb,
                                                  const unsigned short* __restrict__ hn1b,
                                                  const unsigned short* __restrict__ Bp,
                                                  const float* __restrict__ b1,
                                                  unsigned short* __restrict__ x1b) {
    int tid = threadIdx.x;
    int lane = tid & 63;
    int wv = tid >> 6;
    int pr = blockIdx.x * 4 + wv;
    if (pr >= PR_TILES) pr = PR_TILES - 1;
    int mt0 = pr * 2;
    int mt1 = mt0 + 1; if (mt1 >= MT_TILES) mt1 = MT_TILES - 1;
    int q = lane >> 4;
    int rl = lane & 15;
    int row0 = mt0 * 16 + rl, row1 = mt1 * 16 + rl;
    const unsigned short* x0 = xb + row0 * 64 + q * 8;
    const unsigned short* x1 = xb + row1 * 64 + q * 8;
    const unsigned short* h0 = hn1b + row0 * 64 + q * 8;
    const unsigned short* h1 = hn1b + row1 * 64 + q * 8;
    const frag_ab* bp = (const frag_ab*)Bp;
    frag_cd acc0[16], acc1[16];
    #pragma unroll
    for (int nt = 0; nt < 16; nt++) {
        acc0[nt] = (frag_cd){0.f, 0.f, 0.f, 0.f};
        acc1[nt] = (frag_cd){0.f, 0.f, 0.f, 0.f};
    }
    #pragma unroll
    for (int kt = 0; kt < 4; kt++) {
        const unsigned short* a0p = (kt < 2) ? (x0 + kt * 32) : (h0 + (kt - 2) * 32);
        const unsigned short* a1p = (kt < 2) ? (x1 + kt * 32) : (h1 + (kt - 2) * 32);
        frag_ab a0 = *(const frag_ab*)a0p;
        frag_ab a1 = *(const frag_ab*)a1p;
        #pragma unroll
        for (int nt = 0; nt < 16; nt++) {
            frag_ab b = bp[(kt * 16 + nt) * 64 + lane];
            acc0[nt] = __builtin_amdgcn_mfma_f32_16x16x32_bf16(a0, b, acc0[nt], 0, 0, 0);
            acc1[nt] = __builtin_amdgcn_mfma_f32_16x16x32_bf16(a1, b, acc1[nt], 0, 0, 0);
        }
    }
    int r0a = mt0 * 16 + q * 4, r0b = mt1 * 16 + q * 4;
    #pragma unroll
    for (int nt = 0; nt < 16; nt++) {
        int c = nt * 16 + rl;
        float bias = b1[c];
        #pragma unroll
        for (int i = 0; i < 4; i++) {
            float v0 = acc0[nt][i] + bias;
            float v1 = acc1[nt][i] + bias;
            x1b[(r0a + i) * 256 + c] = f2b(v0 > 0.f ? v0 : 0.f);
            x1b[(r0b + i) * 256 + c] = f2b(v1 > 0.f ? v1 : 0.f);
        }
    }
}

__global__ __launch_bounds__(256) void gemm2_mfma(const unsigned short* __restrict__ x1b,
                                                  const unsigned short* __restrict__ Bp,
                                                  const float* __restrict__ b2,
                                                  float* __restrict__ emb,
                                                  unsigned short* __restrict__ zb) {
    int tid = threadIdx.x;
    int lane = tid & 63;
    int wv = tid >> 6;
    int pr = blockIdx.x * 4 + wv;
    if (pr >= PR_TILES) pr = PR_TILES - 1;
    int mt0 = pr * 2;
    int mt1 = mt0 + 1; if (mt1 >= MT_TILES) mt1 = MT_TILES - 1;
    int q = lane >> 4;
    int rl = lane & 15;
    const unsigned short* a0row = x1b + (mt0 * 16 + rl) * 256 + q * 8;
    const unsigned short* a1row = x1b + (mt1 * 16 + rl) * 256 + q * 8;
    const frag_ab* bp = (const frag_ab*)Bp;
    frag_cd acc0[16], acc1[16];
    #pragma unroll
    for (int nt = 0; nt < 16; nt++) {
        acc0[nt] = (frag_cd){0.f, 0.f, 0.f, 0.f};
        acc1[nt] = (frag_cd){0.f, 0.f, 0.f, 0.f};
    }
    #pragma unroll
    for (int kt = 0; kt < 8; kt++) {
        frag_ab a0 = *(const frag_ab*)(a0row + kt * 32);
        frag_ab a1 = *(const frag_ab*)(a1row + kt * 32);
        #pragma unroll
        for (int nt = 0; nt < 16; nt++) {
            frag_ab b = bp[(kt * 16 + nt) * 64 + lane];
            acc0[nt] = __builtin_amdgcn_mfma_f32_16x16x32_bf16(a0, b, acc0[nt], 0, 0, 0);
            acc1[nt] = __builtin_amdgcn_mfma_f32_16x16x32_bf16(a1, b, acc1[nt], 0, 0, 0);
        }
    }
    int r0a = mt0 * 16 + q * 4, r0b = mt1 * 16 + q * 4;
    #pragma unroll
    for (int nt = 0; nt < 8; nt++) {
        int c = nt * 16 + rl;
        float bias = b2[c];
        #pragma unroll
        for (int i = 0; i < 4; i++) {
            emb[(r0a + i) * 128 + c] = acc0[nt][i] + bias;
            emb[(r0b + i) * 128 + c] = acc1[nt][i] + bias;
        }
    }
    #pragma unroll
    for (int nt = 8; nt < 16; nt++) {
        int c = (nt - 8) * 16 + rl;
        #pragma unroll
        for (int i = 0; i < 4; i++) {
            zb[(r0a + i) * 128 + c] = f2b(acc0[nt][i]);
            zb[(r0b + i) * 128 + c] = f2b(acc1[nt][i]);
        }
    }
}

__global__ __launch_bounds__(256) void mlp1_mfma(const unsigned short* __restrict__ embb,
                                                 const unsigned short* __restrict__ Bp,
                                                 const float* __restrict__ bl1,
                                                 unsigned short* __restrict__ h64b) {
    int tid = threadIdx.x;
    int lane = tid & 63;
    int wv = tid >> 6;
    int pr = blockIdx.x * 4 + wv;
    if (pr >= PR_TILES) pr = PR_TILES - 1;
    int mt0 = pr * 2;
    int mt1 = mt0 + 1; if (mt1 >= MT_TILES) mt1 = MT_TILES - 1;
    int q = lane >> 4;
    int rl = lane & 15;
    const unsigned short* a0row = embb + (mt0 * 16 + rl) * 128 + q * 8;
    const unsigned short* a1row = embb + (mt1 * 16 + rl) * 128 + q * 8;
    const frag_ab* bp = (const frag_ab*)Bp;
    frag_cd acc0[4], acc1[4];
    #pragma unroll
    for (int nt = 0; nt < 4; nt++) {
        acc0[nt] = (frag_cd){0.f, 0.f, 0.f, 0.f};
        acc1[nt] = (frag_cd){0.f, 0.f, 0.f, 0.f};
    }
    #pragma unroll
    for (int kt = 0; kt < 4; kt++) {
        frag_ab a0 = *(const frag_ab*)(a0row + kt * 32);
        frag_ab a1 = *(const frag_ab*)(a1row + kt * 32);
        #pragma unroll
        for (int nt = 0; nt < 4; nt++) {
            frag_ab b = bp[(kt * 4 + nt) * 64 + lane];
            acc0[nt] = __builtin_amdgcn_mfma_f32_16x16x32_bf16(a0, b, acc0[nt], 0, 0, 0);
            acc1[nt] = __builtin_amdgcn_mfma_f32_16x16x32_bf16(a1, b, acc1[nt], 0, 0, 0);
        }
    }
    int r0a = mt0 * 16 + q * 4, r0b = mt1 * 16 + q * 4;
    #pragma unroll
    for (int nt = 0; nt < 4; nt++) {
        int c = nt * 16 + rl;
        float bias = bl1[c];
        #pragma unroll
        for (int i = 0; i < 4; i++) {
            float v0 = acc0[nt][i] + bias;
            float v1 = acc1[nt][i] + bias;
            h64b[(r0a + i) * 64 + c] = f2b(v0 > 0.f ? v0 : 0.f);
            h64b[(r0b + i) * 64 + c] = f2b(v1 > 0.f ? v1 : 0.f);
        }
    }
}

// fused: h32 = relu(h64b @ Wl2 + bl2) (MFMA -> LDS), out = h32 @ Wl3 + bl3
__global__ __launch_bounds__(256) void mlp23_mfma(const unsigned short* __restrict__ h64b,
                                                  const unsigned short* __restrict__ Bp,
                                                  const float* __restrict__ bl2,
                                                  const float* __restrict__ Wl3,
                                                  const float* __restrict__ bl3,
                                                  float* __restrict__ out) {
    __shared__ float hs[64][33];
    int tid = threadIdx.x;
    int lane = tid & 63;
    int wv = tid >> 6;
    int mt = blockIdx.x * 4 + wv;
    if (mt >= MT_TILES) mt = MT_TILES - 1;
    int q = lane >> 4;
    int rl = lane & 15;
    const unsigned short* arow = h64b + (mt * 16 + rl) * 64 + q * 8;
    const frag_ab* bp = (const frag_ab*)Bp;
    frag_cd acc[2];
    #pragma unroll
    for (int nt = 0; nt < 2; nt++) acc[nt] = (frag_cd){0.f, 0.f, 0.f, 0.f};
    #pragma unroll
    for (int kt = 0; kt < 2; kt++) {
        frag_ab a = *(const frag_ab*)(arow + kt * 32);
        #pragma unroll
        for (int nt = 0; nt < 2; nt++) {
            frag_ab b = bp[(kt * 2 + nt) * 64 + lane];
            acc[nt] = __builtin_amdgcn_mfma_f32_16x16x32_bf16(a, b, acc[nt], 0, 0, 0);
        }
    }
    #pragma unroll
    for (int nt = 0; nt < 2; nt++) {
        int c = nt * 16 + rl;
        float bias = bl2[c];
        #pragma unroll
        for (int i = 0; i < 4; i++) {
            int lr = wv * 16 + q * 4 + i;
            float v = acc[nt][i] + bias;
            hs[lr][c] = v > 0.f ? v : 0.f;
        }
    }
    __syncthreads();
    int base = blockIdx.x * 64;
    for (int idx = tid; idx < 640; idx += 256) {
        int lr = idx / 10;
        int j = idx - lr * 10;
        int n = base + lr;
        if (n < N_NODES) {
            float a = bl3[j];
            #pragma unroll
            for (int k = 0; k < 32; k++) a += hs[lr][k] * Wl3[k * 10 + j];
            out[n * 10 + j] = a;
        }
    }
}

// ---------------- launch ----------------

extern "C" void kernel_launch(void* const* d_in, const int* in_sizes, int n_in,
                              void* d_out, int out_size, void* d_ws, size_t ws_size,
                              hipStream_t stream) {
    const float* x   = (const float*)d_in[0];
    const int* esrc  = (const int*)d_in[1];
    const int* edst  = (const int*)d_in[2];
    const float* ew  = (const float*)d_in[3];
    const float* W1s = (const float*)d_in[4];
    const float* W1n = (const float*)d_in[5];
    const float* b1  = (const float*)d_in[6];
    const float* W2s = (const float*)d_in[7];
    const float* W2n = (const float*)d_in[8];
    const float* b2  = (const float*)d_in[9];
    const float* Wl1 = (const float*)d_in[10];
    const float* bl1 = (const float*)d_in[11];
    const float* Wl2 = (const float*)d_in[12];
    const float* bl2 = (const float*)d_in[13];
    const float* Wl3 = (const float*)d_in[14];
    const float* bl3 = (const float*)d_in[15];

    float* out = (float*)d_out;       // [50000,10]
    float* emb = out + 500000;        // [50000,128] output 1

    char* ws = (char*)d_ws;
    size_t off = 0;
    auto alloc = [&](size_t bytes) -> void* {
        void* p = ws + off;
        off = (off + bytes + 255) & ~(size_t)255;
        return p;
    };
    int*   row_off = (int*)alloc((size_t)(N_NODES + 1) * 4);
    float* inv_deg = (float*)alloc((size_t)N_NODES * 4);
    int*   G       = (int*)alloc((size_t)NBLK_SORT * 256 * 4);
    int*   bkt_off = (int*)alloc((size_t)(NBKT + 1) * 4);
    int*   bdst    = (int*)alloc((size_t)N_EDGES * 4);
    int2*  bsedge  = (int2*)alloc((size_t)N_EDGES * 8);
    int2*  sedge   = (int2*)alloc((size_t)N_EDGES * 8);
    unsigned short* xb   = (unsigned short*)alloc((size_t)N_NODES * 64 * 2);
    unsigned short* hn1b = (unsigned short*)alloc((size_t)N_NODES * 64 * 2);
    unsigned short* x1b  = (unsigned short*)alloc((size_t)N_NODES * 256 * 2);
    unsigned short* zb   = (unsigned short*)alloc((size_t)N_NODES * 128 * 2);
    unsigned short* embb = (unsigned short*)alloc((size_t)N_NODES * 128 * 2);
    unsigned short* h64b = (unsigned short*)alloc((size_t)N_NODES * 64 * 2);
    unsigned short* B1p  = (unsigned short*)alloc(128 * 256 * 2);
    unsigned short* B2p  = (unsigned short*)alloc(256 * 256 * 2);
    unsigned short* Bl1p = (unsigned short*)alloc(128 * 64 * 2);
    unsigned short* Bl2p = (unsigned short*)alloc(64 * 32 * 2);

    // fused cvt + weight packing (independent of CSR)
    prep_kernel<<<PREP_S4 / 256, 256, 0, stream>>>((const float4*)x, (ushort4*)xb,
                                                   W1s, W1n, W2s, W2n, Wl1, Wl2,
                                                   B1p, B2p, Bl1p, Bl2p);

    // CSR build via 2-level counting sort (no global atomics)
    p1_hist<<<NBLK_SORT, 256, 0, stream>>>(edst, G);
    p2_scan<<<1, 256, 0, stream>>>(G, bkt_off, row_off);
    p3_scatter<<<NBLK_SORT, 256, 0, stream>>>(esrc, edst, ew, G, bdst, bsedge);
    p4_sort<<<NBKT, 256, 0, stream>>>(bkt_off, bdst, bsedge, row_off, inv_deg, sedge);

    const int PBLK = (PR_TILES + 3) / 4;   // 391 (2 m-tiles per wave)
    const int GBLK = (MT_TILES + 3) / 4;   // 782
    const int ABLK = (N_NODES + 3) / 4;    // 12500

    // layer 1
    agg64_kernel<<<ABLK, 256, 0, stream>>>((const unsigned*)xb, row_off, sedge,
                                           inv_deg, (unsigned*)hn1b);
    gemm1_mfma<<<PBLK, 256, 0, stream>>>(xb, hn1b, B1p, b1, x1b);

    // layer 2: GEMM first (self + z), then aggregate z in 128-dim
    gemm2_mfma<<<PBLK, 256, 0, stream>>>(x1b, B2p, b2, emb, zb);
    agg128_kernel<<<ABLK, 256, 0, stream>>>((const unsigned*)zb, row_off, sedge,
                                            inv_deg, emb, (unsigned*)embb);

    // MLP head
    mlp1_mfma<<<PBLK, 256, 0, stream>>>(embb, Bl1p, bl1, h64b);
    mlp23_mfma<<<GBLK, 256, 0, stream>>>(h64b, Bl2p, bl2, Wl3, bl3, out);
}

// Round 8
// 294.733 us; speedup vs baseline: 2.7362x; 1.0161x over previous
//
#include <hip/hip_runtime.h>
#include <hip/hip_bf16.h>

#define N_NODES 50000
#define N_EDGES 800000
#define MT_TILES 3125   // 50000 / 16
#define PR_TILES 1563   // ceil(3125 / 2) wave-pairs (2 m-tiles per wave, small kernels)

#define NBLK_SORT 200
#define CHUNK_SORT 4000   // NBLK_SORT * CHUNK_SORT == N_EDGES
#define NBKT 196          // ceil(50000 / 256)

typedef __attribute__((ext_vector_type(8))) short frag_ab;   // 8 bf16 (4 VGPRs)
typedef __attribute__((ext_vector_type(4))) float frag_cd;   // 4 fp32 acc

static __device__ __forceinline__ unsigned short f2b(float f) {
    union { float f; unsigned u; } v; v.f = f;
    unsigned r = v.u + 0x7fffu + ((v.u >> 16) & 1u);  // RNE
    return (unsigned short)(r >> 16);
}
static __device__ __forceinline__ float b2f(unsigned short b) {
    union { float f; unsigned u; } v; v.u = ((unsigned)b) << 16;
    return v.f;
}
static __device__ __forceinline__ float blo(unsigned p) { return b2f((unsigned short)(p & 0xffffu)); }
static __device__ __forceinline__ float bhi(unsigned p) { return b2f((unsigned short)(p >> 16)); }

// ---------------- fused prep: cvt x -> bf16, pack all weights ----------------
static __device__ __forceinline__ unsigned short packBK_elem(const float* __restrict__ Wa,
                                                             const float* __restrict__ Wb,
                                                             int Ka, int N, int idx) {
    int j = idx & 7;
    int lane = (idx >> 3) & 63;
    int rest = idx >> 9;
    int ntiles = N >> 4;
    int nt = rest % ntiles;
    int kt = rest / ntiles;
    int kk = kt * 32 + (lane >> 4) * 8 + j;
    int nn = nt * 16 + (lane & 15);
    float v = (kk < Ka) ? Wa[kk * N + nn] : Wb[(kk - Ka) * N + nn];
    return f2b(v);
}
static __device__ __forceinline__ unsigned short packBN_elem(const float* __restrict__ Wa,
                                                             const float* __restrict__ Wb,
                                                             int Na, int N, int idx) {
    int j = idx & 7;
    int lane = (idx >> 3) & 63;
    int rest = idx >> 9;
    int ntiles = N >> 4;
    int nt = rest % ntiles;
    int kt = rest / ntiles;
    int kk = kt * 32 + (lane >> 4) * 8 + j;
    int nn = nt * 16 + (lane & 15);
    float v = (nn < Na) ? Wa[kk * Na + nn] : Wb[kk * (N - Na) + (nn - Na)];
    return f2b(v);
}

#define PREP_S0 800000                 // cvt: ushort4 items (N_NODES*64/4)
#define PREP_S1 (PREP_S0 + 32768)      // B1p  128x256
#define PREP_S2 (PREP_S1 + 65536)      // B2p  256x256
#define PREP_S3 (PREP_S2 + 8192)       // Bl1p 128x64
#define PREP_S4 (PREP_S3 + 2048)      // Bl2p 64x32   -> total 908544 = 3549*256

__global__ __launch_bounds__(256) void prep_kernel(const float4* __restrict__ x4,
                                                   ushort4* __restrict__ xb4,
                                                   const float* __restrict__ W1s,
                                                   const float* __restrict__ W1n,
                                                   const float* __restrict__ W2s,
                                                   const float* __restrict__ W2n,
                                                   const float* __restrict__ Wl1,
                                                   const float* __restrict__ Wl2,
                                                   unsigned short* __restrict__ B1p,
                                                   unsigned short* __restrict__ B2p,
                                                   unsigned short* __restrict__ Bl1p,
                                                   unsigned short* __restrict__ Bl2p) {
    int idx = blockIdx.x * 256 + threadIdx.x;
    if (idx < PREP_S0) {
        float4 v = x4[idx];
        ushort4 o;
        o.x = f2b(v.x); o.y = f2b(v.y); o.z = f2b(v.z); o.w = f2b(v.w);
        xb4[idx] = o;
    } else if (idx < PREP_S1) {
        int i = idx - PREP_S0;
        B1p[i] = packBK_elem(W1s, W1n, 64, 256, i);
    } else if (idx < PREP_S2) {
        int i = idx - PREP_S1;
        B2p[i] = packBN_elem(W2s, W2n, 128, 256, i);
    } else if (idx < PREP_S3) {
        int i = idx - PREP_S2;
        Bl1p[i] = packBK_elem(Wl1, Wl1, 128, 64, i);
    } else if (idx < PREP_S4) {
        int i = idx - PREP_S3;
        Bl2p[i] = packBK_elem(Wl2, Wl2, 64, 32, i);
    }
}

// ---------------- CSR build: 2-level counting sort, no global atomics ----------------

__global__ __launch_bounds__(256) void p1_hist(const int* __restrict__ dst,
                                               int* __restrict__ G) {
    __shared__ int h[256];
    int t = threadIdx.x;
    h[t] = 0;
    __syncthreads();
    int base = blockIdx.x * CHUNK_SORT;
    for (int i = t; i < CHUNK_SORT; i += 256) {
        atomicAdd(&h[dst[base + i] >> 8], 1);
    }
    __syncthreads();
    G[blockIdx.x * 256 + t] = h[t];
}

__global__ __launch_bounds__(256) void p2_scan(int* __restrict__ G,
                                               int* __restrict__ bucket_off,
                                               int* __restrict__ row_off) {
    int t = threadIdx.x;
    int s = 0;
    for (int blk = 0; blk < NBLK_SORT; blk++) {
        int v = G[blk * 256 + t];
        G[blk * 256 + t] = s;  // within-bucket prefix across blocks
        s += v;
    }
    __shared__ int sc[256];
    sc[t] = s;
    __syncthreads();
    for (int off = 1; off < 256; off <<= 1) {
        int add = (t >= off) ? sc[t - off] : 0;
        __syncthreads();
        sc[t] += add;
        __syncthreads();
    }
    int boff = sc[t] - s;  // exclusive bucket offset
    if (t <= NBKT) bucket_off[t] = boff;
    if (t == 255) row_off[N_NODES] = sc[255];  // == N_EDGES
    for (int blk = 0; blk < NBLK_SORT; blk++) {
        G[blk * 256 + t] += boff;
    }
}

__global__ __launch_bounds__(256) void p3_scatter(const int* __restrict__ src,
                                                  const int* __restrict__ dst,
                                                  const float* __restrict__ w,
                                                  const int* __restrict__ G,
                                                  int* __restrict__ bdst,
                                                  int2* __restrict__ bsedge) {
    __shared__ int cur[256];
    int t = threadIdx.x;
    cur[t] = G[blockIdx.x * 256 + t];
    __syncthreads();
    int base = blockIdx.x * CHUNK_SORT;
    for (int i = t; i < CHUNK_SORT; i += 256) {
        int e = base + i;
        int d = dst[e];
        int pos = atomicAdd(&cur[d >> 8], 1);
        bdst[pos] = d;
        bsedge[pos] = make_int2(src[e], __float_as_int(w[e]));
    }
}

__global__ __launch_bounds__(256) void p4_sort(const int* __restrict__ bucket_off,
                                               const int* __restrict__ bdst,
                                               const int2* __restrict__ bsedge,
                                               int* __restrict__ row_off,
                                               float* __restrict__ inv_deg,
                                               int2* __restrict__ sedge) {
    __shared__ int lcnt[256];
    __shared__ int lcur[256];
    __shared__ int sc[256];
    int t = threadIdx.x;
    int b = blockIdx.x;
    int e0 = bucket_off[b], e1 = bucket_off[b + 1];
    int d0 = b << 8;
    lcnt[t] = 0;
    __syncthreads();
    for (int e = e0 + t; e < e1; e += 256)
        atomicAdd(&lcnt[bdst[e] - d0], 1);
    __syncthreads();
    int v = lcnt[t];
    sc[t] = v;
    __syncthreads();
    for (int off = 1; off < 256; off <<= 1) {
        int add = (t >= off) ? sc[t - off] : 0;
        __syncthreads();
        sc[t] += add;
        __syncthreads();
    }
    int loff = e0 + sc[t] - v;  // exclusive, global
    lcur[t] = loff;
    int d = d0 + t;
    if (d < N_NODES) {
        row_off[d] = loff;
        inv_deg[d] = 1.0f / (float)(v > 0 ? v : 1);
    }
    __syncthreads();
    for (int e = e0 + t; e < e1; e += 256) {
        int dd = bdst[e];
        int2 sv = bsedge[e];
        int pos = atomicAdd(&lcur[dd - d0], 1);
        sedge[pos] = sv;
    }
}

// ---------------- Aggregations (gather; 4 waves/block, 1 node/wave) ----------------

// d=64: half-wave per edge (32 lanes x 2 dims via dword); 16-edge main (8 in flight/half)
__global__ __launch_bounds__(256) void agg64_kernel(const unsigned* __restrict__ xb32,
                                                    const int* __restrict__ row_off,
                                                    const int2* __restrict__ sedge,
                                                    const float* __restrict__ inv_deg,
                                                    unsigned* __restrict__ hn1b32) {
    int tid = threadIdx.x;
    int lane = tid & 63;
    int half = lane >> 5;
    int l31 = lane & 31;
    int n = blockIdx.x * 4 + (tid >> 6);
    if (n >= N_NODES) return;
    int e0 = row_off[n], e1 = row_off[n + 1];
    float ax = 0.f, ay = 0.f;
    int e = e0;
    for (; e + 16 <= e1; e += 16) {
        int2 m0 = sedge[e + half];
        int2 m1 = sedge[e + 2 + half];
        int2 m2 = sedge[e + 4 + half];
        int2 m3 = sedge[e + 6 + half];
        int2 m4 = sedge[e + 8 + half];
        int2 m5 = sedge[e + 10 + half];
        int2 m6 = sedge[e + 12 + half];
        int2 m7 = sedge[e + 14 + half];
        unsigned p0 = xb32[m0.x * 32 + l31];
        unsigned p1 = xb32[m1.x * 32 + l31];
        unsigned p2 = xb32[m2.x * 32 + l31];
        unsigned p3 = xb32[m3.x * 32 + l31];
        unsigned p4 = xb32[m4.x * 32 + l31];
        unsigned p5 = xb32[m5.x * 32 + l31];
        unsigned p6 = xb32[m6.x * 32 + l31];
        unsigned p7 = xb32[m7.x * 32 + l31];
        float w0 = __int_as_float(m0.y), w1 = __int_as_float(m1.y);
        float w2 = __int_as_float(m2.y), w3 = __int_as_float(m3.y);
        float w4 = __int_as_float(m4.y), w5 = __int_as_float(m5.y);
        float w6 = __int_as_float(m6.y), w7 = __int_as_float(m7.y);
        ax += w0 * blo(p0) + w1 * blo(p1) + w2 * blo(p2) + w3 * blo(p3)
            + w4 * blo(p4) + w5 * blo(p5) + w6 * blo(p6) + w7 * blo(p7);
        ay += w0 * bhi(p0) + w1 * bhi(p1) + w2 * bhi(p2) + w3 * bhi(p3)
            + w4 * bhi(p4) + w5 * bhi(p5) + w6 * bhi(p6) + w7 * bhi(p7);
    }
    for (; e + 8 <= e1; e += 8) {
        int2 m0 = sedge[e + half];
        int2 m1 = sedge[e + 2 + half];
        int2 m2 = sedge[e + 4 + half];
        int2 m3 = sedge[e + 6 + half];
        unsigned p0 = xb32[m0.x * 32 + l31];
        unsigned p1 = xb32[m1.x * 32 + l31];
        unsigned p2 = xb32[m2.x * 32 + l31];
        unsigned p3 = xb32[m3.x * 32 + l31];
        float w0 = __int_as_float(m0.y), w1 = __int_as_float(m1.y);
        float w2 = __int_as_float(m2.y), w3 = __int_as_float(m3.y);
        ax += w0 * blo(p0) + w1 * blo(p1) + w2 * blo(p2) + w3 * blo(p3);
        ay += w0 * bhi(p0) + w1 * bhi(p1) + w2 * bhi(p2) + w3 * bhi(p3);
    }
    for (; e < e1; e += 2) {
        int ee = e + half;
        if (ee < e1) {
            int2 m = sedge[ee];
            unsigned p = xb32[m.x * 32 + l31];
            float w = __int_as_float(m.y);
            ax += w * blo(p);
            ay += w * bhi(p);
        }
    }
    ax += __shfl_xor(ax, 32, 64);
    ay += __shfl_xor(ay, 32, 64);
    if (half == 0) {
        float id = inv_deg[n];
        hn1b32[n * 32 + l31] = (unsigned)f2b(ax * id) | ((unsigned)f2b(ay * id) << 16);
    }
}

// d=128: full wave per edge (2 dims/lane); 8-edge main (8 gathers in flight)
__global__ __launch_bounds__(256) void agg128_kernel(const unsigned* __restrict__ zb32,
                                                     const int* __restrict__ row_off,
                                                     const int2* __restrict__ sedge,
                                                     const float* __restrict__ inv_deg,
                                                     float* __restrict__ emb,
                                                     unsigned* __restrict__ embb32) {
    int tid = threadIdx.x;
    int lane = tid & 63;
    int n = blockIdx.x * 4 + (tid >> 6);
    if (n >= N_NODES) return;
    int e0 = row_off[n], e1 = row_off[n + 1];
    float ax = 0.f, ay = 0.f;
    int e = e0;
    for (; e + 8 <= e1; e += 8) {
        int2 m0 = sedge[e + 0];
        int2 m1 = sedge[e + 1];
        int2 m2 = sedge[e + 2];
        int2 m3 = sedge[e + 3];
        int2 m4 = sedge[e + 4];
        int2 m5 = sedge[e + 5];
        int2 m6 = sedge[e + 6];
        int2 m7 = sedge[e + 7];
        unsigned p0 = zb32[m0.x * 64 + lane];
        unsigned p1 = zb32[m1.x * 64 + lane];
        unsigned p2 = zb32[m2.x * 64 + lane];
        unsigned p3 = zb32[m3.x * 64 + lane];
        unsigned p4 = zb32[m4.x * 64 + lane];
        unsigned p5 = zb32[m5.x * 64 + lane];
        unsigned p6 = zb32[m6.x * 64 + lane];
        unsigned p7 = zb32[m7.x * 64 + lane];
        float w0 = __int_as_float(m0.y), w1 = __int_as_float(m1.y);
        float w2 = __int_as_float(m2.y), w3 = __int_as_float(m3.y);
        float w4 = __int_as_float(m4.y), w5 = __int_as_float(m5.y);
        float w6 = __int_as_float(m6.y), w7 = __int_as_float(m7.y);
        ax += w0 * blo(p0) + w1 * blo(p1) + w2 * blo(p2) + w3 * blo(p3)
            + w4 * blo(p4) + w5 * blo(p5) + w6 * blo(p6) + w7 * blo(p7);
        ay += w0 * bhi(p0) + w1 * bhi(p1) + w2 * bhi(p2) + w3 * bhi(p3)
            + w4 * bhi(p4) + w5 * bhi(p5) + w6 * bhi(p6) + w7 * bhi(p7);
    }
    for (; e + 4 <= e1; e += 4) {
        int2 m0 = sedge[e + 0];
        int2 m1 = sedge[e + 1];
        int2 m2 = sedge[e + 2];
        int2 m3 = sedge[e + 3];
        unsigned p0 = zb32[m0.x * 64 + lane];
        unsigned p1 = zb32[m1.x * 64 + lane];
        unsigned p2 = zb32[m2.x * 64 + lane];
        unsigned p3 = zb32[m3.x * 64 + lane];
        float w0 = __int_as_float(m0.y), w1 = __int_as_float(m1.y);
        float w2 = __int_as_float(m2.y), w3 = __int_as_float(m3.y);
        ax += w0 * blo(p0) + w1 * blo(p1) + w2 * blo(p2) + w3 * blo(p3);
        ay += w0 * bhi(p0) + w1 * bhi(p1) + w2 * bhi(p2) + w3 * bhi(p3);
    }
    for (; e < e1; e++) {
        int2 m = sedge[e];
        unsigned p = zb32[m.x * 64 + lane];
        float w = __int_as_float(m.y);
        ax += w * blo(p);
        ay += w * bhi(p);
    }
    float id = inv_deg[n];
    float2 self = ((const float2*)emb)[n * 64 + lane];
    float vx = self.x + ax * id;
    float vy = self.y + ay * id;
    ((float2*)emb)[n * 64 + lane] = make_float2(vx, vy);
    embb32[n * 64 + lane] = (unsigned)f2b(vx) | ((unsigned)f2b(vy) << 16);
}

// ---------------- MFMA GEMMs: 1 m-tile/wave, B staged per-kt through 16 KB LDS ----------------
// B slice kt = 16 nt x 64 lanes x 8 bf16 = 16 KB; 4-wave block reuses it 4x.

// x1b = bf16(relu([xb|hn1b] @ [W1s;W1n] + b1))   K=128 (4 kt), N=256
__global__ __launch_bounds__(256) void gemm1_mfma(const unsigned short* __restrict__ xb,
                                                  const unsigned short* __restrict__ hn1b,
                                                  const unsigned short* __restrict__ Bp,
                                                  const float* __restrict__ b1,
                                                  unsigned short* __restrict__ x1b) {
    __shared__ __align__(16) unsigned short sB[8192];
    int tid = threadIdx.x;
    int lane = tid & 63;
    int wv = tid >> 6;
    int mt = blockIdx.x * 4 + wv;
    if (mt >= MT_TILES) mt = MT_TILES - 1;  // dup wave, benign same-value stores
    int q = lane >> 4;
    int rl = lane & 15;
    int row = mt * 16 + rl;
    frag_ab a[4];
    a[0] = *(const frag_ab*)(xb + row * 64 + q * 8);
    a[1] = *(const frag_ab*)(xb + row * 64 + q * 8 + 32);
    a[2] = *(const frag_ab*)(hn1b + row * 64 + q * 8);
    a[3] = *(const frag_ab*)(hn1b + row * 64 + q * 8 + 32);
    frag_cd acc[16];
    #pragma unroll
    for (int nt = 0; nt < 16; nt++) acc[nt] = (frag_cd){0.f, 0.f, 0.f, 0.f};
    #pragma unroll
    for (int kt = 0; kt < 4; kt++) {
        __syncthreads();
        #pragma unroll
        for (int i = 0; i < 4; i++) {
            int idx = i * 256 + tid;
            ((float4*)sB)[idx] = ((const float4*)(Bp + kt * 8192))[idx];
        }
        __syncthreads();
        #pragma unroll
        for (int nt = 0; nt < 16; nt++) {
            frag_ab b = *(const frag_ab*)(sB + (nt * 64 + lane) * 8);
            acc[nt] = __builtin_amdgcn_mfma_f32_16x16x32_bf16(a[kt], b, acc[nt], 0, 0, 0);
        }
    }
    int r0 = mt * 16;
    #pragma unroll
    for (int nt = 0; nt < 16; nt++) {
        int c = nt * 16 + rl;
        float bias = b1[c];
        #pragma unroll
        for (int i = 0; i < 4; i++) {
            int r = r0 + q * 4 + i;
            float v = acc[nt][i] + bias;
            v = v > 0.f ? v : 0.f;
            x1b[r * 256 + c] = f2b(v);
        }
    }
}

// self+z: x1b @ [W2s|W2n]; cols 0-127 -> emb fp32 (+b2), cols 128-255 -> zb bf16. K=256 (8 kt)
__global__ __launch_bounds__(256) void gemm2_mfma(const unsigned short* __restrict__ x1b,
                                                  const unsigned short* __restrict__ Bp,
                                                  const float* __restrict__ b2,
                                                  float* __restrict__ emb,
                                                  unsigned short* __restrict__ zb) {
    __shared__ __align__(16) unsigned short sB[8192];
    int tid = threadIdx.x;
    int lane = tid & 63;
    int wv = tid >> 6;
    int mt = blockIdx.x * 4 + wv;
    if (mt >= MT_TILES) mt = MT_TILES - 1;
    int q = lane >> 4;
    int rl = lane & 15;
    int row = mt * 16 + rl;
    const unsigned short* arow = x1b + row * 256 + q * 8;
    frag_ab a[8];
    #pragma unroll
    for (int kt = 0; kt < 8; kt++) a[kt] = *(const frag_ab*)(arow + kt * 32);
    frag_cd acc[16];
    #pragma unroll
    for (int nt = 0; nt < 16; nt++) acc[nt] = (frag_cd){0.f, 0.f, 0.f, 0.f};
    #pragma unroll
    for (int kt = 0; kt < 8; kt++) {
        __syncthreads();
        #pragma unroll
        for (int i = 0; i < 4; i++) {
            int idx = i * 256 + tid;
            ((float4*)sB)[idx] = ((const float4*)(Bp + kt * 8192))[idx];
        }
        __syncthreads();
        #pragma unroll
        for (int nt = 0; nt < 16; nt++) {
            frag_ab b = *(const frag_ab*)(sB + (nt * 64 + lane) * 8);
            acc[nt] = __builtin_amdgcn_mfma_f32_16x16x32_bf16(a[kt], b, acc[nt], 0, 0, 0);
        }
    }
    int r0 = mt * 16;
    #pragma unroll
    for (int nt = 0; nt < 8; nt++) {
        int c = nt * 16 + rl;
        float bias = b2[c];
        #pragma unroll
        for (int i = 0; i < 4; i++) {
            int r = r0 + q * 4 + i;
            emb[r * 128 + c] = acc[nt][i] + bias;
        }
    }
    #pragma unroll
    for (int nt = 8; nt < 16; nt++) {
        int c = (nt - 8) * 16 + rl;
        #pragma unroll
        for (int i = 0; i < 4; i++) {
            int r = r0 + q * 4 + i;
            zb[r * 128 + c] = f2b(acc[nt][i]);
        }
    }
}

// h64b = bf16(relu(embb @ Wl1 + bl1))   K=128, N=64 — 2 m-tiles/wave (only 32 acc regs)
__global__ __launch_bounds__(256) void mlp1_mfma(const unsigned short* __restrict__ embb,
                                                 const unsigned short* __restrict__ Bp,
                                                 const float* __restrict__ bl1,
                                                 unsigned short* __restrict__ h64b) {
    int tid = threadIdx.x;
    int lane = tid & 63;
    int wv = tid >> 6;
    int pr = blockIdx.x * 4 + wv;
    if (pr >= PR_TILES) pr = PR_TILES - 1;
    int mt0 = pr * 2;
    int mt1 = mt0 + 1; if (mt1 >= MT_TILES) mt1 = MT_TILES - 1;
    int q = lane >> 4;
    int rl = lane & 15;
    const unsigned short* a0row = embb + (mt0 * 16 + rl) * 128 + q * 8;
    const unsigned short* a1row = embb + (mt1 * 16 + rl) * 128 + q * 8;
    const frag_ab* bp = (const frag_ab*)Bp;
    frag_cd acc0[4], acc1[4];
    #pragma unroll
    for (int nt = 0; nt < 4; nt++) {
        acc0[nt] = (frag_cd){0.f, 0.f, 0.f, 0.f};
        acc1[nt] = (frag_cd){0.f, 0.f, 0.f, 0.f};
    }
    #pragma unroll
    for (int kt = 0; kt < 4; kt++) {
        frag_ab a0 = *(const frag_ab*)(a0row + kt * 32);
        frag_ab a1 = *(const frag_ab*)(a1row + kt * 32);
        #pragma unroll
        for (int nt = 0; nt < 4; nt++) {
            frag_ab b = bp[(kt * 4 + nt) * 64 + lane];
            acc0[nt] = __builtin_amdgcn_mfma_f32_16x16x32_bf16(a0, b, acc0[nt], 0, 0, 0);
            acc1[nt] = __builtin_amdgcn_mfma_f32_16x16x32_bf16(a1, b, acc1[nt], 0, 0, 0);
        }
    }
    int r0a = mt0 * 16 + q * 4, r0b = mt1 * 16 + q * 4;
    #pragma unroll
    for (int nt = 0; nt < 4; nt++) {
        int c = nt * 16 + rl;
        float bias = bl1[c];
        #pragma unroll
        for (int i = 0; i < 4; i++) {
            float v0 = acc0[nt][i] + bias;
            float v1 = acc1[nt][i] + bias;
            h64b[(r0a + i) * 64 + c] = f2b(v0 > 0.f ? v0 : 0.f);
            h64b[(r0b + i) * 64 + c] = f2b(v1 > 0.f ? v1 : 0.f);
        }
    }
}

// fused: h32 = relu(h64b @ Wl2 + bl2) (MFMA -> LDS), out = h32 @ Wl3 + bl3
__global__ __launch_bounds__(256) void mlp23_mfma(const unsigned short* __restrict__ h64b,
                                                  const unsigned short* __restrict__ Bp,
                                                  const float* __restrict__ bl2,
                                                  const float* __restrict__ Wl3,
                                                  const float* __restrict__ bl3,
                                                  float* __restrict__ out) {
    __shared__ float hs[64][33];
    int tid = threadIdx.x;
    int lane = tid & 63;
    int wv = tid >> 6;
    int mt = blockIdx.x * 4 + wv;
    if (mt >= MT_TILES) mt = MT_TILES - 1;
    int q = lane >> 4;
    int rl = lane & 15;
    const unsigned short* arow = h64b + (mt * 16 + rl) * 64 + q * 8;
    const frag_ab* bp = (const frag_ab*)Bp;
    frag_cd acc[2];
    #pragma unroll
    for (int nt = 0; nt < 2; nt++) acc[nt] = (frag_cd){0.f, 0.f, 0.f, 0.f};
    #pragma unroll
    for (int kt = 0; kt < 2; kt++) {
        frag_ab a = *(const frag_ab*)(arow + kt * 32);
        #pragma unroll
        for (int nt = 0; nt < 2; nt++) {
            frag_ab b = bp[(kt * 2 + nt) * 64 + lane];
            acc[nt] = __builtin_amdgcn_mfma_f32_16x16x32_bf16(a, b, acc[nt], 0, 0, 0);
        }
    }
    #pragma unroll
    for (int nt = 0; nt < 2; nt++) {
        int c = nt * 16 + rl;
        float bias = bl2[c];
        #pragma unroll
        for (int i = 0; i < 4; i++) {
            int lr = wv * 16 + q * 4 + i;
            float v = acc[nt][i] + bias;
            hs[lr][c] = v > 0.f ? v : 0.f;
        }
    }
    __syncthreads();
    int base = blockIdx.x * 64;
    for (int idx = tid; idx < 640; idx += 256) {
        int lr = idx / 10;
        int j = idx - lr * 10;
        int n = base + lr;
        if (n < N_NODES) {
            float a = bl3[j];
            #pragma unroll
            for (int k = 0; k < 32; k++) a += hs[lr][k] * Wl3[k * 10 + j];
            out[n * 10 + j] = a;
        }
    }
}

// ---------------- launch ----------------

extern "C" void kernel_launch(void* const* d_in, const int* in_sizes, int n_in,
                              void* d_out, int out_size, void* d_ws, size_t ws_size,
                              hipStream_t stream) {
    const float* x   = (const float*)d_in[0];
    const int* esrc  = (const int*)d_in[1];
    const int* edst  = (const int*)d_in[2];
    const float* ew  = (const float*)d_in[3];
    const float* W1s = (const float*)d_in[4];
    const float* W1n = (const float*)d_in[5];
    const float* b1  = (const float*)d_in[6];
    const float* W2s = (const float*)d_in[7];
    const float* W2n = (const float*)d_in[8];
    const float* b2  = (const float*)d_in[9];
    const float* Wl1 = (const float*)d_in[10];
    const float* bl1 = (const float*)d_in[11];
    const float* Wl2 = (const float*)d_in[12];
    const float* bl2 = (const float*)d_in[13];
    const float* Wl3 = (const float*)d_in[14];
    const float* bl3 = (const float*)d_in[15];

    float* out = (float*)d_out;       // [50000,10]
    float* emb = out + 500000;        // [50000,128] output 1

    char* ws = (char*)d_ws;
    size_t off = 0;
    auto alloc = [&](size_t bytes) -> void* {
        void* p = ws + off;
        off = (off + bytes + 255) & ~(size_t)255;
        return p;
    };
    int*   row_off = (int*)alloc((size_t)(N_NODES + 1) * 4);
    float* inv_deg = (float*)alloc((size_t)N_NODES * 4);
    int*   G       = (int*)alloc((size_t)NBLK_SORT * 256 * 4);
    int*   bkt_off = (int*)alloc((size_t)(NBKT + 1) * 4);
    int*   bdst    = (int*)alloc((size_t)N_EDGES * 4);
    int2*  bsedge  = (int2*)alloc((size_t)N_EDGES * 8);
    int2*  sedge   = (int2*)alloc((size_t)N_EDGES * 8);
    unsigned short* xb   = (unsigned short*)alloc((size_t)N_NODES * 64 * 2);
    unsigned short* hn1b = (unsigned short*)alloc((size_t)N_NODES * 64 * 2);
    unsigned short* x1b  = (unsigned short*)alloc((size_t)N_NODES * 256 * 2);
    unsigned short* zb   = (unsigned short*)alloc((size_t)N_NODES * 128 * 2);
    unsigned short* embb = (unsigned short*)alloc((size_t)N_NODES * 128 * 2);
    unsigned short* h64b = (unsigned short*)alloc((size_t)N_NODES * 64 * 2);
    unsigned short* B1p  = (unsigned short*)alloc(128 * 256 * 2);
    unsigned short* B2p  = (unsigned short*)alloc(256 * 256 * 2);
    unsigned short* Bl1p = (unsigned short*)alloc(128 * 64 * 2);
    unsigned short* Bl2p = (unsigned short*)alloc(64 * 32 * 2);

    // fused cvt + weight packing (independent of CSR)
    prep_kernel<<<PREP_S4 / 256, 256, 0, stream>>>((const float4*)x, (ushort4*)xb,
                                                   W1s, W1n, W2s, W2n, Wl1, Wl2,
                                                   B1p, B2p, Bl1p, Bl2p);

    // CSR build via 2-level counting sort (no global atomics)
    p1_hist<<<NBLK_SORT, 256, 0, stream>>>(edst, G);
    p2_scan<<<1, 256, 0, stream>>>(G, bkt_off, row_off);
    p3_scatter<<<NBLK_SORT, 256, 0, stream>>>(esrc, edst, ew, G, bdst, bsedge);
    p4_sort<<<NBKT, 256, 0, stream>>>(bkt_off, bdst, bsedge, row_off, inv_deg, sedge);

    const int PBLK = (PR_TILES + 3) / 4;   // 391 (2 m-tiles per wave, small kernels)
    const int GBLK = (MT_TILES + 3) / 4;   // 782
    const int ABLK = (N_NODES + 3) / 4;    // 12500

    // layer 1
    agg64_kernel<<<ABLK, 256, 0, stream>>>((const unsigned*)xb, row_off, sedge,
                                           inv_deg, (unsigned*)hn1b);
    gemm1_mfma<<<GBLK, 256, 0, stream>>>(xb, hn1b, B1p, b1, x1b);

    // layer 2: GEMM first (self + z), then aggregate z in 128-dim
    gemm2_mfma<<<GBLK, 256, 0, stream>>>(x1b, B2p, b2, emb, zb);
    agg128_kernel<<<ABLK, 256, 0, stream>>>((const unsigned*)zb, row_off, sedge,
                                            inv_deg, emb, (unsigned*)embb);

    // MLP head
    mlp1_mfma<<<PBLK, 256, 0, stream>>>(embb, Bl1p, bl1, h64b);
    mlp23_mfma<<<GBLK, 256, 0, stream>>>(h64b, Bl2p, bl2, Wl3, bl3, out);
}

// Round 9
// 279.886 us; speedup vs baseline: 2.8814x; 1.0530x over previous
//
#include <hip/hip_runtime.h>
#include <hip/hip_bf16.h>

#define N_NODES 50000
#define N_EDGES 800000
#define MT_TILES 3125   // 50000 / 16
#define PR_TILES 1563   // ceil(3125 / 2) wave-pairs (2 m-tiles per wave, small kernels)

#define NBLK_SORT 200
#define CHUNK_SORT 4000   // NBLK_SORT * CHUNK_SORT == N_EDGES
#define NBKT 196          // ceil(50000 / 256)

typedef __attribute__((ext_vector_type(8))) short frag_ab;   // 8 bf16 (4 VGPRs)
typedef __attribute__((ext_vector_type(4))) float frag_cd;   // 4 fp32 acc

static __device__ __forceinline__ unsigned short f2b(float f) {
    union { float f; unsigned u; } v; v.f = f;
    unsigned r = v.u + 0x7fffu + ((v.u >> 16) & 1u);  // RNE
    return (unsigned short)(r >> 16);
}
static __device__ __forceinline__ float b2f(unsigned short b) {
    union { float f; unsigned u; } v; v.u = ((unsigned)b) << 16;
    return v.f;
}
static __device__ __forceinline__ float blo(unsigned p) { return b2f((unsigned short)(p & 0xffffu)); }
static __device__ __forceinline__ float bhi(unsigned p) { return b2f((unsigned short)(p >> 16)); }

// ---------------- fused prep (cvt x, pack weights) + p1 bucket histogram ----------------
static __device__ __forceinline__ unsigned short packBK_elem(const float* __restrict__ Wa,
                                                             const float* __restrict__ Wb,
                                                             int Ka, int N, int idx) {
    int j = idx & 7;
    int lane = (idx >> 3) & 63;
    int rest = idx >> 9;
    int ntiles = N >> 4;
    int nt = rest % ntiles;
    int kt = rest / ntiles;
    int kk = kt * 32 + (lane >> 4) * 8 + j;
    int nn = nt * 16 + (lane & 15);
    float v = (kk < Ka) ? Wa[kk * N + nn] : Wb[(kk - Ka) * N + nn];
    return f2b(v);
}
static __device__ __forceinline__ unsigned short packBN_elem(const float* __restrict__ Wa,
                                                             const float* __restrict__ Wb,
                                                             int Na, int N, int idx) {
    int j = idx & 7;
    int lane = (idx >> 3) & 63;
    int rest = idx >> 9;
    int ntiles = N >> 4;
    int nt = rest % ntiles;
    int kt = rest / ntiles;
    int kk = kt * 32 + (lane >> 4) * 8 + j;
    int nn = nt * 16 + (lane & 15);
    float v = (nn < Na) ? Wa[kk * Na + nn] : Wb[kk * (N - Na) + (nn - Na)];
    return f2b(v);
}

#define PREP_S0 800000                 // cvt: ushort4 items (N_NODES*64/4)
#define PREP_S1 (PREP_S0 + 32768)      // B1p  128x256
#define PREP_S2 (PREP_S1 + 65536)      // B2p  256x256
#define PREP_S3 (PREP_S2 + 8192)       // Bl1p 128x64
#define PREP_S4 (PREP_S3 + 2048)       // Bl2p 64x32   -> total 908544 = 3549*256
#define PREP_BLKS 3549

__global__ __launch_bounds__(256) void prep_p1_kernel(const float4* __restrict__ x4,
                                                      ushort4* __restrict__ xb4,
                                                      const float* __restrict__ W1s,
                                                      const float* __restrict__ W1n,
                                                      const float* __restrict__ W2s,
                                                      const float* __restrict__ W2n,
                                                      const float* __restrict__ Wl1,
                                                      const float* __restrict__ Wl2,
                                                      unsigned short* __restrict__ B1p,
                                                      unsigned short* __restrict__ B2p,
                                                      unsigned short* __restrict__ Bl1p,
                                                      unsigned short* __restrict__ Bl2p,
                                                      const int* __restrict__ dst,
                                                      int* __restrict__ G) {
    __shared__ int h[256];
    int bid = blockIdx.x;
    int t = threadIdx.x;
    if (bid >= PREP_BLKS) {
        // p1: per-block bucket histogram (bucket = dst >> 8)
        int blk = bid - PREP_BLKS;
        h[t] = 0;
        __syncthreads();
        int base = blk * CHUNK_SORT;
        for (int i = t; i < CHUNK_SORT; i += 256)
            atomicAdd(&h[dst[base + i] >> 8], 1);
        __syncthreads();
        G[blk * 256 + t] = h[t];
        return;
    }
    int idx = bid * 256 + t;
    if (idx < PREP_S0) {
        float4 v = x4[idx];
        ushort4 o;
        o.x = f2b(v.x); o.y = f2b(v.y); o.z = f2b(v.z); o.w = f2b(v.w);
        xb4[idx] = o;
    } else if (idx < PREP_S1) {
        int i = idx - PREP_S0;
        B1p[i] = packBK_elem(W1s, W1n, 64, 256, i);
    } else if (idx < PREP_S2) {
        int i = idx - PREP_S1;
        B2p[i] = packBN_elem(W2s, W2n, 128, 256, i);
    } else if (idx < PREP_S3) {
        int i = idx - PREP_S2;
        Bl1p[i] = packBK_elem(Wl1, Wl1, 128, 64, i);
    } else {
        int i = idx - PREP_S3;
        Bl2p[i] = packBK_elem(Wl2, Wl2, 64, 32, i);
    }
}

// ---------------- CSR build: parallel scans, no global atomics ----------------

// p2a: one block per bucket column b — scan G[0..199][b] across blocks
__global__ __launch_bounds__(256) void p2a_scan(int* __restrict__ G,
                                                int* __restrict__ colsum) {
    __shared__ int sc[256];
    int b = blockIdx.x;
    int t = threadIdx.x;
    int v = (t < NBLK_SORT) ? G[t * 256 + b] : 0;
    sc[t] = v;
    __syncthreads();
    for (int off = 1; off < 256; off <<= 1) {
        int add = (t >= off) ? sc[t - off] : 0;
        __syncthreads();
        sc[t] += add;
        __syncthreads();
    }
    if (t < NBLK_SORT) G[t * 256 + b] = sc[t] - v;  // exclusive within-bucket prefix
    if (t == 255) colsum[b] = sc[255];
}

// p2b: scan bucket totals -> bucket_off (exclusive)
__global__ __launch_bounds__(256) void p2b_scan(const int* __restrict__ colsum,
                                                int* __restrict__ bucket_off,
                                                int* __restrict__ row_off) {
    __shared__ int sc[256];
    int t = threadIdx.x;
    int v = colsum[t];
    sc[t] = v;
    __syncthreads();
    for (int off = 1; off < 256; off <<= 1) {
        int add = (t >= off) ? sc[t - off] : 0;
        __syncthreads();
        sc[t] += add;
        __syncthreads();
    }
    bucket_off[t] = sc[t] - v;  // exclusive
    if (t == 255) row_off[N_NODES] = sc[255];  // == N_EDGES
}

// p3: scatter edges into bucket-grouped arrays via LDS cursors (bucket_off folded in)
__global__ __launch_bounds__(256) void p3_scatter(const int* __restrict__ src,
                                                  const int* __restrict__ dst,
                                                  const float* __restrict__ w,
                                                  const int* __restrict__ G,
                                                  const int* __restrict__ bucket_off,
                                                  int* __restrict__ bdst,
                                                  int2* __restrict__ bsedge) {
    __shared__ int cur[256];
    int t = threadIdx.x;
    cur[t] = G[blockIdx.x * 256 + t] + bucket_off[t];
    __syncthreads();
    int base = blockIdx.x * CHUNK_SORT;
    for (int i = t; i < CHUNK_SORT; i += 256) {
        int e = base + i;
        int d = dst[e];
        int pos = atomicAdd(&cur[d >> 8], 1);
        bdst[pos] = d;
        bsedge[pos] = make_int2(src[e], __float_as_int(w[e]));
    }
}

// p4: one block per bucket — LDS counting sort by dst, emit row_off/inv_deg/sedge
__global__ __launch_bounds__(256) void p4_sort(const int* __restrict__ bucket_off,
                                               const int* __restrict__ bdst,
                                               const int2* __restrict__ bsedge,
                                               int* __restrict__ row_off,
                                               float* __restrict__ inv_deg,
                                               int2* __restrict__ sedge) {
    __shared__ int lcnt[256];
    __shared__ int lcur[256];
    __shared__ int sc[256];
    int t = threadIdx.x;
    int b = blockIdx.x;
    int e0 = bucket_off[b], e1 = bucket_off[b + 1];
    int d0 = b << 8;
    lcnt[t] = 0;
    __syncthreads();
    for (int e = e0 + t; e < e1; e += 256)
        atomicAdd(&lcnt[bdst[e] - d0], 1);
    __syncthreads();
    int v = lcnt[t];
    sc[t] = v;
    __syncthreads();
    for (int off = 1; off < 256; off <<= 1) {
        int add = (t >= off) ? sc[t - off] : 0;
        __syncthreads();
        sc[t] += add;
        __syncthreads();
    }
    int loff = e0 + sc[t] - v;  // exclusive, global
    lcur[t] = loff;
    int d = d0 + t;
    if (d < N_NODES) {
        row_off[d] = loff;
        inv_deg[d] = 1.0f / (float)(v > 0 ? v : 1);
    }
    __syncthreads();
    for (int e = e0 + t; e < e1; e += 256) {
        int dd = bdst[e];
        int2 sv = bsedge[e];
        int pos = atomicAdd(&lcur[dd - d0], 1);
        sedge[pos] = sv;
    }
}

// ---------------- Aggregations (gather; 4 waves/block, 1 node/wave) ----------------

// d=64: quarter-wave per edge (16 lanes x dwordx2); 16 edges in flight per wave
__global__ __launch_bounds__(256) void agg64_kernel(const uint2* __restrict__ xb2,
                                                    const int* __restrict__ row_off,
                                                    const int2* __restrict__ sedge,
                                                    const float* __restrict__ inv_deg,
                                                    uint2* __restrict__ hn1b2) {
    int tid = threadIdx.x;
    int lane = tid & 63;
    int qr = lane >> 4;
    int l15 = lane & 15;
    int n = blockIdx.x * 4 + (tid >> 6);
    if (n >= N_NODES) return;
    int e0 = row_off[n], e1 = row_off[n + 1];
    float a0 = 0.f, a1 = 0.f, a2 = 0.f, a3 = 0.f;
    int e = e0;
    for (; e + 16 <= e1; e += 16) {
        int2 m0 = sedge[e + qr];
        int2 m1 = sedge[e + 4 + qr];
        int2 m2 = sedge[e + 8 + qr];
        int2 m3 = sedge[e + 12 + qr];
        uint2 p0 = xb2[m0.x * 16 + l15];
        uint2 p1 = xb2[m1.x * 16 + l15];
        uint2 p2 = xb2[m2.x * 16 + l15];
        uint2 p3 = xb2[m3.x * 16 + l15];
        float w0 = __int_as_float(m0.y), w1 = __int_as_float(m1.y);
        float w2 = __int_as_float(m2.y), w3 = __int_as_float(m3.y);
        a0 += w0 * blo(p0.x) + w1 * blo(p1.x) + w2 * blo(p2.x) + w3 * blo(p3.x);
        a1 += w0 * bhi(p0.x) + w1 * bhi(p1.x) + w2 * bhi(p2.x) + w3 * bhi(p3.x);
        a2 += w0 * blo(p0.y) + w1 * blo(p1.y) + w2 * blo(p2.y) + w3 * blo(p3.y);
        a3 += w0 * bhi(p0.y) + w1 * bhi(p1.y) + w2 * bhi(p2.y) + w3 * bhi(p3.y);
    }
    for (; e < e1; e += 4) {
        int ee = e + qr;
        if (ee < e1) {
            int2 m = sedge[ee];
            uint2 p = xb2[m.x * 16 + l15];
            float w = __int_as_float(m.y);
            a0 += w * blo(p.x); a1 += w * bhi(p.x);
            a2 += w * blo(p.y); a3 += w * bhi(p.y);
        }
    }
    a0 += __shfl_xor(a0, 16, 64); a1 += __shfl_xor(a1, 16, 64);
    a2 += __shfl_xor(a2, 16, 64); a3 += __shfl_xor(a3, 16, 64);
    a0 += __shfl_xor(a0, 32, 64); a1 += __shfl_xor(a1, 32, 64);
    a2 += __shfl_xor(a2, 32, 64); a3 += __shfl_xor(a3, 32, 64);
    if (qr == 0) {
        float id = inv_deg[n];
        uint2 o;
        o.x = (unsigned)f2b(a0 * id) | ((unsigned)f2b(a1 * id) << 16);
        o.y = (unsigned)f2b(a2 * id) | ((unsigned)f2b(a3 * id) << 16);
        hn1b2[n * 16 + l15] = o;
    }
}

// d=128: half-wave per edge (32 lanes x dwordx2); 16 edges in flight per wave
__global__ __launch_bounds__(256) void agg128_kernel(const uint2* __restrict__ zb2,
                                                     const int* __restrict__ row_off,
                                                     const int2* __restrict__ sedge,
                                                     const float* __restrict__ inv_deg,
                                                     float* __restrict__ emb,
                                                     uint2* __restrict__ embb2) {
    int tid = threadIdx.x;
    int lane = tid & 63;
    int hf = lane >> 5;
    int l31 = lane & 31;
    int n = blockIdx.x * 4 + (tid >> 6);
    if (n >= N_NODES) return;
    int e0 = row_off[n], e1 = row_off[n + 1];
    float a0 = 0.f, a1 = 0.f, a2 = 0.f, a3 = 0.f;
    int e = e0;
    for (; e + 16 <= e1; e += 16) {
        int2 m0 = sedge[e + hf];
        int2 m1 = sedge[e + 2 + hf];
        int2 m2 = sedge[e + 4 + hf];
        int2 m3 = sedge[e + 6 + hf];
        int2 m4 = sedge[e + 8 + hf];
        int2 m5 = sedge[e + 10 + hf];
        int2 m6 = sedge[e + 12 + hf];
        int2 m7 = sedge[e + 14 + hf];
        uint2 p0 = zb2[m0.x * 32 + l31];
        uint2 p1 = zb2[m1.x * 32 + l31];
        uint2 p2 = zb2[m2.x * 32 + l31];
        uint2 p3 = zb2[m3.x * 32 + l31];
        uint2 p4 = zb2[m4.x * 32 + l31];
        uint2 p5 = zb2[m5.x * 32 + l31];
        uint2 p6 = zb2[m6.x * 32 + l31];
        uint2 p7 = zb2[m7.x * 32 + l31];
        float w0 = __int_as_float(m0.y), w1 = __int_as_float(m1.y);
        float w2 = __int_as_float(m2.y), w3 = __int_as_float(m3.y);
        float w4 = __int_as_float(m4.y), w5 = __int_as_float(m5.y);
        float w6 = __int_as_float(m6.y), w7 = __int_as_float(m7.y);
        a0 += w0 * blo(p0.x) + w1 * blo(p1.x) + w2 * blo(p2.x) + w3 * blo(p3.x)
            + w4 * blo(p4.x) + w5 * blo(p5.x) + w6 * blo(p6.x) + w7 * blo(p7.x);
        a1 += w0 * bhi(p0.x) + w1 * bhi(p1.x) + w2 * bhi(p2.x) + w3 * bhi(p3.x)
            + w4 * bhi(p4.x) + w5 * bhi(p5.x) + w6 * bhi(p6.x) + w7 * bhi(p7.x);
        a2 += w0 * blo(p0.y) + w1 * blo(p1.y) + w2 * blo(p2.y) + w3 * blo(p3.y)
            + w4 * blo(p4.y) + w5 * blo(p5.y) + w6 * blo(p6.y) + w7 * blo(p7.y);
        a3 += w0 * bhi(p0.y) + w1 * bhi(p1.y) + w2 * bhi(p2.y) + w3 * bhi(p3.y)
            + w4 * bhi(p4.y) + w5 * bhi(p5.y) + w6 * bhi(p6.y) + w7 * bhi(p7.y);
    }
    for (; e < e1; e += 2) {
        int ee = e + hf;
        if (ee < e1) {
            int2 m = sedge[ee];
            uint2 p = zb2[m.x * 32 + l31];
            float w = __int_as_float(m.y);
            a0 += w * blo(p.x); a1 += w * bhi(p.x);
            a2 += w * blo(p.y); a3 += w * bhi(p.y);
        }
    }
    a0 += __shfl_xor(a0, 32, 64); a1 += __shfl_xor(a1, 32, 64);
    a2 += __shfl_xor(a2, 32, 64); a3 += __shfl_xor(a3, 32, 64);
    if (hf == 0) {
        float id = inv_deg[n];
        float4 self = ((const float4*)emb)[n * 32 + l31];
        float v0 = self.x + a0 * id;
        float v1 = self.y + a1 * id;
        float v2 = self.z + a2 * id;
        float v3 = self.w + a3 * id;
        ((float4*)emb)[n * 32 + l31] = make_float4(v0, v1, v2, v3);
        uint2 o;
        o.x = (unsigned)f2b(v0) | ((unsigned)f2b(v1) << 16);
        o.y = (unsigned)f2b(v2) | ((unsigned)f2b(v3) << 16);
        embb2[n * 32 + l31] = o;
    }
}

// ---------------- MFMA GEMMs: 1 m-tile/wave, B staged per-kt through 16 KB LDS ----------------

// x1b = bf16(relu([xb|hn1b] @ [W1s;W1n] + b1))   K=128 (4 kt), N=256
__global__ __launch_bounds__(256) void gemm1_mfma(const unsigned short* __restrict__ xb,
                                                  const unsigned short* __restrict__ hn1b,
                                                  const unsigned short* __restrict__ Bp,
                                                  const float* __restrict__ b1,
                                                  unsigned short* __restrict__ x1b) {
    __shared__ __align__(16) unsigned short sB[8192];
    int tid = threadIdx.x;
    int lane = tid & 63;
    int wv = tid >> 6;
    int mt = blockIdx.x * 4 + wv;
    if (mt >= MT_TILES) mt = MT_TILES - 1;  // dup wave, benign same-value stores
    int q = lane >> 4;
    int rl = lane & 15;
    int row = mt * 16 + rl;
    frag_ab a[4];
    a[0] = *(const frag_ab*)(xb + row * 64 + q * 8);
    a[1] = *(const frag_ab*)(xb + row * 64 + q * 8 + 32);
    a[2] = *(const frag_ab*)(hn1b + row * 64 + q * 8);
    a[3] = *(const frag_ab*)(hn1b + row * 64 + q * 8 + 32);
    frag_cd acc[16];
    #pragma unroll
    for (int nt = 0; nt < 16; nt++) acc[nt] = (frag_cd){0.f, 0.f, 0.f, 0.f};
    #pragma unroll
    for (int kt = 0; kt < 4; kt++) {
        __syncthreads();
        #pragma unroll
        for (int i = 0; i < 4; i++) {
            int idx = i * 256 + tid;
            ((float4*)sB)[idx] = ((const float4*)(Bp + kt * 8192))[idx];
        }
        __syncthreads();
        #pragma unroll
        for (int nt = 0; nt < 16; nt++) {
            frag_ab b = *(const frag_ab*)(sB + (nt * 64 + lane) * 8);
            acc[nt] = __builtin_amdgcn_mfma_f32_16x16x32_bf16(a[kt], b, acc[nt], 0, 0, 0);
        }
    }
    int r0 = mt * 16;
    #pragma unroll
    for (int nt = 0; nt < 16; nt++) {
        int c = nt * 16 + rl;
        float bias = b1[c];
        #pragma unroll
        for (int i = 0; i < 4; i++) {
            int r = r0 + q * 4 + i;
            float v = acc[nt][i] + bias;
            v = v > 0.f ? v : 0.f;
            x1b[r * 256 + c] = f2b(v);
        }
    }
}

// self+z: x1b @ [W2s|W2n]; cols 0-127 -> emb fp32 (+b2), cols 128-255 -> zb bf16. K=256 (8 kt)
__global__ __launch_bounds__(256) void gemm2_mfma(const unsigned short* __restrict__ x1b,
                                                  const unsigned short* __restrict__ Bp,
                                                  const float* __restrict__ b2,
                                                  float* __restrict__ emb,
                                                  unsigned short* __restrict__ zb) {
    __shared__ __align__(16) unsigned short sB[8192];
    int tid = threadIdx.x;
    int lane = tid & 63;
    int wv = tid >> 6;
    int mt = blockIdx.x * 4 + wv;
    if (mt >= MT_TILES) mt = MT_TILES - 1;
    int q = lane >> 4;
    int rl = lane & 15;
    int row = mt * 16 + rl;
    const unsigned short* arow = x1b + row * 256 + q * 8;
    frag_ab a[8];
    #pragma unroll
    for (int kt = 0; kt < 8; kt++) a[kt] = *(const frag_ab*)(arow + kt * 32);
    frag_cd acc[16];
    #pragma unroll
    for (int nt = 0; nt < 16; nt++) acc[nt] = (frag_cd){0.f, 0.f, 0.f, 0.f};
    #pragma unroll
    for (int kt = 0; kt < 8; kt++) {
        __syncthreads();
        #pragma unroll
        for (int i = 0; i < 4; i++) {
            int idx = i * 256 + tid;
            ((float4*)sB)[idx] = ((const float4*)(Bp + kt * 8192))[idx];
        }
        __syncthreads();
        #pragma unroll
        for (int nt = 0; nt < 16; nt++) {
            frag_ab b = *(const frag_ab*)(sB + (nt * 64 + lane) * 8);
            acc[nt] = __builtin_amdgcn_mfma_f32_16x16x32_bf16(a[kt], b, acc[nt], 0, 0, 0);
        }
    }
    int r0 = mt * 16;
    #pragma unroll
    for (int nt = 0; nt < 8; nt++) {
        int c = nt * 16 + rl;
        float bias = b2[c];
        #pragma unroll
        for (int i = 0; i < 4; i++) {
            int r = r0 + q * 4 + i;
            emb[r * 128 + c] = acc[nt][i] + bias;
        }
    }
    #pragma unroll
    for (int nt = 8; nt < 16; nt++) {
        int c = (nt - 8) * 16 + rl;
        #pragma unroll
        for (int i = 0; i < 4; i++) {
            int r = r0 + q * 4 + i;
            zb[r * 128 + c] = f2b(acc[nt][i]);
        }
    }
}

// h64b = bf16(relu(embb @ Wl1 + bl1))   K=128, N=64 — 2 m-tiles/wave (only 32 acc regs)
__global__ __launch_bounds__(256) void mlp1_mfma(const unsigned short* __restrict__ embb,
                                                 const unsigned short* __restrict__ Bp,
                                                 const float* __restrict__ bl1,
                                                 unsigned short* __restrict__ h64b) {
    int tid = threadIdx.x;
    int lane = tid & 63;
    int wv = tid >> 6;
    int pr = blockIdx.x * 4 + wv;
    if (pr >= PR_TILES) pr = PR_TILES - 1;
    int mt0 = pr * 2;
    int mt1 = mt0 + 1; if (mt1 >= MT_TILES) mt1 = MT_TILES - 1;
    int q = lane >> 4;
    int rl = lane & 15;
    const unsigned short* a0row = embb + (mt0 * 16 + rl) * 128 + q * 8;
    const unsigned short* a1row = embb + (mt1 * 16 + rl) * 128 + q * 8;
    const frag_ab* bp = (const frag_ab*)Bp;
    frag_cd acc0[4], acc1[4];
    #pragma unroll
    for (int nt = 0; nt < 4; nt++) {
        acc0[nt] = (frag_cd){0.f, 0.f, 0.f, 0.f};
        acc1[nt] = (frag_cd){0.f, 0.f, 0.f, 0.f};
    }
    #pragma unroll
    for (int kt = 0; kt < 4; kt++) {
        frag_ab a0 = *(const frag_ab*)(a0row + kt * 32);
        frag_ab a1 = *(const frag_ab*)(a1row + kt * 32);
        #pragma unroll
        for (int nt = 0; nt < 4; nt++) {
            frag_ab b = bp[(kt * 4 + nt) * 64 + lane];
            acc0[nt] = __builtin_amdgcn_mfma_f32_16x16x32_bf16(a0, b, acc0[nt], 0, 0, 0);
            acc1[nt] = __builtin_amdgcn_mfma_f32_16x16x32_bf16(a1, b, acc1[nt], 0, 0, 0);
        }
    }
    int r0a = mt0 * 16 + q * 4, r0b = mt1 * 16 + q * 4;
    #pragma unroll
    for (int nt = 0; nt < 4; nt++) {
        int c = nt * 16 + rl;
        float bias = bl1[c];
        #pragma unroll
        for (int i = 0; i < 4; i++) {
            float v0 = acc0[nt][i] + bias;
            float v1 = acc1[nt][i] + bias;
            h64b[(r0a + i) * 64 + c] = f2b(v0 > 0.f ? v0 : 0.f);
            h64b[(r0b + i) * 64 + c] = f2b(v1 > 0.f ? v1 : 0.f);
        }
    }
}

// fused: h32 = relu(h64b @ Wl2 + bl2) (MFMA -> LDS), out = h32 @ Wl3 + bl3
__global__ __launch_bounds__(256) void mlp23_mfma(const unsigned short* __restrict__ h64b,
                                                  const unsigned short* __restrict__ Bp,
                                                  const float* __restrict__ bl2,
                                                  const float* __restrict__ Wl3,
                                                  const float* __restrict__ bl3,
                                                  float* __restrict__ out) {
    __shared__ float hs[64][33];
    int tid = threadIdx.x;
    int lane = tid & 63;
    int wv = tid >> 6;
    int mt = blockIdx.x * 4 + wv;
    if (mt >= MT_TILES) mt = MT_TILES - 1;
    int q = lane >> 4;
    int rl = lane & 15;
    const unsigned short* arow = h64b + (mt * 16 + rl) * 64 + q * 8;
    const frag_ab* bp = (const frag_ab*)Bp;
    frag_cd acc[2];
    #pragma unroll
    for (int nt = 0; nt < 2; nt++) acc[nt] = (frag_cd){0.f, 0.f, 0.f, 0.f};
    #pragma unroll
    for (int kt = 0; kt < 2; kt++) {
        frag_ab a = *(const frag_ab*)(arow + kt * 32);
        #pragma unroll
        for (int nt = 0; nt < 2; nt++) {
            frag_ab b = bp[(kt * 2 + nt) * 64 + lane];
            acc[nt] = __builtin_amdgcn_mfma_f32_16x16x32_bf16(a, b, acc[nt], 0, 0, 0);
        }
    }
    #pragma unroll
    for (int nt = 0; nt < 2; nt++) {
        int c = nt * 16 + rl;
        float bias = bl2[c];
        #pragma unroll
        for (int i = 0; i < 4; i++) {
            int lr = wv * 16 + q * 4 + i;
            float v = acc[nt][i] + bias;
            hs[lr][c] = v > 0.f ? v : 0.f;
        }
    }
    __syncthreads();
    int base = blockIdx.x * 64;
    for (int idx = tid; idx < 640; idx += 256) {
        int lr = idx / 10;
        int j = idx - lr * 10;
        int n = base + lr;
        if (n < N_NODES) {
            float a = bl3[j];
            #pragma unroll
            for (int k = 0; k < 32; k++) a += hs[lr][k] * Wl3[k * 10 + j];
            out[n * 10 + j] = a;
        }
    }
}

// ---------------- launch ----------------

extern "C" void kernel_launch(void* const* d_in, const int* in_sizes, int n_in,
                              void* d_out, int out_size, void* d_ws, size_t ws_size,
                              hipStream_t stream) {
    const float* x   = (const float*)d_in[0];
    const int* esrc  = (const int*)d_in[1];
    const int* edst  = (const int*)d_in[2];
    const float* ew  = (const float*)d_in[3];
    const float* W1s = (const float*)d_in[4];
    const float* W1n = (const float*)d_in[5];
    const float* b1  = (const float*)d_in[6];
    const float* W2s = (const float*)d_in[7];
    const float* W2n = (const float*)d_in[8];
    const float* b2  = (const float*)d_in[9];
    const float* Wl1 = (const float*)d_in[10];
    const float* bl1 = (const float*)d_in[11];
    const float* Wl2 = (const float*)d_in[12];
    const float* bl2 = (const float*)d_in[13];
    const float* Wl3 = (const float*)d_in[14];
    const float* bl3 = (const float*)d_in[15];

    float* out = (float*)d_out;       // [50000,10]
    float* emb = out + 500000;        // [50000,128] output 1

    char* ws = (char*)d_ws;
    size_t off = 0;
    auto alloc = [&](size_t bytes) -> void* {
        void* p = ws + off;
        off = (off + bytes + 255) & ~(size_t)255;
        return p;
    };
    int*   row_off = (int*)alloc((size_t)(N_NODES + 1) * 4);
    float* inv_deg = (float*)alloc((size_t)N_NODES * 4);
    int*   G       = (int*)alloc((size_t)NBLK_SORT * 256 * 4);
    int*   colsum  = (int*)alloc(256 * 4);
    int*   bkt_off = (int*)alloc(257 * 4);
    int*   bdst    = (int*)alloc((size_t)N_EDGES * 4);
    int2*  bsedge  = (int2*)alloc((size_t)N_EDGES * 8);
    int2*  sedge   = (int2*)alloc((size_t)N_EDGES * 8);
    unsigned short* xb   = (unsigned short*)alloc((size_t)N_NODES * 64 * 2);
    unsigned short* hn1b = (unsigned short*)alloc((size_t)N_NODES * 64 * 2);
    unsigned short* x1b  = (unsigned short*)alloc((size_t)N_NODES * 256 * 2);
    unsigned short* zb   = (unsigned short*)alloc((size_t)N_NODES * 128 * 2);
    unsigned short* embb = (unsigned short*)alloc((size_t)N_NODES * 128 * 2);
    unsigned short* h64b = (unsigned short*)alloc((size_t)N_NODES * 64 * 2);
    unsigned short* B1p  = (unsigned short*)alloc(128 * 256 * 2);
    unsigned short* B2p  = (unsigned short*)alloc(256 * 256 * 2);
    unsigned short* Bl1p = (unsigned short*)alloc(128 * 64 * 2);
    unsigned short* Bl2p = (unsigned short*)alloc(64 * 32 * 2);

    // fused cvt + weight packing + p1 histogram
    prep_p1_kernel<<<PREP_BLKS + NBLK_SORT, 256, 0, stream>>>(
        (const float4*)x, (ushort4*)xb, W1s, W1n, W2s, W2n, Wl1, Wl2,
        B1p, B2p, Bl1p, Bl2p, edst, G);

    // parallel scans + scatter + per-bucket sort
    p2a_scan<<<256, 256, 0, stream>>>(G, colsum);
    p2b_scan<<<1, 256, 0, stream>>>(colsum, bkt_off, row_off);
    p3_scatter<<<NBLK_SORT, 256, 0, stream>>>(esrc, edst, ew, G, bkt_off, bdst, bsedge);
    p4_sort<<<NBKT, 256, 0, stream>>>(bkt_off, bdst, bsedge, row_off, inv_deg, sedge);

    const int PBLK = (PR_TILES + 3) / 4;   // 391 (2 m-tiles per wave, small kernels)
    const int GBLK = (MT_TILES + 3) / 4;   // 782
    const int ABLK = (N_NODES + 3) / 4;    // 12500

    // layer 1
    agg64_kernel<<<ABLK, 256, 0, stream>>>((const uint2*)xb, row_off, sedge,
                                           inv_deg, (uint2*)hn1b);
    gemm1_mfma<<<GBLK, 256, 0, stream>>>(xb, hn1b, B1p, b1, x1b);

    // layer 2: GEMM first (self + z), then aggregate z in 128-dim
    gemm2_mfma<<<GBLK, 256, 0, stream>>>(x1b, B2p, b2, emb, zb);
    agg128_kernel<<<ABLK, 256, 0, stream>>>((const uint2*)zb, row_off, sedge,
                                            inv_deg, emb, (uint2*)embb);

    // MLP head
    mlp1_mfma<<<PBLK, 256, 0, stream>>>(embb, Bl1p, bl1, h64b);
    mlp23_mfma<<<GBLK, 256, 0, stream>>>(h64b, Bl2p, bl2, Wl3, bl3, out);
}